// Round 1
// baseline (4466.386 us; speedup 1.0000x reference)
//
#include <hip/hip_runtime.h>
#include <cmath>

#define BB 2
#define SEQ 2048
#define DIM 1024
#define NH 16
#define DH 64
#define DEPTH 2
#define FFD 4096
#define CHK 64
#define NCHK (SEQ/CHK)      // 32
#define ROWS (BB*SEQ)       // 4096

__device__ __forceinline__ float gelu_exact(float x) {
    return 0.5f * x * (1.0f + erff(x * 0.70710678118654752f));
}

// ---------------- LayerNorm: one block (256 thr) per row of 1024 ----------------
__global__ __launch_bounds__(256) void ln_kernel(
    const float* __restrict__ x, const float* __restrict__ g,
    const float* __restrict__ b, float* __restrict__ out)
{
    int row = blockIdx.x;
    const float4* xr = (const float4*)(x + (size_t)row * DIM);
    float4* outr = (float4*)(out + (size_t)row * DIM);
    int t = threadIdx.x;
    float4 v = xr[t];
    float s  = v.x + v.y + v.z + v.w;
    float ss = v.x*v.x + v.y*v.y + v.z*v.z + v.w*v.w;
    #pragma unroll
    for (int off = 32; off > 0; off >>= 1) {
        s  += __shfl_down(s, off);
        ss += __shfl_down(ss, off);
    }
    __shared__ float wsum[4], wsq[4], stats[2];
    int wid = t >> 6, lane = t & 63;
    if (lane == 0) { wsum[wid] = s; wsq[wid] = ss; }
    __syncthreads();
    if (t == 0) {
        float S  = wsum[0] + wsum[1] + wsum[2] + wsum[3];
        float SS = wsq[0] + wsq[1] + wsq[2] + wsq[3];
        float mean = S * (1.0f / DIM);
        float var  = SS * (1.0f / DIM) - mean * mean;
        stats[0] = mean;
        stats[1] = rsqrtf(var + 1e-5f);
    }
    __syncthreads();
    float mean = stats[0], rstd = stats[1];
    float4 gv = ((const float4*)g)[t];
    float4 bv = ((const float4*)b)[t];
    float4 o;
    o.x = (v.x - mean) * rstd * gv.x + bv.x;
    o.y = (v.y - mean) * rstd * gv.y + bv.y;
    o.z = (v.z - mean) * rstd * gv.z + bv.z;
    o.w = (v.w - mean) * rstd * gv.w + bv.w;
    outr[t] = o;
}

// ---------------- fp32 tiled GEMM: C[M,N] = A[M,K] @ B[K,N] (+ epilogue) --------
// MODE 0: C = A@B
// MODE 1: C = res + A@B + bias   (residual, in-place safe: res may == C)
// MODE 2: C = gelu(A@B + bias)
template<int MODE>
__global__ __launch_bounds__(256) void gemm_f32(
    const float* __restrict__ A, const float* __restrict__ Bm,
    float* __restrict__ C, const float* __restrict__ bias,
    const float* __restrict__ res, int M, int N, int K)
{
    __shared__ float As[16][65];
    __shared__ float Bs[16][65];
    int t  = threadIdx.x;
    int tx = t & 15, ty = t >> 4;
    int bm = blockIdx.y * 64, bn = blockIdx.x * 64;
    float acc[4][4] = {};
    for (int k0 = 0; k0 < K; k0 += 16) {
        #pragma unroll
        for (int i = 0; i < 4; i++) {
            int m = ty + i * 16;
            As[tx][m] = A[(size_t)(bm + m) * K + k0 + tx];
        }
        #pragma unroll
        for (int i = 0; i < 4; i++) {
            int kk = (t >> 6) + i * 4;
            int n  = t & 63;
            Bs[kk][n] = Bm[(size_t)(k0 + kk) * N + bn + n];
        }
        __syncthreads();
        #pragma unroll
        for (int kk = 0; kk < 16; kk++) {
            float a[4], bb[4];
            #pragma unroll
            for (int i = 0; i < 4; i++) a[i] = As[kk][ty * 4 + i];
            #pragma unroll
            for (int j = 0; j < 4; j++) bb[j] = Bs[kk][tx * 4 + j];
            #pragma unroll
            for (int i = 0; i < 4; i++)
                #pragma unroll
                for (int j = 0; j < 4; j++) acc[i][j] += a[i] * bb[j];
        }
        __syncthreads();
    }
    #pragma unroll
    for (int i = 0; i < 4; i++) {
        int row = bm + ty * 4 + i;
        #pragma unroll
        for (int j = 0; j < 4; j++) {
            int col = bn + tx * 4 + j;
            float v = acc[i][j];
            if (MODE == 1) v += res[(size_t)row * N + col] + bias[col];
            if (MODE == 2) v = gelu_exact(v + bias[col]);
            C[(size_t)row * N + col] = v;
        }
    }
}

// ---------------- attention kernel A: per-chunk local sums ----------------------
// KV[bh,c] = sum_{m in chunk} exp(k_m) outer v_m   (64x64)
// Ksum[bh,c] = sum_{m in chunk} exp(k_m)           (64)
__global__ __launch_bounds__(256) void attn_local(
    const float* __restrict__ kbuf, const float* __restrict__ vbuf,
    float* __restrict__ KV, float* __restrict__ Ksum)
{
    int blk = blockIdx.x;
    int c  = blk % NCHK;
    int bh = blk / NCHK;
    int b = bh / NH, h = bh % NH;
    __shared__ float ek[CHK][DH];
    __shared__ float vs[CHK][DH];
    int t = threadIdx.x;
    size_t gbase = ((size_t)(b * SEQ + c * CHK) * DIM) + h * DH;
    #pragma unroll
    for (int i = 0; i < 4; i++) {
        int idx = t + i * 256;      // float4 index 0..1023
        int m = idx >> 4, c4 = idx & 15;
        float4 k4 = *(const float4*)(kbuf + gbase + (size_t)m * DIM + c4 * 4);
        float4 v4 = *(const float4*)(vbuf + gbase + (size_t)m * DIM + c4 * 4);
        ek[m][c4 * 4 + 0] = expf(k4.x);
        ek[m][c4 * 4 + 1] = expf(k4.y);
        ek[m][c4 * 4 + 2] = expf(k4.z);
        ek[m][c4 * 4 + 3] = expf(k4.w);
        *(float4*)&vs[m][c4 * 4] = v4;
    }
    __syncthreads();
    int d = t >> 2, e0 = (t & 3) * 16;
    float4 acc[4] = {};
    float ksacc = 0.f;
    for (int m = 0; m < CHK; m++) {
        float ekd = ek[m][d];
        ksacc += ekd;
        #pragma unroll
        for (int j = 0; j < 4; j++) {
            float4 vv = *(const float4*)&vs[m][e0 + j * 4];
            acc[j].x += ekd * vv.x;
            acc[j].y += ekd * vv.y;
            acc[j].z += ekd * vv.z;
            acc[j].w += ekd * vv.w;
        }
    }
    float* outp = KV + ((size_t)(bh * NCHK + c) * (DH * DH)) + (size_t)d * DH + e0;
    #pragma unroll
    for (int j = 0; j < 4; j++) *(float4*)(outp + j * 4) = acc[j];
    if ((t & 3) == 0) Ksum[(size_t)(bh * NCHK + c) * DH + d] = ksacc;
}

// ---------------- attention kernel B: in-place exclusive prefix over chunks -----
__global__ __launch_bounds__(256) void attn_scan(
    float* __restrict__ KV, float* __restrict__ Ksum)
{
    int bh = blockIdx.x;
    int t = threadIdx.x;
    float4 run[4] = {};
    float krun = 0.f;
    for (int c = 0; c < NCHK; c++) {
        float* p = KV + ((size_t)(bh * NCHK + c) * (DH * DH)) + (size_t)t * 16;
        #pragma unroll
        for (int j = 0; j < 4; j++) {
            float4 tmp = *(float4*)(p + j * 4);
            *(float4*)(p + j * 4) = run[j];
            run[j].x += tmp.x; run[j].y += tmp.y; run[j].z += tmp.z; run[j].w += tmp.w;
        }
        if (t < DH) {
            float* kp = Ksum + (size_t)(bh * NCHK + c) * DH + t;
            float tmp = *kp;
            *kp = krun;
            krun += tmp;
        }
    }
}

// ---------------- attention kernel C: per-chunk output --------------------------
// one wave (64 thr) per chunk; thread t owns row n = c*CHK + t
__global__ __launch_bounds__(64) void attn_out_k(
    const float* __restrict__ qbuf, const float* __restrict__ kbuf,
    const float* __restrict__ vbuf, const float* __restrict__ KV,
    const float* __restrict__ Ksum, float* __restrict__ abuf)
{
    int blk = blockIdx.x;
    int c  = blk % NCHK;
    int bh = blk / NCHK;
    int b = bh / NH, h = bh % NH;
    __shared__ float ks[CHK][DH];
    __shared__ float vs[CHK][DH];
    __shared__ float qsT[DH][CHK];
    int t = threadIdx.x;   // 0..63
    size_t gbase = ((size_t)(b * SEQ + c * CHK) * DIM) + h * DH;
    #pragma unroll
    for (int i = 0; i < 16; i++) {
        int idx = t + i * 64;       // float4 index 0..1023
        int m = idx >> 4, c4 = idx & 15;
        float4 k4 = *(const float4*)(kbuf + gbase + (size_t)m * DIM + c4 * 4);
        float4 v4 = *(const float4*)(vbuf + gbase + (size_t)m * DIM + c4 * 4);
        ks[m][c4 * 4 + 0] = expf(k4.x);
        ks[m][c4 * 4 + 1] = expf(k4.y);
        ks[m][c4 * 4 + 2] = expf(k4.z);
        ks[m][c4 * 4 + 3] = expf(k4.w);
        *(float4*)&vs[m][c4 * 4] = v4;
    }
    // q row: softmax over feature dim then * dh^-0.5
    float q[DH];
    const float* qr = qbuf + gbase + (size_t)t * DIM;
    #pragma unroll
    for (int d4 = 0; d4 < 16; d4++) {
        float4 q4 = *(const float4*)(qr + d4 * 4);
        q[d4 * 4 + 0] = q4.x; q[d4 * 4 + 1] = q4.y;
        q[d4 * 4 + 2] = q4.z; q[d4 * 4 + 3] = q4.w;
    }
    float mx = q[0];
    #pragma unroll
    for (int d = 1; d < DH; d++) mx = fmaxf(mx, q[d]);
    float ssum = 0.f;
    #pragma unroll
    for (int d = 0; d < DH; d++) { q[d] = expf(q[d] - mx); ssum += q[d]; }
    float qscale = 0.125f / ssum;   // dh^-0.5 = 1/8
    #pragma unroll
    for (int d = 0; d < DH; d++) {
        q[d] *= qscale;
        qsT[d][t] = q[d];
    }
    __syncthreads();
    const float4* ks4 = (const float4*)&ks[0][0];
    const float4* vs4 = (const float4*)&vs[0][0];
    float4 acc[16] = {};
    float denom = 0.f;
    // intra-chunk causal part: rows m <= t
    for (int m = 0; m <= t; m++) {
        float s = 0.f;
        #pragma unroll
        for (int dd = 0; dd < 16; dd++) {
            float4 kk = ks4[m * 16 + dd];
            s += q[dd * 4 + 0] * kk.x + q[dd * 4 + 1] * kk.y
               + q[dd * 4 + 2] * kk.z + q[dd * 4 + 3] * kk.w;
        }
        denom += s;
        #pragma unroll
        for (int e = 0; e < 16; e++) {
            float4 vv = vs4[m * 16 + e];
            acc[e].x += s * vv.x; acc[e].y += s * vv.y;
            acc[e].z += s * vv.z; acc[e].w += s * vv.w;
        }
    }
    // inter-chunk part: q @ Sprev, q . Kprev  (uniform cached global reads)
    const float4* sp4 = (const float4*)(KV + (size_t)(bh * NCHK + c) * (DH * DH));
    const float* kpg = Ksum + (size_t)(bh * NCHK + c) * DH;
    for (int d = 0; d < DH; d++) {
        float qd = qsT[d][t];
        denom += qd * kpg[d];
        #pragma unroll
        for (int e = 0; e < 16; e++) {
            float4 spv = sp4[d * 16 + e];
            acc[e].x += qd * spv.x; acc[e].y += qd * spv.y;
            acc[e].z += qd * spv.z; acc[e].w += qd * spv.w;
        }
    }
    float dinv = 1.0f / fmaxf(denom, 1e-3f);
    float* ar = abuf + gbase + (size_t)t * DIM;
    #pragma unroll
    for (int e = 0; e < 16; e++) {
        float4 o;
        o.x = acc[e].x * dinv; o.y = acc[e].y * dinv;
        o.z = acc[e].z * dinv; o.w = acc[e].w * dinv;
        *(float4*)(ar + e * 4) = o;
    }
}

// ---------------- launch --------------------------------------------------------
extern "C" void kernel_launch(void* const* d_in, const int* in_sizes, int n_in,
                              void* d_out, int out_size, void* d_ws, size_t ws_size,
                              hipStream_t stream) {
    (void)in_sizes; (void)n_in; (void)out_size; (void)ws_size;
    const float* x_in  = (const float*)d_in[0];
    const float* ln1_g = (const float*)d_in[1];
    const float* ln1_b = (const float*)d_in[2];
    const float* Wq    = (const float*)d_in[3];
    const float* Wk    = (const float*)d_in[4];
    const float* Wv    = (const float*)d_in[5];
    const float* Wo    = (const float*)d_in[6];
    const float* bo    = (const float*)d_in[7];
    const float* ln2_g = (const float*)d_in[8];
    const float* ln2_b = (const float*)d_in[9];
    const float* W1    = (const float*)d_in[10];
    const float* b1    = (const float*)d_in[11];
    const float* W2    = (const float*)d_in[12];
    const float* b2    = (const float*)d_in[13];

    float* x = (float*)d_out;
    float* ws = (float*)d_ws;
    const size_t SZ = (size_t)ROWS * DIM;   // 4,194,304 floats

    float* xn = ws;             // SZ ; also reused as KV during attention (xn dead then)
    float* q  = ws + SZ;        // SZ
    float* k  = ws + 2 * SZ;    // SZ
    float* v  = ws + 3 * SZ;    // SZ
    float* a  = ws + 4 * SZ;    // SZ
    float* h1 = ws + SZ;        // 4*SZ (= B*SEQ*FFD), overlaps q,k,v,a (dead during FF)
    float* KV = xn;             // B*NH*NCHK*DH*DH = SZ floats exactly
    float* Ks = ws + 5 * SZ;    // 65536 floats

    hipMemcpyAsync(x, x_in, SZ * sizeof(float), hipMemcpyDeviceToDevice, stream);

    dim3 gD(DIM / 64, ROWS / 64);    // (16, 64)
    dim3 gF1(FFD / 64, ROWS / 64);   // (64, 64)

    for (int l = 0; l < DEPTH; l++) {
        const float* wq = Wq + (size_t)l * DIM * DIM;
        const float* wk = Wk + (size_t)l * DIM * DIM;
        const float* wv = Wv + (size_t)l * DIM * DIM;
        const float* wo = Wo + (size_t)l * DIM * DIM;
        const float* w1 = W1 + (size_t)l * DIM * FFD;
        const float* w2 = W2 + (size_t)l * FFD * DIM;

        // pre-norm attention block
        ln_kernel<<<ROWS, 256, 0, stream>>>(x, ln1_g + l * DIM, ln1_b + l * DIM, xn);
        gemm_f32<0><<<gD, 256, 0, stream>>>(xn, wq, q, nullptr, nullptr, ROWS, DIM, DIM);
        gemm_f32<0><<<gD, 256, 0, stream>>>(xn, wk, k, nullptr, nullptr, ROWS, DIM, DIM);
        gemm_f32<0><<<gD, 256, 0, stream>>>(xn, wv, v, nullptr, nullptr, ROWS, DIM, DIM);
        // xn dead from here until ln2 -> reuse as KV
        attn_local<<<BB * NH * NCHK, 256, 0, stream>>>(k, v, KV, Ks);
        attn_scan<<<BB * NH, 256, 0, stream>>>(KV, Ks);
        attn_out_k<<<BB * NH * NCHK, 64, 0, stream>>>(q, k, v, KV, Ks, a);
        gemm_f32<1><<<gD, 256, 0, stream>>>(a, wo, x, bo + l * DIM, x, ROWS, DIM, DIM);

        // pre-norm FF block
        ln_kernel<<<ROWS, 256, 0, stream>>>(x, ln2_g + l * DIM, ln2_b + l * DIM, xn);
        gemm_f32<2><<<gF1, 256, 0, stream>>>(xn, w1, h1, b1 + l * FFD, nullptr, ROWS, FFD, DIM);
        gemm_f32<1><<<gD, 256, 0, stream>>>(h1, w2, x, b2 + l * DIM, x, ROWS, DIM, FFD);
    }
}

// Round 2
// 1041.570 us; speedup vs baseline: 4.2881x; 4.2881x over previous
//
#include <hip/hip_runtime.h>
#include <cmath>

#define BB 2
#define SEQ 2048
#define DIM 1024
#define NH 16
#define DH 64
#define DEPTH 2
#define FFD 4096
#define CHK 64
#define NCHK (SEQ/CHK)      // 32
#define ROWS (BB*SEQ)       // 4096

typedef __bf16 bf16x8 __attribute__((ext_vector_type(8)));
typedef __bf16 bf16x4 __attribute__((ext_vector_type(4)));
typedef float  f32x4  __attribute__((ext_vector_type(4)));

__device__ __forceinline__ float gelu_exact(float x) {
    return 0.5f * x * (1.0f + erff(x * 0.70710678118654752f));
}

// ---------------- LayerNorm: one block (256 thr) per row of 1024, bf16 out ------
__global__ __launch_bounds__(256) void ln_kernel(
    const float* __restrict__ x, const float* __restrict__ g,
    const float* __restrict__ b, __bf16* __restrict__ out)
{
    int row = blockIdx.x;
    const float4* xr = (const float4*)(x + (size_t)row * DIM);
    int t = threadIdx.x;
    float4 v = xr[t];
    float s  = v.x + v.y + v.z + v.w;
    float ss = v.x*v.x + v.y*v.y + v.z*v.z + v.w*v.w;
    #pragma unroll
    for (int off = 32; off > 0; off >>= 1) {
        s  += __shfl_down(s, off);
        ss += __shfl_down(ss, off);
    }
    __shared__ float wsum[4], wsq[4], stats[2];
    int wid = t >> 6, lane = t & 63;
    if (lane == 0) { wsum[wid] = s; wsq[wid] = ss; }
    __syncthreads();
    if (t == 0) {
        float S  = wsum[0] + wsum[1] + wsum[2] + wsum[3];
        float SS = wsq[0] + wsq[1] + wsq[2] + wsq[3];
        float mean = S * (1.0f / DIM);
        float var  = SS * (1.0f / DIM) - mean * mean;
        stats[0] = mean;
        stats[1] = rsqrtf(var + 1e-5f);
    }
    __syncthreads();
    float mean = stats[0], rstd = stats[1];
    float4 gv = ((const float4*)g)[t];
    float4 bv = ((const float4*)b)[t];
    bf16x4 o;
    o[0] = (__bf16)((v.x - mean) * rstd * gv.x + bv.x);
    o[1] = (__bf16)((v.y - mean) * rstd * gv.y + bv.y);
    o[2] = (__bf16)((v.z - mean) * rstd * gv.z + bv.z);
    o[3] = (__bf16)((v.w - mean) * rstd * gv.w + bv.w);
    *(bf16x4*)(out + (size_t)row * DIM + t * 4) = o;
}

// ---------------- weight transpose + fp32 -> bf16: W[K][N] -> Wt[N][K] ----------
__global__ __launch_bounds__(256) void transpose_bf16(
    const float* __restrict__ W, __bf16* __restrict__ Wt, int K, int N)
{
    __shared__ float tile[32][33];
    int bx = blockIdx.x * 32;   // N
    int by = blockIdx.y * 32;   // K
    int tx = threadIdx.x & 31, ty = threadIdx.x >> 5;   // ty 0..7
    #pragma unroll
    for (int i = 0; i < 32; i += 8)
        tile[ty + i][tx] = W[(size_t)(by + ty + i) * N + bx + tx];
    __syncthreads();
    #pragma unroll
    for (int i = 0; i < 32; i += 8)
        Wt[(size_t)(bx + ty + i) * K + by + tx] = (__bf16)tile[tx][ty + i];
}

// ---------------- bf16 MFMA GEMM: C[M,N] = A[M,K] @ Bt[N,K]^T (+ epilogue) ------
// MODE 0: C = A@B (fp32 out)
// MODE 1: C = res + A@B + bias (fp32 out, in-place safe)
// MODE 2: C = gelu(A@B + bias) (bf16 out if OUTBF)
#define GBM 128
#define GBN 128
#define GBK 64
template<int MODE, int OUTBF>
__global__ __launch_bounds__(256) void gemm_bf16(
    const __bf16* __restrict__ A, const __bf16* __restrict__ Bt,
    void* __restrict__ Cv, const float* __restrict__ bias,
    const float* __restrict__ res, int M, int N, int K)
{
    __shared__ __bf16 Als[GBM * GBK];
    __shared__ __bf16 Bls[GBN * GBK];
    const int t = threadIdx.x;
    const int lane = t & 63;
    const int w = t >> 6;             // 0..3
    const int wr = w >> 1, wc = w & 1;
    const int bm = blockIdx.y * GBM, bn = blockIdx.x * GBN;

    f32x4 acc[4][4] = {};

    // staging geometry: wave w stages rows [w*32, w*32+32) of each tile,
    // 4 insts x (64 lanes x 16B); lane -> row w*32+i*8+(lane>>3), kcol (lane&7)*8
    const int srow = w * 32 + (lane >> 3);
    const int scol = (lane & 7) * 8;
    const __bf16* gA = A + (size_t)(bm + srow) * K + scol;
    const __bf16* gB = Bt + (size_t)(bn + srow) * K + scol;
    __bf16* lA = Als + w * 2048;   // wave-uniform LDS base
    __bf16* lB = Bls + w * 2048;

    for (int k0 = 0; k0 < K; k0 += GBK) {
        #pragma unroll
        for (int i = 0; i < 4; i++) {
            __builtin_amdgcn_global_load_lds(
                (const __attribute__((address_space(1))) void*)(gA + (size_t)(i * 8) * K + k0),
                (__attribute__((address_space(3))) void*)(lA + i * 512), 16, 0, 0);
            __builtin_amdgcn_global_load_lds(
                (const __attribute__((address_space(1))) void*)(gB + (size_t)(i * 8) * K + k0),
                (__attribute__((address_space(3))) void*)(lB + i * 512), 16, 0, 0);
        }
        __syncthreads();
        #pragma unroll
        for (int kk = 0; kk < GBK; kk += 32) {
            bf16x8 af[4], bfr[4];
            #pragma unroll
            for (int m = 0; m < 4; m++)
                af[m] = *(const bf16x8*)&Als[(wr * 64 + m * 16 + (lane & 15)) * GBK + kk + (lane >> 4) * 8];
            #pragma unroll
            for (int n = 0; n < 4; n++)
                bfr[n] = *(const bf16x8*)&Bls[(wc * 64 + n * 16 + (lane & 15)) * GBK + kk + (lane >> 4) * 8];
            #pragma unroll
            for (int m = 0; m < 4; m++)
                #pragma unroll
                for (int n = 0; n < 4; n++)
                    acc[m][n] = __builtin_amdgcn_mfma_f32_16x16x32_bf16(af[m], bfr[n], acc[m][n], 0, 0, 0);
        }
        __syncthreads();
    }
    // epilogue: C/D layout col=lane&15, row=(lane>>4)*4+reg
    const int crow0 = bm + wr * 64 + (lane >> 4) * 4;
    const int ccol0 = bn + wc * 64 + (lane & 15);
    #pragma unroll
    for (int m = 0; m < 4; m++) {
        #pragma unroll
        for (int n = 0; n < 4; n++) {
            int col = ccol0 + n * 16;
            #pragma unroll
            for (int r = 0; r < 4; r++) {
                int row = crow0 + m * 16 + r;
                float v = acc[m][n][r];
                if (MODE == 1) v += res[(size_t)row * N + col] + bias[col];
                if (MODE == 2) v = gelu_exact(v + bias[col]);
                if (OUTBF) ((__bf16*)Cv)[(size_t)row * N + col] = (__bf16)v;
                else       ((float*)Cv)[(size_t)row * N + col] = v;
            }
        }
    }
}

// ---------------- attention kernel A: per-chunk local sums ----------------------
__global__ __launch_bounds__(256) void attn_local(
    const float* __restrict__ kbuf, const float* __restrict__ vbuf,
    float* __restrict__ KV, float* __restrict__ Ksum)
{
    int blk = blockIdx.x;
    int c  = blk % NCHK;
    int bh = blk / NCHK;
    int b = bh / NH, h = bh % NH;
    __shared__ float ek[CHK][DH];
    __shared__ float vs[CHK][DH];
    int t = threadIdx.x;
    size_t gbase = ((size_t)(b * SEQ + c * CHK) * DIM) + h * DH;
    #pragma unroll
    for (int i = 0; i < 4; i++) {
        int idx = t + i * 256;
        int m = idx >> 4, c4 = idx & 15;
        float4 k4 = *(const float4*)(kbuf + gbase + (size_t)m * DIM + c4 * 4);
        float4 v4 = *(const float4*)(vbuf + gbase + (size_t)m * DIM + c4 * 4);
        ek[m][c4 * 4 + 0] = expf(k4.x);
        ek[m][c4 * 4 + 1] = expf(k4.y);
        ek[m][c4 * 4 + 2] = expf(k4.z);
        ek[m][c4 * 4 + 3] = expf(k4.w);
        *(float4*)&vs[m][c4 * 4] = v4;
    }
    __syncthreads();
    int d = t >> 2, e0 = (t & 3) * 16;
    float4 acc[4] = {};
    float ksacc = 0.f;
    for (int m = 0; m < CHK; m++) {
        float ekd = ek[m][d];
        ksacc += ekd;
        #pragma unroll
        for (int j = 0; j < 4; j++) {
            float4 vv = *(const float4*)&vs[m][e0 + j * 4];
            acc[j].x += ekd * vv.x;
            acc[j].y += ekd * vv.y;
            acc[j].z += ekd * vv.z;
            acc[j].w += ekd * vv.w;
        }
    }
    float* outp = KV + ((size_t)(bh * NCHK + c) * (DH * DH)) + (size_t)d * DH + e0;
    #pragma unroll
    for (int j = 0; j < 4; j++) *(float4*)(outp + j * 4) = acc[j];
    if ((t & 3) == 0) Ksum[(size_t)(bh * NCHK + c) * DH + d] = ksacc;
}

// ---------------- attention kernel B: in-place exclusive prefix over chunks -----
__global__ __launch_bounds__(256) void attn_scan(
    float* __restrict__ KV, float* __restrict__ Ksum)
{
    int bh = blockIdx.x;
    int t = threadIdx.x;
    float4 run[4] = {};
    float krun = 0.f;
    for (int c = 0; c < NCHK; c++) {
        float* p = KV + ((size_t)(bh * NCHK + c) * (DH * DH)) + (size_t)t * 16;
        #pragma unroll
        for (int j = 0; j < 4; j++) {
            float4 tmp = *(float4*)(p + j * 4);
            *(float4*)(p + j * 4) = run[j];
            run[j].x += tmp.x; run[j].y += tmp.y; run[j].z += tmp.z; run[j].w += tmp.w;
        }
        if (t < DH) {
            float* kp = Ksum + (size_t)(bh * NCHK + c) * DH + t;
            float tmp = *kp;
            *kp = krun;
            krun += tmp;
        }
    }
}

// ---------------- attention kernel C: per-chunk output (bf16 out) ---------------
__global__ __launch_bounds__(64) void attn_out_k(
    const float* __restrict__ qbuf, const float* __restrict__ kbuf,
    const float* __restrict__ vbuf, const float* __restrict__ KV,
    const float* __restrict__ Ksum, __bf16* __restrict__ abuf)
{
    int blk = blockIdx.x;
    int c  = blk % NCHK;
    int bh = blk / NCHK;
    int b = bh / NH, h = bh % NH;
    __shared__ float ks[CHK][DH];
    __shared__ float vs[CHK][DH];
    __shared__ float qsT[DH][CHK];
    int t = threadIdx.x;   // 0..63
    size_t gbase = ((size_t)(b * SEQ + c * CHK) * DIM) + h * DH;
    #pragma unroll
    for (int i = 0; i < 16; i++) {
        int idx = t + i * 64;
        int m = idx >> 4, c4 = idx & 15;
        float4 k4 = *(const float4*)(kbuf + gbase + (size_t)m * DIM + c4 * 4);
        float4 v4 = *(const float4*)(vbuf + gbase + (size_t)m * DIM + c4 * 4);
        ks[m][c4 * 4 + 0] = expf(k4.x);
        ks[m][c4 * 4 + 1] = expf(k4.y);
        ks[m][c4 * 4 + 2] = expf(k4.z);
        ks[m][c4 * 4 + 3] = expf(k4.w);
        *(float4*)&vs[m][c4 * 4] = v4;
    }
    float q[DH];
    const float* qr = qbuf + gbase + (size_t)t * DIM;
    #pragma unroll
    for (int d4 = 0; d4 < 16; d4++) {
        float4 q4 = *(const float4*)(qr + d4 * 4);
        q[d4 * 4 + 0] = q4.x; q[d4 * 4 + 1] = q4.y;
        q[d4 * 4 + 2] = q4.z; q[d4 * 4 + 3] = q4.w;
    }
    float mx = q[0];
    #pragma unroll
    for (int d = 1; d < DH; d++) mx = fmaxf(mx, q[d]);
    float ssum = 0.f;
    #pragma unroll
    for (int d = 0; d < DH; d++) { q[d] = expf(q[d] - mx); ssum += q[d]; }
    float qscale = 0.125f / ssum;
    #pragma unroll
    for (int d = 0; d < DH; d++) {
        q[d] *= qscale;
        qsT[d][t] = q[d];
    }
    __syncthreads();
    const float4* ks4 = (const float4*)&ks[0][0];
    const float4* vs4 = (const float4*)&vs[0][0];
    float4 acc[16] = {};
    float denom = 0.f;
    for (int m = 0; m <= t; m++) {
        float s = 0.f;
        #pragma unroll
        for (int dd = 0; dd < 16; dd++) {
            float4 kk = ks4[m * 16 + dd];
            s += q[dd * 4 + 0] * kk.x + q[dd * 4 + 1] * kk.y
               + q[dd * 4 + 2] * kk.z + q[dd * 4 + 3] * kk.w;
        }
        denom += s;
        #pragma unroll
        for (int e = 0; e < 16; e++) {
            float4 vv = vs4[m * 16 + e];
            acc[e].x += s * vv.x; acc[e].y += s * vv.y;
            acc[e].z += s * vv.z; acc[e].w += s * vv.w;
        }
    }
    const float4* sp4 = (const float4*)(KV + (size_t)(bh * NCHK + c) * (DH * DH));
    const float* kpg = Ksum + (size_t)(bh * NCHK + c) * DH;
    for (int d = 0; d < DH; d++) {
        float qd = qsT[d][t];
        denom += qd * kpg[d];
        #pragma unroll
        for (int e = 0; e < 16; e++) {
            float4 spv = sp4[d * 16 + e];
            acc[e].x += qd * spv.x; acc[e].y += qd * spv.y;
            acc[e].z += qd * spv.z; acc[e].w += qd * spv.w;
        }
    }
    float dinv = 1.0f / fmaxf(denom, 1e-3f);
    __bf16* ar = abuf + gbase + (size_t)t * DIM;
    #pragma unroll
    for (int e = 0; e < 16; e++) {
        bf16x4 o;
        o[0] = (__bf16)(acc[e].x * dinv);
        o[1] = (__bf16)(acc[e].y * dinv);
        o[2] = (__bf16)(acc[e].z * dinv);
        o[3] = (__bf16)(acc[e].w * dinv);
        *(bf16x4*)(ar + e * 4) = o;
    }
}

// ---------------- launch --------------------------------------------------------
extern "C" void kernel_launch(void* const* d_in, const int* in_sizes, int n_in,
                              void* d_out, int out_size, void* d_ws, size_t ws_size,
                              hipStream_t stream) {
    (void)in_sizes; (void)n_in; (void)out_size; (void)ws_size;
    const float* x_in  = (const float*)d_in[0];
    const float* ln1_g = (const float*)d_in[1];
    const float* ln1_b = (const float*)d_in[2];
    const float* Wq    = (const float*)d_in[3];
    const float* Wk    = (const float*)d_in[4];
    const float* Wv    = (const float*)d_in[5];
    const float* Wo    = (const float*)d_in[6];
    const float* bo    = (const float*)d_in[7];
    const float* ln2_g = (const float*)d_in[8];
    const float* ln2_b = (const float*)d_in[9];
    const float* W1    = (const float*)d_in[10];
    const float* b1    = (const float*)d_in[11];
    const float* W2    = (const float*)d_in[12];
    const float* b2    = (const float*)d_in[13];

    float* x = (float*)d_out;
    const size_t MB = 1024 * 1024;
    char* base = (char*)d_ws;

    // [0,16MB): xn bf16 (8MB) aliased with KV fp32 (16MB) — disjoint lifetimes
    __bf16* xn = (__bf16*)base;
    float*  KV = (float*)base;
    // [16MB,64MB): q,k,v fp32 (16MB each); h1 bf16 (32MB) aliases q+k
    float* q = (float*)(base + 16 * MB);
    float* k = (float*)(base + 32 * MB);
    float* v = (float*)(base + 48 * MB);
    __bf16* h1 = (__bf16*)q;
    // [64MB,72MB): a bf16
    __bf16* a = (__bf16*)(base + 64 * MB);
    // [72MB, 72.25MB): Ksum
    float* Ks = (float*)(base + 72 * MB);
    // [73MB, 97MB): transposed bf16 weights for current layer
    __bf16* wqt = (__bf16*)(base + 73 * MB);   // 2MB
    __bf16* wkt = (__bf16*)(base + 75 * MB);   // 2MB
    __bf16* wvt = (__bf16*)(base + 77 * MB);   // 2MB
    __bf16* wot = (__bf16*)(base + 79 * MB);   // 2MB
    __bf16* w1t = (__bf16*)(base + 81 * MB);   // 8MB
    __bf16* w2t = (__bf16*)(base + 89 * MB);   // 8MB

    const size_t SZ = (size_t)ROWS * DIM;
    hipMemcpyAsync(x, x_in, SZ * sizeof(float), hipMemcpyDeviceToDevice, stream);

    dim3 gD(DIM / GBN, ROWS / GBM);    // (8, 32)
    dim3 gF1(FFD / GBN, ROWS / GBM);   // (32, 32)
    dim3 gTd(DIM / 32, DIM / 32);      // (32, 32)
    dim3 gT1(FFD / 32, DIM / 32);      // (128, 32)
    dim3 gT2(DIM / 32, FFD / 32);      // (32, 128)

    for (int l = 0; l < DEPTH; l++) {
        const float* wq = Wq + (size_t)l * DIM * DIM;
        const float* wk = Wk + (size_t)l * DIM * DIM;
        const float* wv = Wv + (size_t)l * DIM * DIM;
        const float* wo = Wo + (size_t)l * DIM * DIM;
        const float* w1 = W1 + (size_t)l * DIM * FFD;
        const float* w2 = W2 + (size_t)l * FFD * DIM;

        // transpose+convert this layer's weights
        transpose_bf16<<<gTd, 256, 0, stream>>>(wq, wqt, DIM, DIM);
        transpose_bf16<<<gTd, 256, 0, stream>>>(wk, wkt, DIM, DIM);
        transpose_bf16<<<gTd, 256, 0, stream>>>(wv, wvt, DIM, DIM);
        transpose_bf16<<<gTd, 256, 0, stream>>>(wo, wot, DIM, DIM);
        transpose_bf16<<<gT1, 256, 0, stream>>>(w1, w1t, DIM, FFD);
        transpose_bf16<<<gT2, 256, 0, stream>>>(w2, w2t, FFD, DIM);

        // pre-norm attention block
        ln_kernel<<<ROWS, 256, 0, stream>>>(x, ln1_g + l * DIM, ln1_b + l * DIM, xn);
        gemm_bf16<0, 0><<<gD, 256, 0, stream>>>(xn, wqt, q, nullptr, nullptr, ROWS, DIM, DIM);
        gemm_bf16<0, 0><<<gD, 256, 0, stream>>>(xn, wkt, k, nullptr, nullptr, ROWS, DIM, DIM);
        gemm_bf16<0, 0><<<gD, 256, 0, stream>>>(xn, wvt, v, nullptr, nullptr, ROWS, DIM, DIM);
        // xn dead from here -> KV aliases it
        attn_local<<<BB * NH * NCHK, 256, 0, stream>>>(k, v, KV, Ks);
        attn_scan<<<BB * NH, 256, 0, stream>>>(KV, Ks);
        attn_out_k<<<BB * NH * NCHK, 64, 0, stream>>>(q, k, v, KV, Ks, a);
        gemm_bf16<1, 0><<<gD, 256, 0, stream>>>(a, wot, x, bo + l * DIM, x, ROWS, DIM, DIM);

        // pre-norm FF block (q/k/v dead -> h1 aliases)
        ln_kernel<<<ROWS, 256, 0, stream>>>(x, ln2_g + l * DIM, ln2_b + l * DIM, xn);
        gemm_bf16<2, 1><<<gF1, 256, 0, stream>>>(xn, w1t, h1, b1 + l * FFD, nullptr, ROWS, FFD, DIM);
        gemm_bf16<1, 0><<<gD, 256, 0, stream>>>(h1, w2t, x, b2 + l * DIM, x, ROWS, DIM, FFD);
    }
}

// Round 3
// 801.675 us; speedup vs baseline: 5.5713x; 1.2992x over previous
//
#include <hip/hip_runtime.h>
#include <cmath>

#define BB 2
#define SEQ 2048
#define DIM 1024
#define NH 16
#define DH 64
#define DEPTH 2
#define FFD 4096
#define CHK 64
#define NCHK (SEQ/CHK)      // 32
#define ROWS (BB*SEQ)       // 4096

typedef __bf16 bf16x8 __attribute__((ext_vector_type(8)));
typedef __bf16 bf16x4 __attribute__((ext_vector_type(4)));
typedef float  f32x4  __attribute__((ext_vector_type(4)));

__device__ __forceinline__ float gelu_exact(float x) {
    return 0.5f * x * (1.0f + erff(x * 0.70710678118654752f));
}

// ---------------- LayerNorm: one block (256 thr) per row of 1024, bf16 out ------
__global__ __launch_bounds__(256) void ln_kernel(
    const float* __restrict__ x, const float* __restrict__ g,
    const float* __restrict__ b, __bf16* __restrict__ out)
{
    int row = blockIdx.x;
    const float4* xr = (const float4*)(x + (size_t)row * DIM);
    int t = threadIdx.x;
    float4 v = xr[t];
    float s  = v.x + v.y + v.z + v.w;
    float ss = v.x*v.x + v.y*v.y + v.z*v.z + v.w*v.w;
    #pragma unroll
    for (int off = 32; off > 0; off >>= 1) {
        s  += __shfl_down(s, off);
        ss += __shfl_down(ss, off);
    }
    __shared__ float wsum[4], wsq[4], stats[2];
    int wid = t >> 6, lane = t & 63;
    if (lane == 0) { wsum[wid] = s; wsq[wid] = ss; }
    __syncthreads();
    if (t == 0) {
        float S  = wsum[0] + wsum[1] + wsum[2] + wsum[3];
        float SS = wsq[0] + wsq[1] + wsq[2] + wsq[3];
        float mean = S * (1.0f / DIM);
        float var  = SS * (1.0f / DIM) - mean * mean;
        stats[0] = mean;
        stats[1] = rsqrtf(var + 1e-5f);
    }
    __syncthreads();
    float mean = stats[0], rstd = stats[1];
    float4 gv = ((const float4*)g)[t];
    float4 bv = ((const float4*)b)[t];
    bf16x4 o;
    o[0] = (__bf16)((v.x - mean) * rstd * gv.x + bv.x);
    o[1] = (__bf16)((v.y - mean) * rstd * gv.y + bv.y);
    o[2] = (__bf16)((v.z - mean) * rstd * gv.z + bv.z);
    o[3] = (__bf16)((v.w - mean) * rstd * gv.w + bv.w);
    *(bf16x4*)(out + (size_t)row * DIM + t * 4) = o;
}

// ---------------- weight transpose + fp32 -> bf16: W[K][N] -> Wt[N][K] ----------
__global__ __launch_bounds__(256) void transpose_bf16(
    const float* __restrict__ W, __bf16* __restrict__ Wt, int K, int N)
{
    __shared__ float tile[32][33];
    int bx = blockIdx.x * 32;   // N
    int by = blockIdx.y * 32;   // K
    int tx = threadIdx.x & 31, ty = threadIdx.x >> 5;   // ty 0..7
    #pragma unroll
    for (int i = 0; i < 32; i += 8)
        tile[ty + i][tx] = W[(size_t)(by + ty + i) * N + bx + tx];
    __syncthreads();
    #pragma unroll
    for (int i = 0; i < 32; i += 8)
        Wt[(size_t)(bx + ty + i) * K + by + tx] = (__bf16)tile[tx][ty + i];
}

// ---------------- bf16 MFMA GEMM: C[M,N] = A[M,K] @ Bt[N,K]^T (+ epilogue) ------
#define GBM 128
#define GBN 128
#define GBK 64
template<int MODE, int OUTBF>
__global__ __launch_bounds__(256) void gemm_bf16(
    const __bf16* __restrict__ A, const __bf16* __restrict__ Bt,
    void* __restrict__ Cv, const float* __restrict__ bias,
    const float* __restrict__ res, int M, int N, int K)
{
    __shared__ __bf16 Als[GBM * GBK];
    __shared__ __bf16 Bls[GBN * GBK];
    const int t = threadIdx.x;
    const int lane = t & 63;
    const int w = t >> 6;             // 0..3
    const int wr = w >> 1, wc = w & 1;
    const int bm = blockIdx.y * GBM, bn = blockIdx.x * GBN;

    f32x4 acc[4][4] = {};

    const int srow = w * 32 + (lane >> 3);
    const int scol = (lane & 7) * 8;
    const __bf16* gA = A + (size_t)(bm + srow) * K + scol;
    const __bf16* gB = Bt + (size_t)(bn + srow) * K + scol;
    __bf16* lA = Als + w * 2048;
    __bf16* lB = Bls + w * 2048;

    for (int k0 = 0; k0 < K; k0 += GBK) {
        #pragma unroll
        for (int i = 0; i < 4; i++) {
            __builtin_amdgcn_global_load_lds(
                (const __attribute__((address_space(1))) void*)(gA + (size_t)(i * 8) * K + k0),
                (__attribute__((address_space(3))) void*)(lA + i * 512), 16, 0, 0);
            __builtin_amdgcn_global_load_lds(
                (const __attribute__((address_space(1))) void*)(gB + (size_t)(i * 8) * K + k0),
                (__attribute__((address_space(3))) void*)(lB + i * 512), 16, 0, 0);
        }
        __syncthreads();
        #pragma unroll
        for (int kk = 0; kk < GBK; kk += 32) {
            bf16x8 af[4], bfr[4];
            #pragma unroll
            for (int m = 0; m < 4; m++)
                af[m] = *(const bf16x8*)&Als[(wr * 64 + m * 16 + (lane & 15)) * GBK + kk + (lane >> 4) * 8];
            #pragma unroll
            for (int n = 0; n < 4; n++)
                bfr[n] = *(const bf16x8*)&Bls[(wc * 64 + n * 16 + (lane & 15)) * GBK + kk + (lane >> 4) * 8];
            #pragma unroll
            for (int m = 0; m < 4; m++)
                #pragma unroll
                for (int n = 0; n < 4; n++)
                    acc[m][n] = __builtin_amdgcn_mfma_f32_16x16x32_bf16(af[m], bfr[n], acc[m][n], 0, 0, 0);
        }
        __syncthreads();
    }
    const int crow0 = bm + wr * 64 + (lane >> 4) * 4;
    const int ccol0 = bn + wc * 64 + (lane & 15);
    #pragma unroll
    for (int m = 0; m < 4; m++) {
        #pragma unroll
        for (int n = 0; n < 4; n++) {
            int col = ccol0 + n * 16;
            #pragma unroll
            for (int r = 0; r < 4; r++) {
                int row = crow0 + m * 16 + r;
                float v = acc[m][n][r];
                if (MODE == 1) v += res[(size_t)row * N + col] + bias[col];
                if (MODE == 2) v = gelu_exact(v + bias[col]);
                if (OUTBF) ((__bf16*)Cv)[(size_t)row * N + col] = (__bf16)v;
                else       ((float*)Cv)[(size_t)row * N + col] = v;
            }
        }
    }
}

// ---------------- attention kernel A: per-chunk local sums ----------------------
__global__ __launch_bounds__(256) void attn_local(
    const float* __restrict__ kbuf, const float* __restrict__ vbuf,
    float* __restrict__ KV, float* __restrict__ Ksum)
{
    int blk = blockIdx.x;
    int c  = blk % NCHK;
    int bh = blk / NCHK;
    int b = bh / NH, h = bh % NH;
    __shared__ float ek[CHK][DH];
    __shared__ float vs[CHK][DH];
    int t = threadIdx.x;
    size_t gbase = ((size_t)(b * SEQ + c * CHK) * DIM) + h * DH;
    #pragma unroll
    for (int i = 0; i < 4; i++) {
        int idx = t + i * 256;
        int m = idx >> 4, c4 = idx & 15;
        float4 k4 = *(const float4*)(kbuf + gbase + (size_t)m * DIM + c4 * 4);
        float4 v4 = *(const float4*)(vbuf + gbase + (size_t)m * DIM + c4 * 4);
        ek[m][c4 * 4 + 0] = expf(k4.x);
        ek[m][c4 * 4 + 1] = expf(k4.y);
        ek[m][c4 * 4 + 2] = expf(k4.z);
        ek[m][c4 * 4 + 3] = expf(k4.w);
        *(float4*)&vs[m][c4 * 4] = v4;
    }
    __syncthreads();
    int d = t >> 2, e0 = (t & 3) * 16;
    float4 acc[4] = {};
    float ksacc = 0.f;
    for (int m = 0; m < CHK; m++) {
        float ekd = ek[m][d];
        ksacc += ekd;
        #pragma unroll
        for (int j = 0; j < 4; j++) {
            float4 vv = *(const float4*)&vs[m][e0 + j * 4];
            acc[j].x += ekd * vv.x;
            acc[j].y += ekd * vv.y;
            acc[j].z += ekd * vv.z;
            acc[j].w += ekd * vv.w;
        }
    }
    float* outp = KV + ((size_t)(bh * NCHK + c) * (DH * DH)) + (size_t)d * DH + e0;
    #pragma unroll
    for (int j = 0; j < 4; j++) *(float4*)(outp + j * 4) = acc[j];
    if ((t & 3) == 0) Ksum[(size_t)(bh * NCHK + c) * DH + d] = ksacc;
}

// ---------------- attention kernel B: parallel exclusive prefix over chunks -----
// grid (17, 32): bx<16 -> KV elems, bx==16 -> Ksum. One thread per (bh, elem).
__global__ __launch_bounds__(256) void attn_scan2(
    float* __restrict__ KV, float* __restrict__ Ksum)
{
    int bh = blockIdx.y;
    int bx = blockIdx.x;
    int t = threadIdx.x;
    if (bx < 16) {
        int elem = bx * 256 + t;
        float run = 0.f;
        for (int c = 0; c < NCHK; c++) {
            float* p = KV + ((size_t)(bh * NCHK + c)) * (DH * DH) + elem;
            float tmp = *p;
            *p = run;
            run += tmp;
        }
    } else if (t < DH) {
        float run = 0.f;
        for (int c = 0; c < NCHK; c++) {
            float* p = Ksum + ((size_t)(bh * NCHK + c)) * DH + t;
            float tmp = *p;
            *p = run;
            run += tmp;
        }
    }
}

// ---------------- attention kernel C: per-chunk output, 256 thr -----------------
// thread (row, qu): row = t>>2 (query row), qu = t&3.
// intra: keys m = qu + 4i (i<16, m<=row); inter: feature quarter d in [16qu,16qu+16).
// partials combined via shfl_xor(1),(2) within each 4-lane group.
#define LDP 68
__global__ __launch_bounds__(256) void attn_out_k(
    const float* __restrict__ qbuf, const float* __restrict__ kbuf,
    const float* __restrict__ vbuf, const float* __restrict__ KV,
    const float* __restrict__ Ksum, __bf16* __restrict__ abuf)
{
    int blk = blockIdx.x;
    int c  = blk % NCHK;
    int bh = blk / NCHK;
    int b = bh / NH, h = bh % NH;
    __shared__ float ks[CHK][LDP];   // exp(k); later reused as KVT[e][d]
    __shared__ float vs[CHK][LDP];
    int t = threadIdx.x;
    int row = t >> 2;
    int qu  = t & 3;
    size_t gbase = ((size_t)(b * SEQ + c * CHK) * DIM) + h * DH;

    // ---- stage exp(k), v into LDS (coalesced) ----
    #pragma unroll
    for (int i = 0; i < 4; i++) {
        int idx = t + i * 256;
        int m = idx >> 4, c4 = idx & 15;
        float4 k4 = *(const float4*)(kbuf + gbase + (size_t)m * DIM + c4 * 4);
        float4 v4 = *(const float4*)(vbuf + gbase + (size_t)m * DIM + c4 * 4);
        float4 e4;
        e4.x = expf(k4.x); e4.y = expf(k4.y); e4.z = expf(k4.z); e4.w = expf(k4.w);
        *(float4*)&ks[m][c4 * 4] = e4;
        *(float4*)&vs[m][c4 * 4] = v4;
    }

    // ---- q row: softmax over feature dim, * dh^-0.5 (redundant x4, in regs) ----
    float qv[DH];
    const float* qr = qbuf + gbase + (size_t)row * DIM;
    #pragma unroll
    for (int d4 = 0; d4 < 16; d4++) {
        float4 q4 = *(const float4*)(qr + d4 * 4);
        qv[d4 * 4 + 0] = q4.x; qv[d4 * 4 + 1] = q4.y;
        qv[d4 * 4 + 2] = q4.z; qv[d4 * 4 + 3] = q4.w;
    }
    float mx = qv[0];
    #pragma unroll
    for (int d = 1; d < DH; d++) mx = fmaxf(mx, qv[d]);
    float ssum = 0.f;
    #pragma unroll
    for (int d = 0; d < DH; d++) { qv[d] = expf(qv[d] - mx); ssum += qv[d]; }
    float qscale = 0.125f / ssum;
    #pragma unroll
    for (int d = 0; d < DH; d++) qv[d] *= qscale;
    // my feature-quarter copy (static reg indices, select by qu)
    float qmine[16];
    #pragma unroll
    for (int j = 0; j < 16; j++)
        qmine[j] = (qu & 2) ? ((qu & 1) ? qv[48 + j] : qv[32 + j])
                            : ((qu & 1) ? qv[16 + j] : qv[j]);

    __syncthreads();

    // ---- intra-chunk: keys m = qu+4i, m <= row ----
    float acc[DH] = {};
    float denom = 0.f;
    for (int i = 0; i < 16; i++) {
        int m = qu + 4 * i;
        if (m > row) break;
        const float4* krow = (const float4*)&ks[m][0];
        float s = 0.f;
        #pragma unroll
        for (int dd = 0; dd < 16; dd++) {
            float4 kk = krow[dd];
            s += qv[dd * 4 + 0] * kk.x + qv[dd * 4 + 1] * kk.y
               + qv[dd * 4 + 2] * kk.z + qv[dd * 4 + 3] * kk.w;
        }
        denom += s;
        const float4* vrow = (const float4*)&vs[m][0];
        #pragma unroll
        for (int eb = 0; eb < 16; eb++) {
            float4 vv = vrow[eb];
            acc[eb * 4 + 0] += s * vv.x; acc[eb * 4 + 1] += s * vv.y;
            acc[eb * 4 + 2] += s * vv.z; acc[eb * 4 + 3] += s * vv.w;
        }
    }

    // ---- stage KV^T into ks (exp(k) dead now) ----
    __syncthreads();
    {
        const float4* kvg = (const float4*)(KV + (size_t)(bh * NCHK + c) * (DH * DH));
        #pragma unroll
        for (int i = 0; i < 4; i++) {
            int idx = t + i * 256;
            int d = idx >> 4, e4 = idx & 15;
            float4 kv4 = kvg[idx];
            ks[e4 * 4 + 0][d] = kv4.x;
            ks[e4 * 4 + 1][d] = kv4.y;
            ks[e4 * 4 + 2][d] = kv4.z;
            ks[e4 * 4 + 3][d] = kv4.w;
        }
    }
    // Ksum part of denom (my feature quarter, global read)
    {
        const float* kpg = Ksum + (size_t)(bh * NCHK + c) * DH + qu * 16;
        #pragma unroll
        for (int j4 = 0; j4 < 4; j4++) {
            float4 kp = *(const float4*)(kpg + j4 * 4);
            denom += qmine[j4 * 4 + 0] * kp.x + qmine[j4 * 4 + 1] * kp.y
                   + qmine[j4 * 4 + 2] * kp.z + qmine[j4 * 4 + 3] * kp.w;
        }
    }
    __syncthreads();

    // ---- inter-chunk: acc[e] += sum_{d in my quarter} qmine * KVT[e][d] ----
    #pragma unroll
    for (int e = 0; e < DH; e++) {
        const float4* kvt = (const float4*)&ks[e][qu * 16];
        float se = 0.f;
        #pragma unroll
        for (int dd = 0; dd < 4; dd++) {
            float4 kv = kvt[dd];
            se += qmine[dd * 4 + 0] * kv.x + qmine[dd * 4 + 1] * kv.y
                + qmine[dd * 4 + 2] * kv.z + qmine[dd * 4 + 3] * kv.w;
        }
        acc[e] += se;
    }

    // ---- combine quarters (4-lane xor reduce), normalize, store ----
    denom += __shfl_xor(denom, 1);
    denom += __shfl_xor(denom, 2);
    #pragma unroll
    for (int e = 0; e < DH; e++) {
        acc[e] += __shfl_xor(acc[e], 1);
        acc[e] += __shfl_xor(acc[e], 2);
    }
    float dinv = 1.0f / fmaxf(denom, 1e-3f);
    // write my e-quarter (static reg indices, select by qu)
    bf16x8 o0, o1;
    #pragma unroll
    for (int j = 0; j < 16; j++) {
        float v01 = (qu & 2) ? ((qu & 1) ? acc[48 + j] : acc[32 + j])
                             : ((qu & 1) ? acc[16 + j] : acc[j]);
        float ov = v01 * dinv;
        if (j < 8) o0[j] = (__bf16)ov;
        else       o1[j - 8] = (__bf16)ov;
    }
    __bf16* ar = abuf + gbase + (size_t)row * DIM + qu * 16;
    *(bf16x8*)(ar)     = o0;
    *(bf16x8*)(ar + 8) = o1;
}

// ---------------- launch --------------------------------------------------------
extern "C" void kernel_launch(void* const* d_in, const int* in_sizes, int n_in,
                              void* d_out, int out_size, void* d_ws, size_t ws_size,
                              hipStream_t stream) {
    (void)in_sizes; (void)n_in; (void)out_size; (void)ws_size;
    const float* x_in  = (const float*)d_in[0];
    const float* ln1_g = (const float*)d_in[1];
    const float* ln1_b = (const float*)d_in[2];
    const float* Wq    = (const float*)d_in[3];
    const float* Wk    = (const float*)d_in[4];
    const float* Wv    = (const float*)d_in[5];
    const float* Wo    = (const float*)d_in[6];
    const float* bo    = (const float*)d_in[7];
    const float* ln2_g = (const float*)d_in[8];
    const float* ln2_b = (const float*)d_in[9];
    const float* W1    = (const float*)d_in[10];
    const float* b1    = (const float*)d_in[11];
    const float* W2    = (const float*)d_in[12];
    const float* b2    = (const float*)d_in[13];

    float* x = (float*)d_out;
    const size_t MB = 1024 * 1024;
    char* base = (char*)d_ws;

    __bf16* xn = (__bf16*)base;
    float*  KV = (float*)base;
    float* q = (float*)(base + 16 * MB);
    float* k = (float*)(base + 32 * MB);
    float* v = (float*)(base + 48 * MB);
    __bf16* h1 = (__bf16*)q;
    __bf16* a = (__bf16*)(base + 64 * MB);
    float* Ks = (float*)(base + 72 * MB);
    __bf16* wqt = (__bf16*)(base + 73 * MB);
    __bf16* wkt = (__bf16*)(base + 75 * MB);
    __bf16* wvt = (__bf16*)(base + 77 * MB);
    __bf16* wot = (__bf16*)(base + 79 * MB);
    __bf16* w1t = (__bf16*)(base + 81 * MB);
    __bf16* w2t = (__bf16*)(base + 89 * MB);

    const size_t SZ = (size_t)ROWS * DIM;
    hipMemcpyAsync(x, x_in, SZ * sizeof(float), hipMemcpyDeviceToDevice, stream);

    dim3 gD(DIM / GBN, ROWS / GBM);    // (8, 32)
    dim3 gF1(FFD / GBN, ROWS / GBM);   // (32, 32)
    dim3 gTd(DIM / 32, DIM / 32);
    dim3 gT1(FFD / 32, DIM / 32);
    dim3 gT2(DIM / 32, FFD / 32);
    dim3 gScan(17, BB * NH);

    for (int l = 0; l < DEPTH; l++) {
        const float* wq = Wq + (size_t)l * DIM * DIM;
        const float* wk = Wk + (size_t)l * DIM * DIM;
        const float* wv = Wv + (size_t)l * DIM * DIM;
        const float* wo = Wo + (size_t)l * DIM * DIM;
        const float* w1 = W1 + (size_t)l * DIM * FFD;
        const float* w2 = W2 + (size_t)l * FFD * DIM;

        transpose_bf16<<<gTd, 256, 0, stream>>>(wq, wqt, DIM, DIM);
        transpose_bf16<<<gTd, 256, 0, stream>>>(wk, wkt, DIM, DIM);
        transpose_bf16<<<gTd, 256, 0, stream>>>(wv, wvt, DIM, DIM);
        transpose_bf16<<<gTd, 256, 0, stream>>>(wo, wot, DIM, DIM);
        transpose_bf16<<<gT1, 256, 0, stream>>>(w1, w1t, DIM, FFD);
        transpose_bf16<<<gT2, 256, 0, stream>>>(w2, w2t, FFD, DIM);

        // pre-norm attention block
        ln_kernel<<<ROWS, 256, 0, stream>>>(x, ln1_g + l * DIM, ln1_b + l * DIM, xn);
        gemm_bf16<0, 0><<<gD, 256, 0, stream>>>(xn, wqt, q, nullptr, nullptr, ROWS, DIM, DIM);
        gemm_bf16<0, 0><<<gD, 256, 0, stream>>>(xn, wkt, k, nullptr, nullptr, ROWS, DIM, DIM);
        gemm_bf16<0, 0><<<gD, 256, 0, stream>>>(xn, wvt, v, nullptr, nullptr, ROWS, DIM, DIM);
        // xn dead from here -> KV aliases it
        attn_local<<<BB * NH * NCHK, 256, 0, stream>>>(k, v, KV, Ks);
        attn_scan2<<<gScan, 256, 0, stream>>>(KV, Ks);
        attn_out_k<<<BB * NH * NCHK, 256, 0, stream>>>(q, k, v, KV, Ks, a);
        gemm_bf16<1, 0><<<gD, 256, 0, stream>>>(a, wot, x, bo + l * DIM, x, ROWS, DIM, DIM);

        // pre-norm FF block
        ln_kernel<<<ROWS, 256, 0, stream>>>(x, ln2_g + l * DIM, ln2_b + l * DIM, xn);
        gemm_bf16<2, 1><<<gF1, 256, 0, stream>>>(xn, w1t, h1, b1 + l * FFD, nullptr, ROWS, FFD, DIM);
        gemm_bf16<1, 0><<<gD, 256, 0, stream>>>(h1, w2t, x, b2 + l * DIM, x, ROWS, DIM, FFD);
    }
}

// Round 5
// 630.898 us; speedup vs baseline: 7.0794x; 1.2707x over previous
//
#include <hip/hip_runtime.h>
#include <cmath>

#define BB 2
#define SEQ 2048
#define DIM 1024
#define NH 16
#define DH 64
#define DEPTH 2
#define FFD 4096
#define CHK 64
#define NCHK (SEQ/CHK)      // 32
#define ROWS (BB*SEQ)       // 4096

typedef __bf16 bf16x8 __attribute__((ext_vector_type(8)));
typedef __bf16 bf16x4 __attribute__((ext_vector_type(4)));
typedef float  f32x4  __attribute__((ext_vector_type(4)));

__device__ __forceinline__ float gelu_exact(float x) {
    return 0.5f * x * (1.0f + erff(x * 0.70710678118654752f));
}

// swizzled halfword index into a [64][64] bf16 tile with 128B pitch:
// flips col bits 3..5 by row&7 -> conflict-free vector r/w (G4 / T2)
__device__ __forceinline__ int swz128(int row, int col) {
    return row * 64 + (col ^ ((row & 7) << 3));
}

// ---------------- LayerNorm: one block (256 thr) per row of 1024, bf16 out ------
__global__ __launch_bounds__(256) void ln_kernel(
    const float* __restrict__ x, const float* __restrict__ g,
    const float* __restrict__ b, __bf16* __restrict__ out)
{
    int row = blockIdx.x;
    const float4* xr = (const float4*)(x + (size_t)row * DIM);
    int t = threadIdx.x;
    float4 v = xr[t];
    float s  = v.x + v.y + v.z + v.w;
    float ss = v.x*v.x + v.y*v.y + v.z*v.z + v.w*v.w;
    #pragma unroll
    for (int off = 32; off > 0; off >>= 1) {
        s  += __shfl_down(s, off);
        ss += __shfl_down(ss, off);
    }
    __shared__ float wsum[4], wsq[4], stats[2];
    int wid = t >> 6, lane = t & 63;
    if (lane == 0) { wsum[wid] = s; wsq[wid] = ss; }
    __syncthreads();
    if (t == 0) {
        float S  = wsum[0] + wsum[1] + wsum[2] + wsum[3];
        float SS = wsq[0] + wsq[1] + wsq[2] + wsq[3];
        float mean = S * (1.0f / DIM);
        float var  = SS * (1.0f / DIM) - mean * mean;
        stats[0] = mean;
        stats[1] = rsqrtf(var + 1e-5f);
    }
    __syncthreads();
    float mean = stats[0], rstd = stats[1];
    float4 gv = ((const float4*)g)[t];
    float4 bv = ((const float4*)b)[t];
    bf16x4 o;
    o[0] = (__bf16)((v.x - mean) * rstd * gv.x + bv.x);
    o[1] = (__bf16)((v.y - mean) * rstd * gv.y + bv.y);
    o[2] = (__bf16)((v.z - mean) * rstd * gv.z + bv.z);
    o[3] = (__bf16)((v.w - mean) * rstd * gv.w + bv.w);
    *(bf16x4*)(out + (size_t)row * DIM + t * 4) = o;
}

// ---------------- weight transpose + fp32 -> bf16: W[K][N] -> Wt[N][K] ----------
__global__ __launch_bounds__(256) void transpose_bf16(
    const float* __restrict__ W, __bf16* __restrict__ Wt, int K, int N)
{
    __shared__ float tile[32][33];
    int bx = blockIdx.x * 32;   // N
    int by = blockIdx.y * 32;   // K
    int tx = threadIdx.x & 31, ty = threadIdx.x >> 5;   // ty 0..7
    #pragma unroll
    for (int i = 0; i < 32; i += 8)
        tile[ty + i][tx] = W[(size_t)(by + ty + i) * N + bx + tx];
    __syncthreads();
    #pragma unroll
    for (int i = 0; i < 32; i += 8)
        Wt[(size_t)(bx + ty + i) * K + by + tx] = (__bf16)tile[tx][ty + i];
}

// ---------------- bf16 MFMA GEMM: C[M,N] = A[M,K] @ Bt[N,K]^T (+ epilogue) ------
#define GBM 128
#define GBN 128
#define GBK 64
template<int MODE, int OUTBF>
__global__ __launch_bounds__(256) void gemm_bf16(
    const __bf16* __restrict__ A, const __bf16* __restrict__ Bt,
    void* __restrict__ Cv, const float* __restrict__ bias,
    const float* __restrict__ res, int M, int N, int K)
{
    __shared__ __bf16 Als[GBM * GBK];
    __shared__ __bf16 Bls[GBN * GBK];
    const int t = threadIdx.x;
    const int lane = t & 63;
    const int w = t >> 6;             // 0..3
    const int wr = w >> 1, wc = w & 1;
    const int bm = blockIdx.y * GBM, bn = blockIdx.x * GBN;

    f32x4 acc[4][4] = {};

    const int srow = w * 32 + (lane >> 3);
    const int scol = (lane & 7) * 8;
    const __bf16* gA = A + (size_t)(bm + srow) * K + scol;
    const __bf16* gB = Bt + (size_t)(bn + srow) * K + scol;
    __bf16* lA = Als + w * 2048;
    __bf16* lB = Bls + w * 2048;

    for (int k0 = 0; k0 < K; k0 += GBK) {
        #pragma unroll
        for (int i = 0; i < 4; i++) {
            __builtin_amdgcn_global_load_lds(
                (const __attribute__((address_space(1))) void*)(gA + (size_t)(i * 8) * K + k0),
                (__attribute__((address_space(3))) void*)(lA + i * 512), 16, 0, 0);
            __builtin_amdgcn_global_load_lds(
                (const __attribute__((address_space(1))) void*)(gB + (size_t)(i * 8) * K + k0),
                (__attribute__((address_space(3))) void*)(lB + i * 512), 16, 0, 0);
        }
        __syncthreads();
        #pragma unroll
        for (int kk = 0; kk < GBK; kk += 32) {
            bf16x8 af[4], bfr[4];
            #pragma unroll
            for (int m = 0; m < 4; m++)
                af[m] = *(const bf16x8*)&Als[(wr * 64 + m * 16 + (lane & 15)) * GBK + kk + (lane >> 4) * 8];
            #pragma unroll
            for (int n = 0; n < 4; n++)
                bfr[n] = *(const bf16x8*)&Bls[(wc * 64 + n * 16 + (lane & 15)) * GBK + kk + (lane >> 4) * 8];
            #pragma unroll
            for (int m = 0; m < 4; m++)
                #pragma unroll
                for (int n = 0; n < 4; n++)
                    acc[m][n] = __builtin_amdgcn_mfma_f32_16x16x32_bf16(af[m], bfr[n], acc[m][n], 0, 0, 0);
        }
        __syncthreads();
    }
    const int crow0 = bm + wr * 64 + (lane >> 4) * 4;
    const int ccol0 = bn + wc * 64 + (lane & 15);
    #pragma unroll
    for (int m = 0; m < 4; m++) {
        #pragma unroll
        for (int n = 0; n < 4; n++) {
            int col = ccol0 + n * 16;
            #pragma unroll
            for (int r = 0; r < 4; r++) {
                int row = crow0 + m * 16 + r;
                float v = acc[m][n][r];
                if (MODE == 1) v += res[(size_t)row * N + col] + bias[col];
                if (MODE == 2) v = gelu_exact(v + bias[col]);
                if (OUTBF) ((__bf16*)Cv)[(size_t)row * N + col] = (__bf16)v;
                else       ((float*)Cv)[(size_t)row * N + col] = v;
            }
        }
    }
}

// ---------------- attn kernel A: per-chunk KVT_c[e][d] = sum_m v[m][e]ek[m][d] --
// MFMA: KVT = mfma(A = vT rows (direct global), B^T = ekT rows (LDS transpose)).
__global__ __launch_bounds__(256) void attn_local_m(
    const __bf16* __restrict__ kg, const __bf16* __restrict__ vTg,
    float* __restrict__ KVT, float* __restrict__ Ksum)
{
    int blk = blockIdx.x;
    int c = blk % NCHK, bh = blk / NCHK;
    int b = bh / NH, h = bh % NH;
    __shared__ __bf16 ek_s[64 * 64];    // swizzled pitch-64hw
    __shared__ __bf16 ekT_s[64 * 68];   // pitch 68hw (136B)
    __shared__ float ksum_p[4][64];
    int t = threadIdx.x, w = t >> 6, l = t & 63;
    size_t rowbase = (size_t)(b * SEQ + c * CHK);

    // stage ek_s[m][d] = exp(k) bf16
    {
        int m = t >> 2, dq = t & 3;
        const __bf16* kr = kg + (rowbase + m) * DIM + h * DH + dq * 16;
        bf16x8 k0 = *(const bf16x8*)kr;
        bf16x8 k1 = *(const bf16x8*)(kr + 8);
        bf16x8 e0, e1;
        #pragma unroll
        for (int j = 0; j < 8; j++) {
            e0[j] = (__bf16)__expf((float)k0[j]);
            e1[j] = (__bf16)__expf((float)k1[j]);
        }
        *(bf16x8*)&ek_s[swz128(m, dq * 16)] = e0;
        *(bf16x8*)&ek_s[swz128(m, dq * 16 + 8)] = e1;
    }
    __syncthreads();
    // transpose: thread (d=l, m-range w*16..+16): uniform-row reads, packed b64 writes
    {
        float kacc = 0.f;
        #pragma unroll
        for (int g = 0; g < 4; g++) {
            bf16x4 pk;
            #pragma unroll
            for (int j = 0; j < 4; j++) {
                __bf16 e = ek_s[swz128(w * 16 + g * 4 + j, l)];
                pk[j] = e;
                kacc += (float)e;
            }
            *(bf16x4*)&ekT_s[l * 68 + w * 16 + g * 4] = pk;
        }
        ksum_p[w][l] = kacc;
    }
    __syncthreads();
    // MFMA: wave w owns e-strip [w*16, w*16+16)
    f32x4 acc[4] = {};
    const __bf16* vbase = vTg + (size_t)(h * DH + w * 16 + (l & 15)) * ROWS
                        + (size_t)b * SEQ + c * CHK + (l >> 4) * 8;   // FIX: + b*SEQ
    bf16x8 a0 = *(const bf16x8*)vbase;
    bf16x8 a1 = *(const bf16x8*)(vbase + 32);
    #pragma unroll
    for (int fn = 0; fn < 4; fn++) {
        int rbase = (fn * 16 + (l & 15)) * 68 + (l >> 4) * 8;
        bf16x4 b0a = *(const bf16x4*)&ekT_s[rbase];
        bf16x4 b0b = *(const bf16x4*)&ekT_s[rbase + 4];
        bf16x4 b1a = *(const bf16x4*)&ekT_s[rbase + 32];
        bf16x4 b1b = *(const bf16x4*)&ekT_s[rbase + 36];
        bf16x8 b0, b1;
        #pragma unroll
        for (int j = 0; j < 4; j++) {
            b0[j] = b0a[j]; b0[j + 4] = b0b[j];
            b1[j] = b1a[j]; b1[j + 4] = b1b[j];
        }
        acc[fn] = __builtin_amdgcn_mfma_f32_16x16x32_bf16(a0, b0, acc[fn], 0, 0, 0);
        acc[fn] = __builtin_amdgcn_mfma_f32_16x16x32_bf16(a1, b1, acc[fn], 0, 0, 0);
    }
    float* kvout = KVT + (size_t)(bh * NCHK + c) * (DH * DH);
    #pragma unroll
    for (int fn = 0; fn < 4; fn++)
        #pragma unroll
        for (int r = 0; r < 4; r++)
            kvout[(w * 16 + (l >> 4) * 4 + r) * DH + fn * 16 + (l & 15)] = acc[fn][r];
    if (t < 64) {
        float s = ksum_p[0][t] + ksum_p[1][t] + ksum_p[2][t] + ksum_p[3][t];
        Ksum[(size_t)(bh * NCHK + c) * DH + t] = s;
    }
}

// ---------------- attn kernel B: parallel exclusive prefix over chunks ----------
__global__ __launch_bounds__(256) void attn_scan2(
    float* __restrict__ KV, float* __restrict__ Ksum)
{
    int bh = blockIdx.y;
    int bx = blockIdx.x;
    int t = threadIdx.x;
    if (bx < 16) {
        int elem = bx * 256 + t;
        float run = 0.f;
        for (int c = 0; c < NCHK; c++) {
            float* p = KV + ((size_t)(bh * NCHK + c)) * (DH * DH) + elem;
            float tmp = *p;
            *p = run;
            run += tmp;
        }
    } else if (t < DH) {
        float run = 0.f;
        for (int c = 0; c < NCHK; c++) {
            float* p = Ksum + ((size_t)(bh * NCHK + c)) * DH + t;
            float tmp = *p;
            *p = run;
            run += tmp;
        }
    }
}

// ---------------- attn kernel C: per-chunk output via MFMA ----------------------
// S^T = mfma(A=EK, B^T=Q) -> mask -> s_s rows; O = mfma(S, V^T) + mfma(Q, KVT).
// denom[i] = q.Ksum_prev + rowsum(masked S^T[:,i]).
__global__ __launch_bounds__(256) void attn_out_m(
    const __bf16* __restrict__ qg, const __bf16* __restrict__ kg,
    const __bf16* __restrict__ vTg, const float* __restrict__ KVT,
    const float* __restrict__ Ksum, __bf16* __restrict__ ag)
{
    int blk = blockIdx.x;
    int c = blk % NCHK, bh = blk / NCHK;
    int b = bh / NH, h = bh % NH;
    __shared__ __bf16 q_s[64 * 64];
    __shared__ __bf16 ek_s[64 * 64];
    __shared__ __bf16 s_s[64 * 64];
    __shared__ __bf16 kvT_s[64 * 64];
    __shared__ float denom_s[64];
    int t = threadIdx.x, w = t >> 6, l = t & 63;
    size_t rowbase = (size_t)(b * SEQ + c * CHK);

    // P0a: q softmax (4 thr/row) + stage bf16 + ksum-part of denom
    {
        int i = t >> 2, dq = t & 3;
        const __bf16* qr = qg + (rowbase + i) * DIM + h * DH + dq * 16;
        bf16x8 q0 = *(const bf16x8*)qr, q1 = *(const bf16x8*)(qr + 8);
        float qf[16];
        #pragma unroll
        for (int j = 0; j < 8; j++) { qf[j] = (float)q0[j]; qf[8 + j] = (float)q1[j]; }
        float mx = qf[0];
        #pragma unroll
        for (int j = 1; j < 16; j++) mx = fmaxf(mx, qf[j]);
        mx = fmaxf(mx, __shfl_xor(mx, 1));
        mx = fmaxf(mx, __shfl_xor(mx, 2));
        float ss = 0.f;
        #pragma unroll
        for (int j = 0; j < 16; j++) { qf[j] = __expf(qf[j] - mx); ss += qf[j]; }
        ss += __shfl_xor(ss, 1);
        ss += __shfl_xor(ss, 2);
        float sc = 0.125f / ss;
        bf16x8 o0, o1;
        #pragma unroll
        for (int j = 0; j < 8; j++) {
            o0[j] = (__bf16)(qf[j] * sc);
            o1[j] = (__bf16)(qf[8 + j] * sc);
        }
        *(bf16x8*)&q_s[swz128(i, dq * 16)] = o0;
        *(bf16x8*)&q_s[swz128(i, dq * 16 + 8)] = o1;
        const float* kp = Ksum + (size_t)(bh * NCHK + c) * DH + dq * 16;
        float dk = 0.f;
        #pragma unroll
        for (int j = 0; j < 16; j++) dk += (qf[j] * sc) * kp[j];
        dk += __shfl_xor(dk, 1);
        dk += __shfl_xor(dk, 2);
        if (dq == 0) denom_s[i] = dk;
    }
    // P0b: ek stage
    {
        int m = t >> 2, dq = t & 3;
        const __bf16* kr = kg + (rowbase + m) * DIM + h * DH + dq * 16;
        bf16x8 k0 = *(const bf16x8*)kr, k1 = *(const bf16x8*)(kr + 8);
        bf16x8 e0, e1;
        #pragma unroll
        for (int j = 0; j < 8; j++) {
            e0[j] = (__bf16)__expf((float)k0[j]);
            e1[j] = (__bf16)__expf((float)k1[j]);
        }
        *(bf16x8*)&ek_s[swz128(m, dq * 16)] = e0;
        *(bf16x8*)&ek_s[swz128(m, dq * 16 + 8)] = e1;
    }
    // P0c: kvT stage fp32 -> bf16
    {
        int e = t >> 2, dq = t & 3;
        const float* kvr = KVT + (size_t)(bh * NCHK + c) * (DH * DH) + e * DH + dq * 16;
        bf16x8 o0, o1;
        #pragma unroll
        for (int j = 0; j < 8; j++) { o0[j] = (__bf16)kvr[j]; o1[j] = (__bf16)kvr[8 + j]; }
        *(bf16x8*)&kvT_s[swz128(e, dq * 16)] = o0;
        *(bf16x8*)&kvT_s[swz128(e, dq * 16 + 8)] = o1;
    }
    __syncthreads();

    // P1: S^T (wave w owns i-strip [w*16,w*16+16))
    bf16x8 bq0 = *(const bf16x8*)&q_s[swz128(w * 16 + (l & 15), (l >> 4) * 8)];
    bf16x8 bq1 = *(const bf16x8*)&q_s[swz128(w * 16 + (l & 15), 32 + (l >> 4) * 8)];
    int i_col = w * 16 + (l & 15);
    float dsum = 0.f;
    #pragma unroll
    for (int fm = 0; fm < 4; fm++) {
        bf16x8 ae0 = *(const bf16x8*)&ek_s[swz128(fm * 16 + (l & 15), (l >> 4) * 8)];
        bf16x8 ae1 = *(const bf16x8*)&ek_s[swz128(fm * 16 + (l & 15), 32 + (l >> 4) * 8)];
        f32x4 z = {};
        z = __builtin_amdgcn_mfma_f32_16x16x32_bf16(ae0, bq0, z, 0, 0, 0);
        z = __builtin_amdgcn_mfma_f32_16x16x32_bf16(ae1, bq1, z, 0, 0, 0);
        bf16x4 pk;
        #pragma unroll
        for (int r = 0; r < 4; r++) {
            int m = fm * 16 + (l >> 4) * 4 + r;
            float v = (m <= i_col) ? z[r] : 0.f;
            pk[r] = (__bf16)v;
            dsum += (float)pk[r];
        }
        *(bf16x4*)&s_s[swz128(i_col, fm * 16 + (l >> 4) * 4)] = pk;
    }
    dsum += __shfl_xor(dsum, 16);
    dsum += __shfl_xor(dsum, 32);
    if (l < 16) denom_s[w * 16 + l] += dsum;

    // P2: O = S@V + Q@KVprev (same wave wrote its s_s rows -> no barrier needed)
    bf16x8 as0 = *(const bf16x8*)&s_s[swz128(w * 16 + (l & 15), (l >> 4) * 8)];
    bf16x8 as1 = *(const bf16x8*)&s_s[swz128(w * 16 + (l & 15), 32 + (l >> 4) * 8)];
    f32x4 oacc[4] = {};
    #pragma unroll
    for (int fn = 0; fn < 4; fn++) {
        const __bf16* vb = vTg + (size_t)(h * DH + fn * 16 + (l & 15)) * ROWS
                         + (size_t)b * SEQ + c * CHK + (l >> 4) * 8;   // FIX: + b*SEQ
        bf16x8 bv0 = *(const bf16x8*)vb;
        bf16x8 bv1 = *(const bf16x8*)(vb + 32);
        bf16x8 bk0 = *(const bf16x8*)&kvT_s[swz128(fn * 16 + (l & 15), (l >> 4) * 8)];
        bf16x8 bk1 = *(const bf16x8*)&kvT_s[swz128(fn * 16 + (l & 15), 32 + (l >> 4) * 8)];
        f32x4 z = oacc[fn];
        z = __builtin_amdgcn_mfma_f32_16x16x32_bf16(as0, bv0, z, 0, 0, 0);
        z = __builtin_amdgcn_mfma_f32_16x16x32_bf16(as1, bv1, z, 0, 0, 0);
        z = __builtin_amdgcn_mfma_f32_16x16x32_bf16(bq0, bk0, z, 0, 0, 0);
        z = __builtin_amdgcn_mfma_f32_16x16x32_bf16(bq1, bk1, z, 0, 0, 0);
        oacc[fn] = z;
    }
    // epilogue
    #pragma unroll
    for (int r = 0; r < 4; r++) {
        int i = w * 16 + (l >> 4) * 4 + r;
        float dinv = 1.0f / fmaxf(denom_s[i], 1e-3f);
        #pragma unroll
        for (int fn = 0; fn < 4; fn++)
            ag[(rowbase + i) * DIM + h * DH + fn * 16 + (l & 15)] = (__bf16)(oacc[fn][r] * dinv);
    }
}

// ---------------- launch --------------------------------------------------------
extern "C" void kernel_launch(void* const* d_in, const int* in_sizes, int n_in,
                              void* d_out, int out_size, void* d_ws, size_t ws_size,
                              hipStream_t stream) {
    (void)in_sizes; (void)n_in; (void)out_size; (void)ws_size;
    const float* x_in  = (const float*)d_in[0];
    const float* ln1_g = (const float*)d_in[1];
    const float* ln1_b = (const float*)d_in[2];
    const float* Wq    = (const float*)d_in[3];
    const float* Wk    = (const float*)d_in[4];
    const float* Wv    = (const float*)d_in[5];
    const float* Wo    = (const float*)d_in[6];
    const float* bo    = (const float*)d_in[7];
    const float* ln2_g = (const float*)d_in[8];
    const float* ln2_b = (const float*)d_in[9];
    const float* W1    = (const float*)d_in[10];
    const float* b1    = (const float*)d_in[11];
    const float* W2    = (const float*)d_in[12];
    const float* b2    = (const float*)d_in[13];

    float* x = (float*)d_out;
    const size_t MB = 1024 * 1024;
    char* base = (char*)d_ws;

    __bf16* xn  = (__bf16*)base;              // 8MB [0,8)
    __bf16* qgb = (__bf16*)(base + 8 * MB);   // 8MB [8,16)
    __bf16* kgb = (__bf16*)(base + 16 * MB);  // 8MB [16,24)
    __bf16* vTg = (__bf16*)(base + 24 * MB);  // 8MB [24,32)
    __bf16* a   = (__bf16*)(base + 32 * MB);  // 8MB [32,40)
    __bf16* h1  = (__bf16*)(base + 8 * MB);   // 32MB, aliases q/k/vT/a (dead in FF)
    float*  KVT = (float*)(base + 40 * MB);   // 16MB [40,56)
    float*  Ks  = (float*)(base + 56 * MB);   // 256KB
    __bf16* wqt = (__bf16*)(base + 57 * MB);  // 2MB
    __bf16* wkt = (__bf16*)(base + 59 * MB);  // 2MB
    __bf16* wvt = (__bf16*)(base + 61 * MB);  // 2MB
    __bf16* wot = (__bf16*)(base + 63 * MB);  // 2MB
    __bf16* w1t = (__bf16*)(base + 65 * MB);  // 8MB
    __bf16* w2t = (__bf16*)(base + 73 * MB);  // 8MB

    const size_t SZ = (size_t)ROWS * DIM;
    hipMemcpyAsync(x, x_in, SZ * sizeof(float), hipMemcpyDeviceToDevice, stream);

    dim3 gD(DIM / GBN, ROWS / GBM);    // (8, 32)  C = [ROWS x DIM]
    dim3 gVT(ROWS / GBN, DIM / GBM);   // (32, 8)  C = [DIM x ROWS] (v^T)
    dim3 gF1(FFD / GBN, ROWS / GBM);   // (32, 32)
    dim3 gTd(DIM / 32, DIM / 32);
    dim3 gT1(FFD / 32, DIM / 32);
    dim3 gT2(DIM / 32, FFD / 32);
    dim3 gScan(17, BB * NH);

    for (int l = 0; l < DEPTH; l++) {
        const float* wq = Wq + (size_t)l * DIM * DIM;
        const float* wk = Wk + (size_t)l * DIM * DIM;
        const float* wv = Wv + (size_t)l * DIM * DIM;
        const float* wo = Wo + (size_t)l * DIM * DIM;
        const float* w1 = W1 + (size_t)l * DIM * FFD;
        const float* w2 = W2 + (size_t)l * FFD * DIM;

        transpose_bf16<<<gTd, 256, 0, stream>>>(wq, wqt, DIM, DIM);
        transpose_bf16<<<gTd, 256, 0, stream>>>(wk, wkt, DIM, DIM);
        transpose_bf16<<<gTd, 256, 0, stream>>>(wv, wvt, DIM, DIM);
        transpose_bf16<<<gTd, 256, 0, stream>>>(wo, wot, DIM, DIM);
        transpose_bf16<<<gT1, 256, 0, stream>>>(w1, w1t, DIM, FFD);
        transpose_bf16<<<gT2, 256, 0, stream>>>(w2, w2t, FFD, DIM);

        // pre-norm attention block
        ln_kernel<<<ROWS, 256, 0, stream>>>(x, ln1_g + l * DIM, ln1_b + l * DIM, xn);
        gemm_bf16<0, 1><<<gD, 256, 0, stream>>>(xn, wqt, qgb, nullptr, nullptr, ROWS, DIM, DIM);
        gemm_bf16<0, 1><<<gD, 256, 0, stream>>>(xn, wkt, kgb, nullptr, nullptr, ROWS, DIM, DIM);
        // v^T = Wv^T @ xn^T via operand swap
        gemm_bf16<0, 1><<<gVT, 256, 0, stream>>>(wvt, xn, vTg, nullptr, nullptr, DIM, ROWS, DIM);
        attn_local_m<<<BB * NH * NCHK, 256, 0, stream>>>(kgb, vTg, KVT, Ks);
        attn_scan2<<<gScan, 256, 0, stream>>>(KVT, Ks);
        attn_out_m<<<BB * NH * NCHK, 256, 0, stream>>>(qgb, kgb, vTg, KVT, Ks, a);
        gemm_bf16<1, 0><<<gD, 256, 0, stream>>>(a, wot, x, bo + l * DIM, x, ROWS, DIM, DIM);

        // pre-norm FF block (q/k/vT/a dead -> h1 aliases)
        ln_kernel<<<ROWS, 256, 0, stream>>>(x, ln2_g + l * DIM, ln2_b + l * DIM, xn);
        gemm_bf16<2, 1><<<gF1, 256, 0, stream>>>(xn, w1t, h1, b1 + l * FFD, nullptr, ROWS, FFD, DIM);
        gemm_bf16<1, 0><<<gD, 256, 0, stream>>>(h1, w2t, x, b2 + l * DIM, x, ROWS, DIM, FFD);
    }
}

// Round 7
// 527.645 us; speedup vs baseline: 8.4648x; 1.1957x over previous
//
#include <hip/hip_runtime.h>
#include <cmath>

#define BB 2
#define SEQ 2048
#define DIM 1024
#define NH 16
#define DH 64
#define DEPTH 2
#define FFD 4096
#define CHK 64
#define NCHK (SEQ/CHK)      // 32
#define ROWS (BB*SEQ)       // 4096
#define QKP (3*DIM)         // fused qkv row pitch (3072)

typedef __bf16 bf16x8 __attribute__((ext_vector_type(8)));
typedef __bf16 bf16x4 __attribute__((ext_vector_type(4)));
typedef float  f32x4  __attribute__((ext_vector_type(4)));

#define AS1 __attribute__((address_space(1)))
#define AS3 __attribute__((address_space(3)))
#define FENCE() asm volatile("" ::: "memory")
#define WAIT_LGKM0() do { \
    asm volatile("s_waitcnt lgkmcnt(0)" ::: "memory"); \
    __builtin_amdgcn_sched_barrier(0); \
} while (0)

__device__ __forceinline__ float gelu_exact(float x) {
    return 0.5f * x * (1.0f + erff(x * 0.70710678118654752f));
}

// swizzled halfword index into a row-pitch-64hw (128B) bf16 tile:
// 16B-slot index ^= row&7  -> <=2-way bank conflicts on MFMA frag reads
__device__ __forceinline__ int swz128(int row, int col) {
    return row * 64 + (col ^ ((row & 7) << 3));
}

// T1: XCD-contiguous bijective block swizzle (m204) + width-4 column-group order
__device__ __forceinline__ void swz_tile(int bid, int NX, int NY, int& tx, int& ty) {
    int NB = NX * NY;
    int q = NB >> 3, r = NB & 7;
    int xcd = bid & 7, seq = bid >> 3;
    int start = (xcd < r) ? xcd * (q + 1) : r * (q + 1) + (xcd - r) * q;
    int wgid = start + seq;
    int g = 0, rem = wgid;
    int gw = (NX < 4) ? NX : 4;
    while (rem >= gw * NY) {
        rem -= gw * NY; g++;
        int left = NX - 4 * g;
        gw = left < 4 ? left : 4;
    }
    ty = rem / gw;
    tx = 4 * g + rem % gw;
}

// ---------------- LayerNorm ------------------------------------------------------
__global__ __launch_bounds__(256) void ln_kernel(
    const float* __restrict__ x, const float* __restrict__ g,
    const float* __restrict__ b, __bf16* __restrict__ out)
{
    int row = blockIdx.x;
    const float4* xr = (const float4*)(x + (size_t)row * DIM);
    int t = threadIdx.x;
    float4 v = xr[t];
    float s  = v.x + v.y + v.z + v.w;
    float ss = v.x*v.x + v.y*v.y + v.z*v.z + v.w*v.w;
    #pragma unroll
    for (int off = 32; off > 0; off >>= 1) {
        s  += __shfl_down(s, off);
        ss += __shfl_down(ss, off);
    }
    __shared__ float wsum[4], wsq[4], stats[2];
    int wid = t >> 6, lane = t & 63;
    if (lane == 0) { wsum[wid] = s; wsq[wid] = ss; }
    __syncthreads();
    if (t == 0) {
        float S  = wsum[0] + wsum[1] + wsum[2] + wsum[3];
        float SS = wsq[0] + wsq[1] + wsq[2] + wsq[3];
        float mean = S * (1.0f / DIM);
        float var  = SS * (1.0f / DIM) - mean * mean;
        stats[0] = mean;
        stats[1] = rsqrtf(var + 1e-5f);
    }
    __syncthreads();
    float mean = stats[0], rstd = stats[1];
    float4 gv = ((const float4*)g)[t];
    float4 bv = ((const float4*)b)[t];
    bf16x4 o;
    o[0] = (__bf16)((v.x - mean) * rstd * gv.x + bv.x);
    o[1] = (__bf16)((v.y - mean) * rstd * gv.y + bv.y);
    o[2] = (__bf16)((v.z - mean) * rstd * gv.z + bv.z);
    o[3] = (__bf16)((v.w - mean) * rstd * gv.w + bv.w);
    *(bf16x4*)(out + (size_t)row * DIM + t * 4) = o;
}

// ---------------- weight transpose + fp32 -> bf16: W[K][N] -> Wt[N][K] -----------
__global__ __launch_bounds__(256) void transpose_bf16(
    const float* __restrict__ W, __bf16* __restrict__ Wt, int K, int N)
{
    __shared__ float tile[32][33];
    int bx = blockIdx.x * 32;
    int by = blockIdx.y * 32;
    int tx = threadIdx.x & 31, ty = threadIdx.x >> 5;
    #pragma unroll
    for (int i = 0; i < 32; i += 8)
        tile[ty + i][tx] = W[(size_t)(by + ty + i) * N + bx + tx];
    __syncthreads();
    #pragma unroll
    for (int i = 0; i < 32; i += 8)
        Wt[(size_t)(bx + ty + i) * K + by + tx] = (__bf16)tile[tx][ty + i];
}

// ---------------- v transpose: qkv[:,2048+d] -> vT[d][row] -----------------------
__global__ __launch_bounds__(256) void transpose_v(
    const __bf16* __restrict__ qkv, __bf16* __restrict__ vT)
{
    __shared__ __bf16 tile[64 * 64];
    int bx = blockIdx.x;  // row tile (ROWS/64)
    int by = blockIdx.y;  // d tile (DIM/64)
    int t = threadIdx.x;
    int r0 = t >> 3, sl = t & 7;
    #pragma unroll
    for (int i = 0; i < 2; i++) {
        int row = i * 32 + r0;
        bf16x8 d = *(const bf16x8*)(qkv + (size_t)(bx * 64 + row) * QKP + 2 * DIM + by * 64 + sl * 8);
        *(bf16x8*)&tile[row * 64 + ((sl ^ (row & 7)) << 3)] = d;
    }
    __syncthreads();
    #pragma unroll
    for (int i = 0; i < 2; i++) {
        int d = i * 32 + r0;
        int rbase = sl * 8;
        bf16x8 o;
        #pragma unroll
        for (int j = 0; j < 8; j++) {
            int rr = rbase + j;
            o[j] = tile[rr * 64 + (((((d >> 3)) ^ (rr & 7)) << 3) | (d & 7))];
        }
        *(bf16x8*)(vT + (size_t)(by * 64 + d) * ROWS + bx * 64 + rbase) = o;
    }
}

// ---------------- gemm128: 128x128, m97 2-barrier structure + T1 swizzle ---------
#define GBM 128
#define GBN 128
#define GBK 64
template<int MODE, int OUTBF>
__global__ __launch_bounds__(256) void gemm_bf16(
    const __bf16* __restrict__ A, const __bf16* __restrict__ Bt,
    void* __restrict__ Cv, const float* __restrict__ bias,
    const float* __restrict__ res, int M, int N, int K, int NXT, int NYT)
{
    __shared__ __bf16 Als[GBM * GBK];
    __shared__ __bf16 Bls[GBN * GBK];
    int tx, ty;
    swz_tile(blockIdx.x, NXT, NYT, tx, ty);
    const int t = threadIdx.x;
    const int lane = t & 63;
    const int w = t >> 6;
    const int wr = w >> 1, wc = w & 1;
    const int bm = ty * GBM, bn = tx * GBN;

    f32x4 acc[4][4] = {};

    const int srow = w * 32 + (lane >> 3);
    const int scol = (lane & 7) * 8;
    const __bf16* gA = A + (size_t)(bm + srow) * K + scol;
    const __bf16* gB = Bt + (size_t)(bn + srow) * K + scol;
    __bf16* lA = Als + w * 2048;
    __bf16* lB = Bls + w * 2048;

    for (int k0 = 0; k0 < K; k0 += GBK) {
        #pragma unroll
        for (int i = 0; i < 4; i++) {
            __builtin_amdgcn_global_load_lds(
                (const AS1 void*)(gA + (size_t)(i * 8) * K + k0),
                (AS3 void*)(lA + i * 512), 16, 0, 0);
            __builtin_amdgcn_global_load_lds(
                (const AS1 void*)(gB + (size_t)(i * 8) * K + k0),
                (AS3 void*)(lB + i * 512), 16, 0, 0);
        }
        __syncthreads();
        #pragma unroll
        for (int kk = 0; kk < GBK; kk += 32) {
            bf16x8 af[4], bfr[4];
            #pragma unroll
            for (int m = 0; m < 4; m++)
                af[m] = *(const bf16x8*)&Als[(wr * 64 + m * 16 + (lane & 15)) * GBK + kk + (lane >> 4) * 8];
            #pragma unroll
            for (int n = 0; n < 4; n++)
                bfr[n] = *(const bf16x8*)&Bls[(wc * 64 + n * 16 + (lane & 15)) * GBK + kk + (lane >> 4) * 8];
            #pragma unroll
            for (int m = 0; m < 4; m++)
                #pragma unroll
                for (int n = 0; n < 4; n++)
                    acc[m][n] = __builtin_amdgcn_mfma_f32_16x16x32_bf16(af[m], bfr[n], acc[m][n], 0, 0, 0);
        }
        __syncthreads();
    }
    const int crow0 = bm + wr * 64 + (lane >> 4) * 4;
    const int ccol0 = bn + wc * 64 + (lane & 15);
    #pragma unroll
    for (int m = 0; m < 4; m++) {
        #pragma unroll
        for (int n = 0; n < 4; n++) {
            int col = ccol0 + n * 16;
            #pragma unroll
            for (int r = 0; r < 4; r++) {
                int row = crow0 + m * 16 + r;
                float v = acc[m][n][r];
                if (MODE == 1) v += res[(size_t)row * N + col] + bias[col];
                if (MODE == 2) v = gelu_exact(v + bias[col]);
                if (OUTBF) ((__bf16*)Cv)[(size_t)row * N + col] = (__bf16)v;
                else       ((float*)Cv)[(size_t)row * N + col] = v;
            }
        }
    }
}

// ---------------- gemm256: 256x256, BK=64, 8-wave, 8-phase counted-vmcnt ---------
// T2 swizzle: LDS linear dest, inverse-swizzled global source, swizzled ds_read.
// RACE FIX (m201 template, rule #18): every phase is now
//   {LD issue, STAGE issue, [vmcnt], FENCE, s_barrier, lgkmcnt(0)+sched_barrier,
//    MFMA cluster, FENCE, s_barrier}
// so all waves' ds_reads of a region complete before the closing barrier, and the
// overwriting STAGE of that region is always issued after that barrier.
#define TBM 256
#define TBN 256
#define TBK 64
template<int MODE, int OUTBF>
__global__ __launch_bounds__(512) void gemm256(
    const __bf16* __restrict__ A, const __bf16* __restrict__ Bt,
    void* __restrict__ Cv, const float* __restrict__ bias,
    const float* __restrict__ res, int M, int N, int K, int NXT, int NYT)
{
    __shared__ __bf16 lds[2][2][TBM * TBK];   // [buf][A/B][256*64] = 128 KiB
    int tx, ty;
    swz_tile(blockIdx.x, NXT, NYT, tx, ty);
    const int bm = ty * TBM, bn = tx * TBN;
    const int t = threadIdx.x;
    const int l = t & 63, w = t >> 6;
    const int wm = w >> 2, wn = w & 3;        // 2 x 4 waves
    const int lm = l & 15, lk = l >> 4;

    f32x4 acc[8][4] = {};
    const int nt = K / TBK;                   // K-tiles (even, >=2)
    const int NIT = nt / 2;

    // stage half-tile: buffer bf, mat (0=A,1=B), half hf, K-tile kt  (2 loads)
    auto STAGEH = [&](int bf, int mat, int hf, int kt) {
        const __bf16* src = mat ? Bt : A;
        int base = mat ? bn : bm;
        int k0 = kt * TBK;
        #pragma unroll
        for (int i = 0; i < 2; i++) {
            int row = hf * 128 + i * 64 + (t >> 3);
            int sl = (t & 7) ^ (row & 7);     // inverse swizzle on source
            __builtin_amdgcn_global_load_lds(
                (const AS1 void*)(src + (size_t)(base + row) * K + k0 + sl * 8),
                (AS3 void*)(&lds[bf][mat][(hf * 2 + i) * 4096 + w * 512]), 16, 0, 0);
        }
    };
    // A-group g (m = g*4..g*4+3), both kk  -> af[j*2+kk]
    auto LDA = [&](int bf, int g, bf16x8* af) {
        #pragma unroll
        for (int j = 0; j < 4; j++)
            #pragma unroll
            for (int kk = 0; kk < 2; kk++) {
                int row = wm * 128 + (g * 4 + j) * 16 + lm;
                int slot = kk * 4 + lk;
                af[j * 2 + kk] = *(const bf16x8*)&lds[bf][0][row * 64 + ((slot ^ (row & 7)) << 3)];
            }
    };
    // all B (n=0..3), both kk -> bfv[n*2+kk]
    auto LDB = [&](int bf, bf16x8* bfv) {
        #pragma unroll
        for (int n = 0; n < 4; n++)
            #pragma unroll
            for (int kk = 0; kk < 2; kk++) {
                int row = wn * 64 + n * 16 + lm;
                int slot = kk * 4 + lk;
                bfv[n * 2 + kk] = *(const bf16x8*)&lds[bf][1][row * 64 + ((slot ^ (row & 7)) << 3)];
            }
    };
    // 16 MFMA: A-group g x B-group ng (n = ng*2, ng*2+1)
    auto MM = [&](int g, int ng, bf16x8* af, bf16x8* bfv) {
        __builtin_amdgcn_s_setprio(1);
        #pragma unroll
        for (int j = 0; j < 4; j++)
            #pragma unroll
            for (int nn = 0; nn < 2; nn++)
                #pragma unroll
                for (int kk = 0; kk < 2; kk++)
                    acc[g * 4 + j][ng * 2 + nn] = __builtin_amdgcn_mfma_f32_16x16x32_bf16(
                        af[j * 2 + kk], bfv[(ng * 2 + nn) * 2 + kk], acc[g * 4 + j][ng * 2 + nn], 0, 0, 0);
        __builtin_amdgcn_s_setprio(0);
    };

    // ---- prologue: T0 fully, T1.{B0,B1,A0}; vmcnt(6) leaves T1's 3 halves in flight
    STAGEH(0, 0, 0, 0); STAGEH(0, 0, 1, 0); STAGEH(0, 1, 0, 0); STAGEH(0, 1, 1, 0);
    STAGEH(1, 1, 0, 1); STAGEH(1, 1, 1, 1); STAGEH(1, 0, 0, 1);
    asm volatile("s_waitcnt vmcnt(6)" ::: "memory");
    __builtin_amdgcn_s_barrier();

    bf16x8 aF[8], bF[8];
    for (int it = 0; it < NIT; it++) {
        int T2 = 2 * it + 2, U2 = 2 * it + 3;
        // Ph1: T:(A0 x B0); reads A-g0 + all B of buf0; stage U.A1
        LDA(0, 0, aF); LDB(0, bF);
        STAGEH(1, 0, 1, 2 * it + 1);
        FENCE(); __builtin_amdgcn_s_barrier();
        WAIT_LGKM0();
        MM(0, 0, aF, bF);
        FENCE(); __builtin_amdgcn_s_barrier();
        // Ph2: T:(A0 x B1); stage T'.B0
        if (T2 < nt) STAGEH(0, 1, 0, T2);
        FENCE(); __builtin_amdgcn_s_barrier();
        WAIT_LGKM0();
        MM(0, 1, aF, bF);
        FENCE(); __builtin_amdgcn_s_barrier();
        // Ph3: T:(A1 x B1); reads A-g1; stage T'.B1
        LDA(0, 1, aF);
        if (T2 < nt) STAGEH(0, 1, 1, T2);
        FENCE(); __builtin_amdgcn_s_barrier();
        WAIT_LGKM0();
        MM(1, 1, aF, bF);
        FENCE(); __builtin_amdgcn_s_barrier();
        // Ph4: T:(A1 x B0); stage T'.A0; counted vmcnt -> U fully landed
        if (T2 < nt) {
            STAGEH(0, 0, 0, T2);
            asm volatile("s_waitcnt vmcnt(6)" ::: "memory");
        } else {
            asm volatile("s_waitcnt vmcnt(0)" ::: "memory");
        }
        __builtin_amdgcn_s_barrier();
        WAIT_LGKM0();
        MM(1, 0, aF, bF);
        FENCE(); __builtin_amdgcn_s_barrier();
        // Ph5: U:(A0 x B0); reads buf1; stage T'.A1
        LDA(1, 0, aF); LDB(1, bF);
        if (T2 < nt) STAGEH(0, 0, 1, T2);
        FENCE(); __builtin_amdgcn_s_barrier();
        WAIT_LGKM0();
        MM(0, 0, aF, bF);
        FENCE(); __builtin_amdgcn_s_barrier();
        // Ph6: U:(A0 x B1); stage U'.B0
        if (U2 < nt) STAGEH(1, 1, 0, U2);
        FENCE(); __builtin_amdgcn_s_barrier();
        WAIT_LGKM0();
        MM(0, 1, aF, bF);
        FENCE(); __builtin_amdgcn_s_barrier();
        // Ph7: U:(A1 x B1); reads A-g1 buf1; stage U'.B1
        LDA(1, 1, aF);
        if (U2 < nt) STAGEH(1, 1, 1, U2);
        FENCE(); __builtin_amdgcn_s_barrier();
        WAIT_LGKM0();
        MM(1, 1, aF, bF);
        FENCE(); __builtin_amdgcn_s_barrier();
        // Ph8: U:(A1 x B0); stage U'.A0; counted vmcnt -> T' fully landed
        if (U2 < nt) {
            STAGEH(1, 0, 0, U2);
            asm volatile("s_waitcnt vmcnt(6)" ::: "memory");
        } else {
            asm volatile("s_waitcnt vmcnt(0)" ::: "memory");
        }
        __builtin_amdgcn_s_barrier();
        WAIT_LGKM0();
        MM(1, 0, aF, bF);
        FENCE(); __builtin_amdgcn_s_barrier();
    }

    // epilogue: C/D layout col=lane&15, row=(lane>>4)*4+r
    #pragma unroll
    for (int m = 0; m < 8; m++) {
        #pragma unroll
        for (int n = 0; n < 4; n++) {
            int col = bn + wn * 64 + n * 16 + lm;
            #pragma unroll
            for (int r = 0; r < 4; r++) {
                int row = bm + wm * 128 + m * 16 + lk * 4 + r;
                float v = acc[m][n][r];
                if (MODE == 1) v += res[(size_t)row * N + col] + bias[col];
                if (MODE == 2) v = gelu_exact(v + bias[col]);
                if (OUTBF) ((__bf16*)Cv)[(size_t)row * N + col] = (__bf16)v;
                else       ((float*)Cv)[(size_t)row * N + col] = v;
            }
        }
    }
}

// ---------------- attn kernel A: per-chunk KVT_c[e][d] = sum_m v[m][e]ek[m][d] --
__global__ __launch_bounds__(256) void attn_local_m(
    const __bf16* __restrict__ qkv, const __bf16* __restrict__ vTg,
    float* __restrict__ KVT, float* __restrict__ Ksum)
{
    int blk = blockIdx.x;
    int c = blk % NCHK, bh = blk / NCHK;
    int b = bh / NH, h = bh % NH;
    __shared__ __bf16 ek_s[64 * 64];
    __shared__ __bf16 ekT_s[64 * 68];
    __shared__ float ksum_p[4][64];
    int t = threadIdx.x, w = t >> 6, l = t & 63;
    size_t rowbase = (size_t)(b * SEQ + c * CHK);

    {
        int m = t >> 2, dq = t & 3;
        const __bf16* kr = qkv + (rowbase + m) * QKP + DIM + h * DH + dq * 16;
        bf16x8 k0 = *(const bf16x8*)kr;
        bf16x8 k1 = *(const bf16x8*)(kr + 8);
        bf16x8 e0, e1;
        #pragma unroll
        for (int j = 0; j < 8; j++) {
            e0[j] = (__bf16)__expf((float)k0[j]);
            e1[j] = (__bf16)__expf((float)k1[j]);
        }
        *(bf16x8*)&ek_s[swz128(m, dq * 16)] = e0;
        *(bf16x8*)&ek_s[swz128(m, dq * 16 + 8)] = e1;
    }
    __syncthreads();
    {
        float kacc = 0.f;
        #pragma unroll
        for (int g = 0; g < 4; g++) {
            bf16x4 pk;
            #pragma unroll
            for (int j = 0; j < 4; j++) {
                __bf16 e = ek_s[swz128(w * 16 + g * 4 + j, l)];
                pk[j] = e;
                kacc += (float)e;
            }
            *(bf16x4*)&ekT_s[l * 68 + w * 16 + g * 4] = pk;
        }
        ksum_p[w][l] = kacc;
    }
    __syncthreads();
    f32x4 acc[4] = {};
    const __bf16* vbase = vTg + (size_t)(h * DH + w * 16 + (l & 15)) * ROWS
                        + (size_t)b * SEQ + c * CHK + (l >> 4) * 8;
    bf16x8 a0 = *(const bf16x8*)vbase;
    bf16x8 a1 = *(const bf16x8*)(vbase + 32);
    #pragma unroll
    for (int fn = 0; fn < 4; fn++) {
        int rbase = (fn * 16 + (l & 15)) * 68 + (l >> 4) * 8;
        bf16x4 b0a = *(const bf16x4*)&ekT_s[rbase];
        bf16x4 b0b = *(const bf16x4*)&ekT_s[rbase + 4];
        bf16x4 b1a = *(const bf16x4*)&ekT_s[rbase + 32];
        bf16x4 b1b = *(const bf16x4*)&ekT_s[rbase + 36];
        bf16x8 b0, b1;
        #pragma unroll
        for (int j = 0; j < 4; j++) {
            b0[j] = b0a[j]; b0[j + 4] = b0b[j];
            b1[j] = b1a[j]; b1[j + 4] = b1b[j];
        }
        acc[fn] = __builtin_amdgcn_mfma_f32_16x16x32_bf16(a0, b0, acc[fn], 0, 0, 0);
        acc[fn] = __builtin_amdgcn_mfma_f32_16x16x32_bf16(a1, b1, acc[fn], 0, 0, 0);
    }
    float* kvout = KVT + (size_t)(bh * NCHK + c) * (DH * DH);
    #pragma unroll
    for (int fn = 0; fn < 4; fn++)
        #pragma unroll
        for (int r = 0; r < 4; r++)
            kvout[(w * 16 + (l >> 4) * 4 + r) * DH + fn * 16 + (l & 15)] = acc[fn][r];
    if (t < 64) {
        float s = ksum_p[0][t] + ksum_p[1][t] + ksum_p[2][t] + ksum_p[3][t];
        Ksum[(size_t)(bh * NCHK + c) * DH + t] = s;
    }
}

// ---------------- attn kernel B: parallel exclusive prefix over chunks ----------
__global__ __launch_bounds__(256) void attn_scan2(
    float* __restrict__ KV, float* __restrict__ Ksum)
{
    int bh = blockIdx.y;
    int bx = blockIdx.x;
    int t = threadIdx.x;
    if (bx < 16) {
        int elem = bx * 256 + t;
        float run = 0.f;
        for (int c = 0; c < NCHK; c++) {
            float* p = KV + ((size_t)(bh * NCHK + c)) * (DH * DH) + elem;
            float tmp = *p;
            *p = run;
            run += tmp;
        }
    } else if (t < DH) {
        float run = 0.f;
        for (int c = 0; c < NCHK; c++) {
            float* p = Ksum + ((size_t)(bh * NCHK + c)) * DH + t;
            float tmp = *p;
            *p = run;
            run += tmp;
        }
    }
}

// ---------------- attn kernel C: per-chunk output via MFMA ----------------------
__global__ __launch_bounds__(256) void attn_out_m(
    const __bf16* __restrict__ qkv, const __bf16* __restrict__ vTg,
    const float* __restrict__ KVT, const float* __restrict__ Ksum,
    __bf16* __restrict__ ag)
{
    int blk = blockIdx.x;
    int c = blk % NCHK, bh = blk / NCHK;
    int b = bh / NH, h = bh % NH;
    __shared__ __bf16 q_s[64 * 64];
    __shared__ __bf16 ek_s[64 * 64];
    __shared__ __bf16 s_s[64 * 64];
    __shared__ __bf16 kvT_s[64 * 64];
    __shared__ float denom_s[64];
    int t = threadIdx.x, w = t >> 6, l = t & 63;
    size_t rowbase = (size_t)(b * SEQ + c * CHK);

    {
        int i = t >> 2, dq = t & 3;
        const __bf16* qr = qkv + (rowbase + i) * QKP + h * DH + dq * 16;
        bf16x8 q0 = *(const bf16x8*)qr, q1 = *(const bf16x8*)(qr + 8);
        float qf[16];
        #pragma unroll
        for (int j = 0; j < 8; j++) { qf[j] = (float)q0[j]; qf[8 + j] = (float)q1[j]; }
        float mx = qf[0];
        #pragma unroll
        for (int j = 1; j < 16; j++) mx = fmaxf(mx, qf[j]);
        mx = fmaxf(mx, __shfl_xor(mx, 1));
        mx = fmaxf(mx, __shfl_xor(mx, 2));
        float ss = 0.f;
        #pragma unroll
        for (int j = 0; j < 16; j++) { qf[j] = __expf(qf[j] - mx); ss += qf[j]; }
        ss += __shfl_xor(ss, 1);
        ss += __shfl_xor(ss, 2);
        float sc = 0.125f / ss;
        bf16x8 o0, o1;
        #pragma unroll
        for (int j = 0; j < 8; j++) {
            o0[j] = (__bf16)(qf[j] * sc);
            o1[j] = (__bf16)(qf[8 + j] * sc);
        }
        *(bf16x8*)&q_s[swz128(i, dq * 16)] = o0;
        *(bf16x8*)&q_s[swz128(i, dq * 16 + 8)] = o1;
        const float* kp = Ksum + (size_t)(bh * NCHK + c) * DH + dq * 16;
        float dk = 0.f;
        #pragma unroll
        for (int j = 0; j < 16; j++) dk += (qf[j] * sc) * kp[j];
        dk += __shfl_xor(dk, 1);
        dk += __shfl_xor(dk, 2);
        if (dq == 0) denom_s[i] = dk;
    }
    {
        int m = t >> 2, dq = t & 3;
        const __bf16* kr = qkv + (rowbase + m) * QKP + DIM + h * DH + dq * 16;
        bf16x8 k0 = *(const bf16x8*)kr, k1 = *(const bf16x8*)(kr + 8);
        bf16x8 e0, e1;
        #pragma unroll
        for (int j = 0; j < 8; j++) {
            e0[j] = (__bf16)__expf((float)k0[j]);
            e1[j] = (__bf16)__expf((float)k1[j]);
        }
        *(bf16x8*)&ek_s[swz128(m, dq * 16)] = e0;
        *(bf16x8*)&ek_s[swz128(m, dq * 16 + 8)] = e1;
    }
    {
        int e = t >> 2, dq = t & 3;
        const float* kvr = KVT + (size_t)(bh * NCHK + c) * (DH * DH) + e * DH + dq * 16;
        bf16x8 o0, o1;
        #pragma unroll
        for (int j = 0; j < 8; j++) { o0[j] = (__bf16)kvr[j]; o1[j] = (__bf16)kvr[8 + j]; }
        *(bf16x8*)&kvT_s[swz128(e, dq * 16)] = o0;
        *(bf16x8*)&kvT_s[swz128(e, dq * 16 + 8)] = o1;
    }
    __syncthreads();

    bf16x8 bq0 = *(const bf16x8*)&q_s[swz128(w * 16 + (l & 15), (l >> 4) * 8)];
    bf16x8 bq1 = *(const bf16x8*)&q_s[swz128(w * 16 + (l & 15), 32 + (l >> 4) * 8)];
    int i_col = w * 16 + (l & 15);
    float dsum = 0.f;
    #pragma unroll
    for (int fm = 0; fm < 4; fm++) {
        bf16x8 ae0 = *(const bf16x8*)&ek_s[swz128(fm * 16 + (l & 15), (l >> 4) * 8)];
        bf16x8 ae1 = *(const bf16x8*)&ek_s[swz128(fm * 16 + (l & 15), 32 + (l >> 4) * 8)];
        f32x4 z = {};
        z = __builtin_amdgcn_mfma_f32_16x16x32_bf16(ae0, bq0, z, 0, 0, 0);
        z = __builtin_amdgcn_mfma_f32_16x16x32_bf16(ae1, bq1, z, 0, 0, 0);
        bf16x4 pk;
        #pragma unroll
        for (int r = 0; r < 4; r++) {
            int m = fm * 16 + (l >> 4) * 4 + r;
            float v = (m <= i_col) ? z[r] : 0.f;
            pk[r] = (__bf16)v;
            dsum += (float)pk[r];
        }
        *(bf16x4*)&s_s[swz128(i_col, fm * 16 + (l >> 4) * 4)] = pk;
    }
    dsum += __shfl_xor(dsum, 16);
    dsum += __shfl_xor(dsum, 32);
    if (l < 16) denom_s[w * 16 + l] += dsum;

    bf16x8 as0 = *(const bf16x8*)&s_s[swz128(w * 16 + (l & 15), (l >> 4) * 8)];
    bf16x8 as1 = *(const bf16x8*)&s_s[swz128(w * 16 + (l & 15), 32 + (l >> 4) * 8)];
    f32x4 oacc[4] = {};
    #pragma unroll
    for (int fn = 0; fn < 4; fn++) {
        const __bf16* vb = vTg + (size_t)(h * DH + fn * 16 + (l & 15)) * ROWS
                         + (size_t)b * SEQ + c * CHK + (l >> 4) * 8;
        bf16x8 bv0 = *(const bf16x8*)vb;
        bf16x8 bv1 = *(const bf16x8*)(vb + 32);
        bf16x8 bk0 = *(const bf16x8*)&kvT_s[swz128(fn * 16 + (l & 15), (l >> 4) * 8)];
        bf16x8 bk1 = *(const bf16x8*)&kvT_s[swz128(fn * 16 + (l & 15), 32 + (l >> 4) * 8)];
        f32x4 z = oacc[fn];
        z = __builtin_amdgcn_mfma_f32_16x16x32_bf16(as0, bv0, z, 0, 0, 0);
        z = __builtin_amdgcn_mfma_f32_16x16x32_bf16(as1, bv1, z, 0, 0, 0);
        z = __builtin_amdgcn_mfma_f32_16x16x32_bf16(bq0, bk0, z, 0, 0, 0);
        z = __builtin_amdgcn_mfma_f32_16x16x32_bf16(bq1, bk1, z, 0, 0, 0);
        oacc[fn] = z;
    }
    #pragma unroll
    for (int r = 0; r < 4; r++) {
        int i = w * 16 + (l >> 4) * 4 + r;
        float dinv = 1.0f / fmaxf(denom_s[i], 1e-3f);
        #pragma unroll
        for (int fn = 0; fn < 4; fn++)
            ag[(rowbase + i) * DIM + h * DH + fn * 16 + (l & 15)] = (__bf16)(oacc[fn][r] * dinv);
    }
}

// ---------------- launch --------------------------------------------------------
extern "C" void kernel_launch(void* const* d_in, const int* in_sizes, int n_in,
                              void* d_out, int out_size, void* d_ws, size_t ws_size,
                              hipStream_t stream) {
    (void)in_sizes; (void)n_in; (void)out_size; (void)ws_size;
    const float* x_in  = (const float*)d_in[0];
    const float* ln1_g = (const float*)d_in[1];
    const float* ln1_b = (const float*)d_in[2];
    const float* Wq    = (const float*)d_in[3];
    const float* Wk    = (const float*)d_in[4];
    const float* Wv    = (const float*)d_in[5];
    const float* Wo    = (const float*)d_in[6];
    const float* bo    = (const float*)d_in[7];
    const float* ln2_g = (const float*)d_in[8];
    const float* ln2_b = (const float*)d_in[9];
    const float* W1    = (const float*)d_in[10];
    const float* b1    = (const float*)d_in[11];
    const float* W2    = (const float*)d_in[12];
    const float* b2    = (const float*)d_in[13];

    float* x = (float*)d_out;
    const size_t MB = 1024 * 1024;
    char* base = (char*)d_ws;

    __bf16* xn   = (__bf16*)base;              // 8MB  [0,8)
    __bf16* qkv  = (__bf16*)(base + 8 * MB);   // 24MB [8,32)
    __bf16* vTg  = (__bf16*)(base + 32 * MB);  // 8MB  [32,40)
    __bf16* h1   = (__bf16*)(base + 8 * MB);   // 32MB, aliases qkv+vT (dead in FF)
    __bf16* a    = (__bf16*)(base + 40 * MB);  // 8MB  [40,48)
    float*  KVT  = (float*)(base + 48 * MB);   // 16MB [48,64)
    float*  Ks   = (float*)(base + 64 * MB);   // 256KB
    __bf16* wqkt = (__bf16*)(base + 65 * MB);  // 6MB  [65,71) fused qkv weights^T
    __bf16* wot  = (__bf16*)(base + 71 * MB);  // 2MB
    __bf16* w1t  = (__bf16*)(base + 73 * MB);  // 8MB
    __bf16* w2t  = (__bf16*)(base + 81 * MB);  // 8MB

    const size_t SZ = (size_t)ROWS * DIM;
    hipMemcpyAsync(x, x_in, SZ * sizeof(float), hipMemcpyDeviceToDevice, stream);

    dim3 gTd(DIM / 32, DIM / 32);
    dim3 gT1(FFD / 32, DIM / 32);
    dim3 gT2(DIM / 32, FFD / 32);
    dim3 gScan(17, BB * NH);
    dim3 gTv(ROWS / 64, DIM / 64);

    for (int l = 0; l < DEPTH; l++) {
        const float* wq = Wq + (size_t)l * DIM * DIM;
        const float* wk = Wk + (size_t)l * DIM * DIM;
        const float* wv = Wv + (size_t)l * DIM * DIM;
        const float* wo = Wo + (size_t)l * DIM * DIM;
        const float* w1 = W1 + (size_t)l * DIM * FFD;
        const float* w2 = W2 + (size_t)l * FFD * DIM;

        transpose_bf16<<<gTd, 256, 0, stream>>>(wq, wqkt, DIM, DIM);
        transpose_bf16<<<gTd, 256, 0, stream>>>(wk, wqkt + (size_t)DIM * DIM, DIM, DIM);
        transpose_bf16<<<gTd, 256, 0, stream>>>(wv, wqkt + 2 * (size_t)DIM * DIM, DIM, DIM);
        transpose_bf16<<<gTd, 256, 0, stream>>>(wo, wot, DIM, DIM);
        transpose_bf16<<<gT1, 256, 0, stream>>>(w1, w1t, DIM, FFD);
        transpose_bf16<<<gT2, 256, 0, stream>>>(w2, w2t, FFD, DIM);

        // pre-norm attention block
        ln_kernel<<<ROWS, 256, 0, stream>>>(x, ln1_g + l * DIM, ln1_b + l * DIM, xn);
        // fused QKV: [4096 x 3072] = xn @ wqkv^T   (grid 12 x 16)
        gemm256<0, 1><<<12 * 16, 512, 0, stream>>>(xn, wqkt, qkv, nullptr, nullptr,
                                                   ROWS, QKP, DIM, 12, 16);
        transpose_v<<<gTv, 256, 0, stream>>>(qkv, vTg);
        attn_local_m<<<BB * NH * NCHK, 256, 0, stream>>>(qkv, vTg, KVT, Ks);
        attn_scan2<<<gScan, 256, 0, stream>>>(KVT, Ks);
        attn_out_m<<<BB * NH * NCHK, 256, 0, stream>>>(qkv, vTg, KVT, Ks, a);
        gemm_bf16<1, 0><<<8 * 32, 256, 0, stream>>>(a, wot, x, bo + l * DIM, x,
                                                    ROWS, DIM, DIM, 8, 32);

        // pre-norm FF block (qkv/vT dead -> h1 aliases)
        ln_kernel<<<ROWS, 256, 0, stream>>>(x, ln2_g + l * DIM, ln2_b + l * DIM, xn);
        gemm256<2, 1><<<16 * 16, 512, 0, stream>>>(xn, w1t, h1, b1 + l * FFD, nullptr,
                                                   ROWS, FFD, DIM, 16, 16);
        gemm_bf16<1, 0><<<8 * 32, 256, 0, stream>>>(h1, w2t, x, b2 + l * DIM, x,
                                                    ROWS, DIM, FFD, 8, 32);
    }
}

// Round 8
// 459.491 us; speedup vs baseline: 9.7203x; 1.1483x over previous
//
#include <hip/hip_runtime.h>
#include <cmath>

#define BB 2
#define SEQ 2048
#define DIM 1024
#define NH 16
#define DH 64
#define DEPTH 2
#define FFD 4096
#define CHK 64
#define NCHK (SEQ/CHK)      // 32
#define ROWS (BB*SEQ)       // 4096
#define QKP (3*DIM)         // fused qkv row pitch (3072)

typedef __bf16 bf16x8 __attribute__((ext_vector_type(8)));
typedef __bf16 bf16x4 __attribute__((ext_vector_type(4)));
typedef float  f32x4  __attribute__((ext_vector_type(4)));

#define AS1 __attribute__((address_space(1)))
#define AS3 __attribute__((address_space(3)))
#define FENCE() asm volatile("" ::: "memory")
#define WAIT_LGKM0() do { \
    asm volatile("s_waitcnt lgkmcnt(0)" ::: "memory"); \
    __builtin_amdgcn_sched_barrier(0); \
} while (0)

__device__ __forceinline__ float gelu_exact(float x) {
    return 0.5f * x * (1.0f + erff(x * 0.70710678118654752f));
}

// swizzled halfword index into a row-pitch-64hw (128B) bf16 tile
__device__ __forceinline__ int swz128(int row, int col) {
    return row * 64 + (col ^ ((row & 7) << 3));
}

// T1: XCD-contiguous bijective block swizzle (m204) + width-4 column-group order
__device__ __forceinline__ void swz_tile(int bid, int NX, int NY, int& tx, int& ty) {
    int NB = NX * NY;
    int q = NB >> 3, r = NB & 7;
    int xcd = bid & 7, seq = bid >> 3;
    int start = (xcd < r) ? xcd * (q + 1) : r * (q + 1) + (xcd - r) * q;
    int wgid = start + seq;
    int g = 0, rem = wgid;
    int gw = (NX < 4) ? NX : 4;
    while (rem >= gw * NY) {
        rem -= gw * NY; g++;
        int left = NX - 4 * g;
        gw = left < 4 ? left : 4;
    }
    ty = rem / gw;
    tx = 4 * g + rem % gw;
}

// ---------------- LayerNorm ------------------------------------------------------
__global__ __launch_bounds__(256) void ln_kernel(
    const float* __restrict__ x, const float* __restrict__ g,
    const float* __restrict__ b, __bf16* __restrict__ out)
{
    int row = blockIdx.x;
    const float4* xr = (const float4*)(x + (size_t)row * DIM);
    int t = threadIdx.x;
    float4 v = xr[t];
    float s  = v.x + v.y + v.z + v.w;
    float ss = v.x*v.x + v.y*v.y + v.z*v.z + v.w*v.w;
    #pragma unroll
    for (int off = 32; off > 0; off >>= 1) {
        s  += __shfl_down(s, off);
        ss += __shfl_down(ss, off);
    }
    __shared__ float wsum[4], wsq[4], stats[2];
    int wid = t >> 6, lane = t & 63;
    if (lane == 0) { wsum[wid] = s; wsq[wid] = ss; }
    __syncthreads();
    if (t == 0) {
        float S  = wsum[0] + wsum[1] + wsum[2] + wsum[3];
        float SS = wsq[0] + wsq[1] + wsq[2] + wsq[3];
        float mean = S * (1.0f / DIM);
        float var  = SS * (1.0f / DIM) - mean * mean;
        stats[0] = mean;
        stats[1] = rsqrtf(var + 1e-5f);
    }
    __syncthreads();
    float mean = stats[0], rstd = stats[1];
    float4 gv = ((const float4*)g)[t];
    float4 bv = ((const float4*)b)[t];
    bf16x4 o;
    o[0] = (__bf16)((v.x - mean) * rstd * gv.x + bv.x);
    o[1] = (__bf16)((v.y - mean) * rstd * gv.y + bv.y);
    o[2] = (__bf16)((v.z - mean) * rstd * gv.z + bv.z);
    o[3] = (__bf16)((v.w - mean) * rstd * gv.w + bv.w);
    *(bf16x4*)(out + (size_t)row * DIM + t * 4) = o;
}

// ---------------- weight transpose + fp32 -> bf16: W[K][N] -> Wt[N][K] -----------
__global__ __launch_bounds__(256) void transpose_bf16(
    const float* __restrict__ W, __bf16* __restrict__ Wt, int K, int N)
{
    __shared__ float tile[32][33];
    int bx = blockIdx.x * 32;
    int by = blockIdx.y * 32;
    int tx = threadIdx.x & 31, ty = threadIdx.x >> 5;
    #pragma unroll
    for (int i = 0; i < 32; i += 8)
        tile[ty + i][tx] = W[(size_t)(by + ty + i) * N + bx + tx];
    __syncthreads();
    #pragma unroll
    for (int i = 0; i < 32; i += 8)
        Wt[(size_t)(bx + ty + i) * K + by + tx] = (__bf16)tile[tx][ty + i];
}

// ---------------- v transpose: qkv[:,2048+d] -> vT[d][row] -----------------------
__global__ __launch_bounds__(256) void transpose_v(
    const __bf16* __restrict__ qkv, __bf16* __restrict__ vT)
{
    __shared__ __bf16 tile[64 * 64];
    int bx = blockIdx.x;  // row tile (ROWS/64)
    int by = blockIdx.y;  // d tile (DIM/64)
    int t = threadIdx.x;
    int r0 = t >> 3, sl = t & 7;
    #pragma unroll
    for (int i = 0; i < 2; i++) {
        int row = i * 32 + r0;
        bf16x8 d = *(const bf16x8*)(qkv + (size_t)(bx * 64 + row) * QKP + 2 * DIM + by * 64 + sl * 8);
        *(bf16x8*)&tile[row * 64 + ((sl ^ (row & 7)) << 3)] = d;
    }
    __syncthreads();
    #pragma unroll
    for (int i = 0; i < 2; i++) {
        int d = i * 32 + r0;
        int rbase = sl * 8;
        bf16x8 o;
        #pragma unroll
        for (int j = 0; j < 8; j++) {
            int rr = rbase + j;
            o[j] = tile[rr * 64 + (((((d >> 3)) ^ (rr & 7)) << 3) | (d & 7))];
        }
        *(bf16x8*)(vT + (size_t)(by * 64 + d) * ROWS + bx * 64 + rbase) = o;
    }
}

// ---------------- gemm128: 128x128, m97 2-barrier structure + T1 swizzle ---------
#define GBM 128
#define GBN 128
#define GBK 64
template<int MODE, int OUTBF>
__global__ __launch_bounds__(256) void gemm_bf16(
    const __bf16* __restrict__ A, const __bf16* __restrict__ Bt,
    void* __restrict__ Cv, const float* __restrict__ bias,
    const float* __restrict__ res, int M, int N, int K, int NXT, int NYT)
{
    __shared__ __bf16 Als[GBM * GBK];
    __shared__ __bf16 Bls[GBN * GBK];
    int tx, ty;
    swz_tile(blockIdx.x, NXT, NYT, tx, ty);
    const int t = threadIdx.x;
    const int lane = t & 63;
    const int w = t >> 6;
    const int wr = w >> 1, wc = w & 1;
    const int bm = ty * GBM, bn = tx * GBN;

    f32x4 acc[4][4] = {};

    const int srow = w * 32 + (lane >> 3);
    const int scol = (lane & 7) * 8;
    const __bf16* gA = A + (size_t)(bm + srow) * K + scol;
    const __bf16* gB = Bt + (size_t)(bn + srow) * K + scol;
    __bf16* lA = Als + w * 2048;
    __bf16* lB = Bls + w * 2048;

    for (int k0 = 0; k0 < K; k0 += GBK) {
        #pragma unroll
        for (int i = 0; i < 4; i++) {
            __builtin_amdgcn_global_load_lds(
                (const AS1 void*)(gA + (size_t)(i * 8) * K + k0),
                (AS3 void*)(lA + i * 512), 16, 0, 0);
            __builtin_amdgcn_global_load_lds(
                (const AS1 void*)(gB + (size_t)(i * 8) * K + k0),
                (AS3 void*)(lB + i * 512), 16, 0, 0);
        }
        __syncthreads();
        #pragma unroll
        for (int kk = 0; kk < GBK; kk += 32) {
            bf16x8 af[4], bfr[4];
            #pragma unroll
            for (int m = 0; m < 4; m++)
                af[m] = *(const bf16x8*)&Als[(wr * 64 + m * 16 + (lane & 15)) * GBK + kk + (lane >> 4) * 8];
            #pragma unroll
            for (int n = 0; n < 4; n++)
                bfr[n] = *(const bf16x8*)&Bls[(wc * 64 + n * 16 + (lane & 15)) * GBK + kk + (lane >> 4) * 8];
            #pragma unroll
            for (int m = 0; m < 4; m++)
                #pragma unroll
                for (int n = 0; n < 4; n++)
                    acc[m][n] = __builtin_amdgcn_mfma_f32_16x16x32_bf16(af[m], bfr[n], acc[m][n], 0, 0, 0);
        }
        __syncthreads();
    }
    const int crow0 = bm + wr * 64 + (lane >> 4) * 4;
    const int ccol0 = bn + wc * 64 + (lane & 15);
    #pragma unroll
    for (int m = 0; m < 4; m++) {
        #pragma unroll
        for (int n = 0; n < 4; n++) {
            int col = ccol0 + n * 16;
            #pragma unroll
            for (int r = 0; r < 4; r++) {
                int row = crow0 + m * 16 + r;
                float v = acc[m][n][r];
                if (MODE == 1) v += res[(size_t)row * N + col] + bias[col];
                if (MODE == 2) v = gelu_exact(v + bias[col]);
                if (OUTBF) ((__bf16*)Cv)[(size_t)row * N + col] = (__bf16)v;
                else       ((float*)Cv)[(size_t)row * N + col] = v;
            }
        }
    }
}

// ---------------- gemm256: 256x256, BK=64, 8-wave, 8-phase counted-vmcnt ---------
// Kp = row pitch of A/Bt; K = extent of this block's K-walk (K == Kp when NS==1).
// NS>1: split-K — block group sk handles columns [sk*K, sk*K+K), writes its
// partial to Cv + sk*M*N elements.
#define TBM 256
#define TBN 256
#define TBK 64
template<int MODE, int OUTBF>
__global__ __launch_bounds__(512) void gemm256(
    const __bf16* __restrict__ A, const __bf16* __restrict__ Bt,
    void* __restrict__ Cv, const float* __restrict__ bias,
    const float* __restrict__ res, int M, int N, int K, int Kp,
    int NXT, int NYT, int NS)
{
    __shared__ __bf16 lds[2][2][TBM * TBK];   // [buf][A/B][256*64] = 128 KiB
    int nb = NXT * NYT;
    int sk = blockIdx.x / nb;
    int tx, ty;
    swz_tile(blockIdx.x % nb, NXT, NYT, tx, ty);
    if (NS > 1) {
        A  += (size_t)sk * K;
        Bt += (size_t)sk * K;
        Cv = (void*)((char*)Cv + (size_t)sk * M * N * (OUTBF ? 2 : 4));
    }
    const int bm = ty * TBM, bn = tx * TBN;
    const int t = threadIdx.x;
    const int l = t & 63, w = t >> 6;
    const int wm = w >> 2, wn = w & 3;        // 2 x 4 waves
    const int lm = l & 15, lk = l >> 4;

    f32x4 acc[8][4] = {};
    const int nt = K / TBK;                   // K-tiles (even, >=2)
    const int NIT = nt / 2;

    auto STAGEH = [&](int bf, int mat, int hf, int kt) {
        const __bf16* src = mat ? Bt : A;
        int base = mat ? bn : bm;
        int k0 = kt * TBK;
        #pragma unroll
        for (int i = 0; i < 2; i++) {
            int row = hf * 128 + i * 64 + (t >> 3);
            int sl = (t & 7) ^ (row & 7);     // inverse swizzle on source
            __builtin_amdgcn_global_load_lds(
                (const AS1 void*)(src + (size_t)(base + row) * Kp + k0 + sl * 8),
                (AS3 void*)(&lds[bf][mat][(hf * 2 + i) * 4096 + w * 512]), 16, 0, 0);
        }
    };
    auto LDA = [&](int bf, int g, bf16x8* af) {
        #pragma unroll
        for (int j = 0; j < 4; j++)
            #pragma unroll
            for (int kk = 0; kk < 2; kk++) {
                int row = wm * 128 + (g * 4 + j) * 16 + lm;
                int slot = kk * 4 + lk;
                af[j * 2 + kk] = *(const bf16x8*)&lds[bf][0][row * 64 + ((slot ^ (row & 7)) << 3)];
            }
    };
    auto LDB = [&](int bf, bf16x8* bfv) {
        #pragma unroll
        for (int n = 0; n < 4; n++)
            #pragma unroll
            for (int kk = 0; kk < 2; kk++) {
                int row = wn * 64 + n * 16 + lm;
                int slot = kk * 4 + lk;
                bfv[n * 2 + kk] = *(const bf16x8*)&lds[bf][1][row * 64 + ((slot ^ (row & 7)) << 3)];
            }
    };
    auto MM = [&](int g, int ng, bf16x8* af, bf16x8* bfv) {
        __builtin_amdgcn_s_setprio(1);
        #pragma unroll
        for (int j = 0; j < 4; j++)
            #pragma unroll
            for (int nn = 0; nn < 2; nn++)
                #pragma unroll
                for (int kk = 0; kk < 2; kk++)
                    acc[g * 4 + j][ng * 2 + nn] = __builtin_amdgcn_mfma_f32_16x16x32_bf16(
                        af[j * 2 + kk], bfv[(ng * 2 + nn) * 2 + kk], acc[g * 4 + j][ng * 2 + nn], 0, 0, 0);
        __builtin_amdgcn_s_setprio(0);
    };

    // ---- prologue: T0 fully, T1.{B0,B1,A0}; vmcnt(6) leaves T1's 3 halves in flight
    STAGEH(0, 0, 0, 0); STAGEH(0, 0, 1, 0); STAGEH(0, 1, 0, 0); STAGEH(0, 1, 1, 0);
    STAGEH(1, 1, 0, 1); STAGEH(1, 1, 1, 1); STAGEH(1, 0, 0, 1);
    asm volatile("s_waitcnt vmcnt(6)" ::: "memory");
    __builtin_amdgcn_s_barrier();

    bf16x8 aF[8], bF[8];
    for (int it = 0; it < NIT; it++) {
        int T2 = 2 * it + 2, U2 = 2 * it + 3;
        // Ph1: T:(A0 x B0); stage U.A1
        LDA(0, 0, aF); LDB(0, bF);
        STAGEH(1, 0, 1, 2 * it + 1);
        FENCE(); __builtin_amdgcn_s_barrier();
        WAIT_LGKM0();
        MM(0, 0, aF, bF);
        FENCE(); __builtin_amdgcn_s_barrier();
        // Ph2: T:(A0 x B1); stage T'.B0
        if (T2 < nt) STAGEH(0, 1, 0, T2);
        FENCE(); __builtin_amdgcn_s_barrier();
        WAIT_LGKM0();
        MM(0, 1, aF, bF);
        FENCE(); __builtin_amdgcn_s_barrier();
        // Ph3: T:(A1 x B1); stage T'.B1
        LDA(0, 1, aF);
        if (T2 < nt) STAGEH(0, 1, 1, T2);
        FENCE(); __builtin_amdgcn_s_barrier();
        WAIT_LGKM0();
        MM(1, 1, aF, bF);
        FENCE(); __builtin_amdgcn_s_barrier();
        // Ph4: T:(A1 x B0); stage T'.A0; counted vmcnt
        if (T2 < nt) {
            STAGEH(0, 0, 0, T2);
            asm volatile("s_waitcnt vmcnt(6)" ::: "memory");
        } else {
            asm volatile("s_waitcnt vmcnt(0)" ::: "memory");
        }
        __builtin_amdgcn_s_barrier();
        WAIT_LGKM0();
        MM(1, 0, aF, bF);
        FENCE(); __builtin_amdgcn_s_barrier();
        // Ph5: U:(A0 x B0); stage T'.A1
        LDA(1, 0, aF); LDB(1, bF);
        if (T2 < nt) STAGEH(0, 0, 1, T2);
        FENCE(); __builtin_amdgcn_s_barrier();
        WAIT_LGKM0();
        MM(0, 0, aF, bF);
        FENCE(); __builtin_amdgcn_s_barrier();
        // Ph6: U:(A0 x B1); stage U'.B0
        if (U2 < nt) STAGEH(1, 1, 0, U2);
        FENCE(); __builtin_amdgcn_s_barrier();
        WAIT_LGKM0();
        MM(0, 1, aF, bF);
        FENCE(); __builtin_amdgcn_s_barrier();
        // Ph7: U:(A1 x B1); stage U'.B1
        LDA(1, 1, aF);
        if (U2 < nt) STAGEH(1, 1, 1, U2);
        FENCE(); __builtin_amdgcn_s_barrier();
        WAIT_LGKM0();
        MM(1, 1, aF, bF);
        FENCE(); __builtin_amdgcn_s_barrier();
        // Ph8: U:(A1 x B0); stage U'.A0; counted vmcnt
        if (U2 < nt) {
            STAGEH(1, 0, 0, U2);
            asm volatile("s_waitcnt vmcnt(6)" ::: "memory");
        } else {
            asm volatile("s_waitcnt vmcnt(0)" ::: "memory");
        }
        __builtin_amdgcn_s_barrier();
        WAIT_LGKM0();
        MM(1, 0, aF, bF);
        FENCE(); __builtin_amdgcn_s_barrier();
    }

    // epilogue: C/D layout col=lane&15, row=(lane>>4)*4+r
    #pragma unroll
    for (int m = 0; m < 8; m++) {
        #pragma unroll
        for (int n = 0; n < 4; n++) {
            int col = bn + wn * 64 + n * 16 + lm;
            #pragma unroll
            for (int r = 0; r < 4; r++) {
                int row = bm + wm * 128 + m * 16 + lk * 4 + r;
                float v = acc[m][n][r];
                if (MODE == 1) v += res[(size_t)row * N + col] + bias[col];
                if (MODE == 2) v = gelu_exact(v + bias[col]);
                if (OUTBF) ((__bf16*)Cv)[(size_t)row * N + col] = (__bf16)v;
                else       ((float*)Cv)[(size_t)row * N + col] = v;
            }
        }
    }
}

// ---------------- reduce4: x += bias + sum of 4 bf16 split-K partials ------------
__global__ __launch_bounds__(256) void reduce4(
    const __bf16* __restrict__ parts, const float* __restrict__ bias,
    float* __restrict__ x)
{
    const size_t PS = (size_t)ROWS * DIM;     // elems per partial
    int idx = blockIdx.x * 256 + threadIdx.x; // float4 index, ROWS*DIM/4 total
    float4 xr = ((const float4*)x)[idx];
    float4 bv = ((const float4*)bias)[idx & (DIM / 4 - 1)];
    float o0 = xr.x + bv.x, o1 = xr.y + bv.y, o2 = xr.z + bv.z, o3 = xr.w + bv.w;
    #pragma unroll
    for (int s = 0; s < 4; s++) {
        bf16x4 p = *(const bf16x4*)(parts + s * PS + (size_t)idx * 4);
        o0 += (float)p[0]; o1 += (float)p[1]; o2 += (float)p[2]; o3 += (float)p[3];
    }
    float4 o = {o0, o1, o2, o3};
    ((float4*)x)[idx] = o;
}

// ---------------- attn kernel A: per-chunk KVT_c[e][d] = sum_m v[m][e]ek[m][d] --
__global__ __launch_bounds__(256) void attn_local_m(
    const __bf16* __restrict__ qkv, const __bf16* __restrict__ vTg,
    float* __restrict__ KVT, float* __restrict__ Ksum)
{
    int blk = blockIdx.x;
    int c = blk % NCHK, bh = blk / NCHK;
    int b = bh / NH, h = bh % NH;
    __shared__ __bf16 ek_s[64 * 64];
    __shared__ __bf16 ekT_s[64 * 68];
    __shared__ float ksum_p[4][64];
    int t = threadIdx.x, w = t >> 6, l = t & 63;
    size_t rowbase = (size_t)(b * SEQ + c * CHK);

    {
        int m = t >> 2, dq = t & 3;
        const __bf16* kr = qkv + (rowbase + m) * QKP + DIM + h * DH + dq * 16;
        bf16x8 k0 = *(const bf16x8*)kr;
        bf16x8 k1 = *(const bf16x8*)(kr + 8);
        bf16x8 e0, e1;
        #pragma unroll
        for (int j = 0; j < 8; j++) {
            e0[j] = (__bf16)__expf((float)k0[j]);
            e1[j] = (__bf16)__expf((float)k1[j]);
        }
        *(bf16x8*)&ek_s[swz128(m, dq * 16)] = e0;
        *(bf16x8*)&ek_s[swz128(m, dq * 16 + 8)] = e1;
    }
    __syncthreads();
    {
        float kacc = 0.f;
        #pragma unroll
        for (int g = 0; g < 4; g++) {
            bf16x4 pk;
            #pragma unroll
            for (int j = 0; j < 4; j++) {
                __bf16 e = ek_s[swz128(w * 16 + g * 4 + j, l)];
                pk[j] = e;
                kacc += (float)e;
            }
            *(bf16x4*)&ekT_s[l * 68 + w * 16 + g * 4] = pk;
        }
        ksum_p[w][l] = kacc;
    }
    __syncthreads();
    f32x4 acc[4] = {};
    const __bf16* vbase = vTg + (size_t)(h * DH + w * 16 + (l & 15)) * ROWS
                        + (size_t)b * SEQ + c * CHK + (l >> 4) * 8;
    bf16x8 a0 = *(const bf16x8*)vbase;
    bf16x8 a1 = *(const bf16x8*)(vbase + 32);
    #pragma unroll
    for (int fn = 0; fn < 4; fn++) {
        int rbase = (fn * 16 + (l & 15)) * 68 + (l >> 4) * 8;
        bf16x4 b0a = *(const bf16x4*)&ekT_s[rbase];
        bf16x4 b0b = *(const bf16x4*)&ekT_s[rbase + 4];
        bf16x4 b1a = *(const bf16x4*)&ekT_s[rbase + 32];
        bf16x4 b1b = *(const bf16x4*)&ekT_s[rbase + 36];
        bf16x8 b0, b1;
        #pragma unroll
        for (int j = 0; j < 4; j++) {
            b0[j] = b0a[j]; b0[j + 4] = b0b[j];
            b1[j] = b1a[j]; b1[j + 4] = b1b[j];
        }
        acc[fn] = __builtin_amdgcn_mfma_f32_16x16x32_bf16(a0, b0, acc[fn], 0, 0, 0);
        acc[fn] = __builtin_amdgcn_mfma_f32_16x16x32_bf16(a1, b1, acc[fn], 0, 0, 0);
    }
    float* kvout = KVT + (size_t)(bh * NCHK + c) * (DH * DH);
    #pragma unroll
    for (int fn = 0; fn < 4; fn++)
        #pragma unroll
        for (int r = 0; r < 4; r++)
            kvout[(w * 16 + (l >> 4) * 4 + r) * DH + fn * 16 + (l & 15)] = acc[fn][r];
    if (t < 64) {
        float s = ksum_p[0][t] + ksum_p[1][t] + ksum_p[2][t] + ksum_p[3][t];
        Ksum[(size_t)(bh * NCHK + c) * DH + t] = s;
    }
}

// ---------------- attn kernel B: parallel exclusive prefix over chunks ----------
__global__ __launch_bounds__(256) void attn_scan2(
    float* __restrict__ KV, float* __restrict__ Ksum)
{
    int bh = blockIdx.y;
    int bx = blockIdx.x;
    int t = threadIdx.x;
    if (bx < 16) {
        int elem = bx * 256 + t;
        float run = 0.f;
        for (int c = 0; c < NCHK; c++) {
            float* p = KV + ((size_t)(bh * NCHK + c)) * (DH * DH) + elem;
            float tmp = *p;
            *p = run;
            run += tmp;
        }
    } else if (t < DH) {
        float run = 0.f;
        for (int c = 0; c < NCHK; c++) {
            float* p = Ksum + ((size_t)(bh * NCHK + c)) * DH + t;
            float tmp = *p;
            *p = run;
            run += tmp;
        }
    }
}

// ---------------- attn kernel C: per-chunk output via MFMA ----------------------
__global__ __launch_bounds__(256) void attn_out_m(
    const __bf16* __restrict__ qkv, const __bf16* __restrict__ vTg,
    const float* __restrict__ KVT, const float* __restrict__ Ksum,
    __bf16* __restrict__ ag)
{
    int blk = blockIdx.x;
    int c = blk % NCHK, bh = blk / NCHK;
    int b = bh / NH, h = bh % NH;
    __shared__ __bf16 q_s[64 * 64];
    __shared__ __bf16 ek_s[64 * 64];
    __shared__ __bf16 s_s[64 * 64];
    __shared__ __bf16 kvT_s[64 * 64];
    __shared__ float denom_s[64];
    int t = threadIdx.x, w = t >> 6, l = t & 63;
    size_t rowbase = (size_t)(b * SEQ + c * CHK);

    {
        int i = t >> 2, dq = t & 3;
        const __bf16* qr = qkv + (rowbase + i) * QKP + h * DH + dq * 16;
        bf16x8 q0 = *(const bf16x8*)qr, q1 = *(const bf16x8*)(qr + 8);
        float qf[16];
        #pragma unroll
        for (int j = 0; j < 8; j++) { qf[j] = (float)q0[j]; qf[8 + j] = (float)q1[j]; }
        float mx = qf[0];
        #pragma unroll
        for (int j = 1; j < 16; j++) mx = fmaxf(mx, qf[j]);
        mx = fmaxf(mx, __shfl_xor(mx, 1));
        mx = fmaxf(mx, __shfl_xor(mx, 2));
        float ss = 0.f;
        #pragma unroll
        for (int j = 0; j < 16; j++) { qf[j] = __expf(qf[j] - mx); ss += qf[j]; }
        ss += __shfl_xor(ss, 1);
        ss += __shfl_xor(ss, 2);
        float sc = 0.125f / ss;
        bf16x8 o0, o1;
        #pragma unroll
        for (int j = 0; j < 8; j++) {
            o0[j] = (__bf16)(qf[j] * sc);
            o1[j] = (__bf16)(qf[8 + j] * sc);
        }
        *(bf16x8*)&q_s[swz128(i, dq * 16)] = o0;
        *(bf16x8*)&q_s[swz128(i, dq * 16 + 8)] = o1;
        const float* kp = Ksum + (size_t)(bh * NCHK + c) * DH + dq * 16;
        float dk = 0.f;
        #pragma unroll
        for (int j = 0; j < 16; j++) dk += (qf[j] * sc) * kp[j];
        dk += __shfl_xor(dk, 1);
        dk += __shfl_xor(dk, 2);
        if (dq == 0) denom_s[i] = dk;
    }
    {
        int m = t >> 2, dq = t & 3;
        const __bf16* kr = qkv + (rowbase + m) * QKP + DIM + h * DH + dq * 16;
        bf16x8 k0 = *(const bf16x8*)kr, k1 = *(const bf16x8*)(kr + 8);
        bf16x8 e0, e1;
        #pragma unroll
        for (int j = 0; j < 8; j++) {
            e0[j] = (__bf16)__expf((float)k0[j]);
            e1[j] = (__bf16)__expf((float)k1[j]);
        }
        *(bf16x8*)&ek_s[swz128(m, dq * 16)] = e0;
        *(bf16x8*)&ek_s[swz128(m, dq * 16 + 8)] = e1;
    }
    {
        int e = t >> 2, dq = t & 3;
        const float* kvr = KVT + (size_t)(bh * NCHK + c) * (DH * DH) + e * DH + dq * 16;
        bf16x8 o0, o1;
        #pragma unroll
        for (int j = 0; j < 8; j++) { o0[j] = (__bf16)kvr[j]; o1[j] = (__bf16)kvr[8 + j]; }
        *(bf16x8*)&kvT_s[swz128(e, dq * 16)] = o0;
        *(bf16x8*)&kvT_s[swz128(e, dq * 16 + 8)] = o1;
    }
    __syncthreads();

    bf16x8 bq0 = *(const bf16x8*)&q_s[swz128(w * 16 + (l & 15), (l >> 4) * 8)];
    bf16x8 bq1 = *(const bf16x8*)&q_s[swz128(w * 16 + (l & 15), 32 + (l >> 4) * 8)];
    int i_col = w * 16 + (l & 15);
    float dsum = 0.f;
    #pragma unroll
    for (int fm = 0; fm < 4; fm++) {
        bf16x8 ae0 = *(const bf16x8*)&ek_s[swz128(fm * 16 + (l & 15), (l >> 4) * 8)];
        bf16x8 ae1 = *(const bf16x8*)&ek_s[swz128(fm * 16 + (l & 15), 32 + (l >> 4) * 8)];
        f32x4 z = {};
        z = __builtin_amdgcn_mfma_f32_16x16x32_bf16(ae0, bq0, z, 0, 0, 0);
        z = __builtin_amdgcn_mfma_f32_16x16x32_bf16(ae1, bq1, z, 0, 0, 0);
        bf16x4 pk;
        #pragma unroll
        for (int r = 0; r < 4; r++) {
            int m = fm * 16 + (l >> 4) * 4 + r;
            float v = (m <= i_col) ? z[r] : 0.f;
            pk[r] = (__bf16)v;
            dsum += (float)pk[r];
        }
        *(bf16x4*)&s_s[swz128(i_col, fm * 16 + (l >> 4) * 4)] = pk;
    }
    dsum += __shfl_xor(dsum, 16);
    dsum += __shfl_xor(dsum, 32);
    if (l < 16) denom_s[w * 16 + l] += dsum;

    bf16x8 as0 = *(const bf16x8*)&s_s[swz128(w * 16 + (l & 15), (l >> 4) * 8)];
    bf16x8 as1 = *(const bf16x8*)&s_s[swz128(w * 16 + (l & 15), 32 + (l >> 4) * 8)];
    f32x4 oacc[4] = {};
    #pragma unroll
    for (int fn = 0; fn < 4; fn++) {
        const __bf16* vb = vTg + (size_t)(h * DH + fn * 16 + (l & 15)) * ROWS
                         + (size_t)b * SEQ + c * CHK + (l >> 4) * 8;
        bf16x8 bv0 = *(const bf16x8*)vb;
        bf16x8 bv1 = *(const bf16x8*)(vb + 32);
        bf16x8 bk0 = *(const bf16x8*)&kvT_s[swz128(fn * 16 + (l & 15), (l >> 4) * 8)];
        bf16x8 bk1 = *(const bf16x8*)&kvT_s[swz128(fn * 16 + (l & 15), 32 + (l >> 4) * 8)];
        f32x4 z = oacc[fn];
        z = __builtin_amdgcn_mfma_f32_16x16x32_bf16(as0, bv0, z, 0, 0, 0);
        z = __builtin_amdgcn_mfma_f32_16x16x32_bf16(as1, bv1, z, 0, 0, 0);
        z = __builtin_amdgcn_mfma_f32_16x16x32_bf16(bq0, bk0, z, 0, 0, 0);
        z = __builtin_amdgcn_mfma_f32_16x16x32_bf16(bq1, bk1, z, 0, 0, 0);
        oacc[fn] = z;
    }
    #pragma unroll
    for (int r = 0; r < 4; r++) {
        int i = w * 16 + (l >> 4) * 4 + r;
        float dinv = 1.0f / fmaxf(denom_s[i], 1e-3f);
        #pragma unroll
        for (int fn = 0; fn < 4; fn++)
            ag[(rowbase + i) * DIM + h * DH + fn * 16 + (l & 15)] = (__bf16)(oacc[fn][r] * dinv);
    }
}

// ---------------- launch --------------------------------------------------------
extern "C" void kernel_launch(void* const* d_in, const int* in_sizes, int n_in,
                              void* d_out, int out_size, void* d_ws, size_t ws_size,
                              hipStream_t stream) {
    (void)in_sizes; (void)n_in; (void)out_size; (void)ws_size;
    const float* x_in  = (const float*)d_in[0];
    const float* ln1_g = (const float*)d_in[1];
    const float* ln1_b = (const float*)d_in[2];
    const float* Wq    = (const float*)d_in[3];
    const float* Wk    = (const float*)d_in[4];
    const float* Wv    = (const float*)d_in[5];
    const float* Wo    = (const float*)d_in[6];
    const float* bo    = (const float*)d_in[7];
    const float* ln2_g = (const float*)d_in[8];
    const float* ln2_b = (const float*)d_in[9];
    const float* W1    = (const float*)d_in[10];
    const float* b1    = (const float*)d_in[11];
    const float* W2    = (const float*)d_in[12];
    const float* b2    = (const float*)d_in[13];

    float* x = (float*)d_out;
    const size_t MB = 1024 * 1024;
    char* base = (char*)d_ws;

    // layout (lifetimes):
    //  [0,24)  qkv   (attn)        | [0,32) h1 (FF)
    //  [24,32) vTg   (attn)        |
    //  [32,40) xn    (LN->GEMM A)  | [32,64) parts (FF2 split-K partials)
    //  [40,48) a     (attn out)    |
    //  [48,64) KVT   (attn)        |
    //  [64,..) Ks; [65,89) weights
    __bf16* qkv   = (__bf16*)base;
    __bf16* vTg   = (__bf16*)(base + 24 * MB);
    __bf16* h1    = (__bf16*)base;
    __bf16* xn    = (__bf16*)(base + 32 * MB);
    __bf16* parts = (__bf16*)(base + 32 * MB);
    __bf16* a     = (__bf16*)(base + 40 * MB);
    float*  KVT   = (float*)(base + 48 * MB);
    float*  Ks    = (float*)(base + 64 * MB);
    __bf16* wqkt  = (__bf16*)(base + 65 * MB);  // 6MB
    __bf16* wot   = (__bf16*)(base + 71 * MB);  // 2MB
    __bf16* w1t   = (__bf16*)(base + 73 * MB);  // 8MB
    __bf16* w2t   = (__bf16*)(base + 81 * MB);  // 8MB

    const size_t SZ = (size_t)ROWS * DIM;
    hipMemcpyAsync(x, x_in, SZ * sizeof(float), hipMemcpyDeviceToDevice, stream);

    dim3 gTd(DIM / 32, DIM / 32);
    dim3 gT1(FFD / 32, DIM / 32);
    dim3 gT2(DIM / 32, FFD / 32);
    dim3 gScan(17, BB * NH);
    dim3 gTv(ROWS / 64, DIM / 64);

    for (int l = 0; l < DEPTH; l++) {
        const float* wq = Wq + (size_t)l * DIM * DIM;
        const float* wk = Wk + (size_t)l * DIM * DIM;
        const float* wv = Wv + (size_t)l * DIM * DIM;
        const float* wo = Wo + (size_t)l * DIM * DIM;
        const float* w1 = W1 + (size_t)l * DIM * FFD;
        const float* w2 = W2 + (size_t)l * FFD * DIM;

        transpose_bf16<<<gTd, 256, 0, stream>>>(wq, wqkt, DIM, DIM);
        transpose_bf16<<<gTd, 256, 0, stream>>>(wk, wqkt + (size_t)DIM * DIM, DIM, DIM);
        transpose_bf16<<<gTd, 256, 0, stream>>>(wv, wqkt + 2 * (size_t)DIM * DIM, DIM, DIM);
        transpose_bf16<<<gTd, 256, 0, stream>>>(wo, wot, DIM, DIM);
        transpose_bf16<<<gT1, 256, 0, stream>>>(w1, w1t, DIM, FFD);
        transpose_bf16<<<gT2, 256, 0, stream>>>(w2, w2t, FFD, DIM);

        // pre-norm attention block
        ln_kernel<<<ROWS, 256, 0, stream>>>(x, ln1_g + l * DIM, ln1_b + l * DIM, xn);
        gemm256<0, 1><<<12 * 16, 512, 0, stream>>>(xn, wqkt, qkv, nullptr, nullptr,
                                                   ROWS, QKP, DIM, DIM, 12, 16, 1);
        transpose_v<<<gTv, 256, 0, stream>>>(qkv, vTg);
        attn_local_m<<<BB * NH * NCHK, 256, 0, stream>>>(qkv, vTg, KVT, Ks);
        attn_scan2<<<gScan, 256, 0, stream>>>(KVT, Ks);
        attn_out_m<<<BB * NH * NCHK, 256, 0, stream>>>(qkv, vTg, KVT, Ks, a);
        gemm_bf16<1, 0><<<8 * 32, 256, 0, stream>>>(a, wot, x, bo + l * DIM, x,
                                                    ROWS, DIM, DIM, 8, 32);

        // pre-norm FF block
        ln_kernel<<<ROWS, 256, 0, stream>>>(x, ln2_g + l * DIM, ln2_b + l * DIM, xn);
        gemm256<2, 1><<<16 * 16, 512, 0, stream>>>(xn, w1t, h1, b1 + l * FFD, nullptr,
                                                   ROWS, FFD, DIM, DIM, 16, 16, 1);
        // FF2: split-K 4 over K=4096 -> bf16 partials + fused reduce epilogue
        gemm256<0, 1><<<4 * 16 * 4, 512, 0, stream>>>(h1, w2t, parts, nullptr, nullptr,
                                                      ROWS, DIM, FFD / 4, FFD, 4, 16, 4);
        reduce4<<<ROWS * DIM / 4 / 256, 256, 0, stream>>>(parts, b2 + l * DIM, x);
    }
}

// Round 9
// 432.787 us; speedup vs baseline: 10.3201x; 1.0617x over previous
//
#include <hip/hip_runtime.h>
#include <cmath>

#define BB 2
#define SEQ 2048
#define DIM 1024
#define NH 16
#define DH 64
#define DEPTH 2
#define FFD 4096
#define CHK 64
#define NCHK (SEQ/CHK)      // 32
#define ROWS (BB*SEQ)       // 4096
#define QKP (3*DIM)         // fused qkv row pitch (3072)

typedef __bf16 bf16x8 __attribute__((ext_vector_type(8)));
typedef __bf16 bf16x4 __attribute__((ext_vector_type(4)));
typedef float  f32x4  __attribute__((ext_vector_type(4)));

#define AS1 __attribute__((address_space(1)))
#define AS3 __attribute__((address_space(3)))
#define FENCE() asm volatile("" ::: "memory")
#define WAIT_LGKM0_NOPIN() asm volatile("s_waitcnt lgkmcnt(0)" ::: "memory")

// tanh-form GELU: x * sigmoid(1.5957691(x + 0.044715 x^3)); |err| < 1e-3 vs exact
// (invisible under bf16 output rounding; ~9 VALU ops vs erff's ~35)
__device__ __forceinline__ float gelu_fast(float x) {
    float x3 = x * x * x;
    float y = 1.5957691216057308f * (x + 0.044715f * x3);
    return x * __builtin_amdgcn_rcpf(1.0f + __expf(-y));
}

// swizzled halfword index into a row-pitch-64hw (128B) bf16 tile
__device__ __forceinline__ int swz128(int row, int col) {
    return row * 64 + (col ^ ((row & 7) << 3));
}

// T1: XCD-contiguous bijective block swizzle (m204) + width-4 column-group order
__device__ __forceinline__ void swz_tile(int bid, int NX, int NY, int& tx, int& ty) {
    int NB = NX * NY;
    int q = NB >> 3, r = NB & 7;
    int xcd = bid & 7, seq = bid >> 3;
    int start = (xcd < r) ? xcd * (q + 1) : r * (q + 1) + (xcd - r) * q;
    int wgid = start + seq;
    int g = 0, rem = wgid;
    int gw = (NX < 4) ? NX : 4;
    while (rem >= gw * NY) {
        rem -= gw * NY; g++;
        int left = NX - 4 * g;
        gw = left < 4 ? left : 4;
    }
    ty = rem / gw;
    tx = 4 * g + rem % gw;
}

// ---------------- LayerNorm ------------------------------------------------------
__global__ __launch_bounds__(256) void ln_kernel(
    const float* __restrict__ x, const float* __restrict__ g,
    const float* __restrict__ b, __bf16* __restrict__ out)
{
    int row = blockIdx.x;
    const float4* xr = (const float4*)(x + (size_t)row * DIM);
    int t = threadIdx.x;
    float4 v = xr[t];
    float s  = v.x + v.y + v.z + v.w;
    float ss = v.x*v.x + v.y*v.y + v.z*v.z + v.w*v.w;
    #pragma unroll
    for (int off = 32; off > 0; off >>= 1) {
        s  += __shfl_down(s, off);
        ss += __shfl_down(ss, off);
    }
    __shared__ float wsum[4], wsq[4], stats[2];
    int wid = t >> 6, lane = t & 63;
    if (lane == 0) { wsum[wid] = s; wsq[wid] = ss; }
    __syncthreads();
    if (t == 0) {
        float S  = wsum[0] + wsum[1] + wsum[2] + wsum[3];
        float SS = wsq[0] + wsq[1] + wsq[2] + wsq[3];
        float mean = S * (1.0f / DIM);
        float var  = SS * (1.0f / DIM) - mean * mean;
        stats[0] = mean;
        stats[1] = rsqrtf(var + 1e-5f);
    }
    __syncthreads();
    float mean = stats[0], rstd = stats[1];
    float4 gv = ((const float4*)g)[t];
    float4 bv = ((const float4*)b)[t];
    bf16x4 o;
    o[0] = (__bf16)((v.x - mean) * rstd * gv.x + bv.x);
    o[1] = (__bf16)((v.y - mean) * rstd * gv.y + bv.y);
    o[2] = (__bf16)((v.z - mean) * rstd * gv.z + bv.z);
    o[3] = (__bf16)((v.w - mean) * rstd * gv.w + bv.w);
    *(bf16x4*)(out + (size_t)row * DIM + t * 4) = o;
}

// ---------------- weight transpose + fp32 -> bf16: W[K][N] -> Wt[N][K] -----------
__global__ __launch_bounds__(256) void transpose_bf16(
    const float* __restrict__ W, __bf16* __restrict__ Wt, int K, int N)
{
    __shared__ float tile[32][33];
    int bx = blockIdx.x * 32;
    int by = blockIdx.y * 32;
    int tx = threadIdx.x & 31, ty = threadIdx.x >> 5;
    #pragma unroll
    for (int i = 0; i < 32; i += 8)
        tile[ty + i][tx] = W[(size_t)(by + ty + i) * N + bx + tx];
    __syncthreads();
    #pragma unroll
    for (int i = 0; i < 32; i += 8)
        Wt[(size_t)(bx + ty + i) * K + by + tx] = (__bf16)tile[tx][ty + i];
}

// ---------------- v transpose: qkv[:,2048+d] -> vT[d][row] -----------------------
__global__ __launch_bounds__(256) void transpose_v(
    const __bf16* __restrict__ qkv, __bf16* __restrict__ vT)
{
    __shared__ __bf16 tile[64 * 64];
    int bx = blockIdx.x;  // row tile (ROWS/64)
    int by = blockIdx.y;  // d tile (DIM/64)
    int t = threadIdx.x;
    int r0 = t >> 3, sl = t & 7;
    #pragma unroll
    for (int i = 0; i < 2; i++) {
        int row = i * 32 + r0;
        bf16x8 d = *(const bf16x8*)(qkv + (size_t)(bx * 64 + row) * QKP + 2 * DIM + by * 64 + sl * 8);
        *(bf16x8*)&tile[row * 64 + ((sl ^ (row & 7)) << 3)] = d;
    }
    __syncthreads();
    #pragma unroll
    for (int i = 0; i < 2; i++) {
        int d = i * 32 + r0;
        int rbase = sl * 8;
        bf16x8 o;
        #pragma unroll
        for (int j = 0; j < 8; j++) {
            int rr = rbase + j;
            o[j] = tile[rr * 64 + (((((d >> 3)) ^ (rr & 7)) << 3) | (d & 7))];
        }
        *(bf16x8*)(vT + (size_t)(by * 64 + d) * ROWS + bx * 64 + rbase) = o;
    }
}

// ---------------- gemm128: 128x128, m97 2-barrier structure + T1 swizzle ---------
#define GBM 128
#define GBN 128
#define GBK 64
template<int MODE, int OUTBF>
__global__ __launch_bounds__(256) void gemm_bf16(
    const __bf16* __restrict__ A, const __bf16* __restrict__ Bt,
    void* __restrict__ Cv, const float* __restrict__ bias,
    const float* __restrict__ res, int M, int N, int K, int NXT, int NYT)
{
    __shared__ __bf16 Als[GBM * GBK];
    __shared__ __bf16 Bls[GBN * GBK];
    int tx, ty;
    swz_tile(blockIdx.x, NXT, NYT, tx, ty);
    const int t = threadIdx.x;
    const int lane = t & 63;
    const int w = t >> 6;
    const int wr = w >> 1, wc = w & 1;
    const int bm = ty * GBM, bn = tx * GBN;

    f32x4 acc[4][4] = {};

    const int srow = w * 32 + (lane >> 3);
    const int scol = (lane & 7) * 8;
    const __bf16* gA = A + (size_t)(bm + srow) * K + scol;
    const __bf16* gB = Bt + (size_t)(bn + srow) * K + scol;
    __bf16* lA = Als + w * 2048;
    __bf16* lB = Bls + w * 2048;

    for (int k0 = 0; k0 < K; k0 += GBK) {
        #pragma unroll
        for (int i = 0; i < 4; i++) {
            __builtin_amdgcn_global_load_lds(
                (const AS1 void*)(gA + (size_t)(i * 8) * K + k0),
                (AS3 void*)(lA + i * 512), 16, 0, 0);
            __builtin_amdgcn_global_load_lds(
                (const AS1 void*)(gB + (size_t)(i * 8) * K + k0),
                (AS3 void*)(lB + i * 512), 16, 0, 0);
        }
        __syncthreads();
        #pragma unroll
        for (int kk = 0; kk < GBK; kk += 32) {
            bf16x8 af[4], bfr[4];
            #pragma unroll
            for (int m = 0; m < 4; m++)
                af[m] = *(const bf16x8*)&Als[(wr * 64 + m * 16 + (lane & 15)) * GBK + kk + (lane >> 4) * 8];
            #pragma unroll
            for (int n = 0; n < 4; n++)
                bfr[n] = *(const bf16x8*)&Bls[(wc * 64 + n * 16 + (lane & 15)) * GBK + kk + (lane >> 4) * 8];
            #pragma unroll
            for (int m = 0; m < 4; m++)
                #pragma unroll
                for (int n = 0; n < 4; n++)
                    acc[m][n] = __builtin_amdgcn_mfma_f32_16x16x32_bf16(af[m], bfr[n], acc[m][n], 0, 0, 0);
        }
        __syncthreads();
    }
    const int crow0 = bm + wr * 64 + (lane >> 4) * 4;
    const int ccol0 = bn + wc * 64 + (lane & 15);
    #pragma unroll
    for (int m = 0; m < 4; m++) {
        #pragma unroll
        for (int n = 0; n < 4; n++) {
            int col = ccol0 + n * 16;
            #pragma unroll
            for (int r = 0; r < 4; r++) {
                int row = crow0 + m * 16 + r;
                float v = acc[m][n][r];
                if (MODE == 1) v += res[(size_t)row * N + col] + bias[col];
                if (MODE == 2) v = gelu_fast(v + bias[col]);
                if (OUTBF) ((__bf16*)Cv)[(size_t)row * N + col] = (__bf16)v;
                else       ((float*)Cv)[(size_t)row * N + col] = v;
            }
        }
    }
}

// ---------------- gemm256: 256x256, BK=64, 8-wave, 8-phase counted-vmcnt ---------
// Kp = row pitch of A/Bt; K = extent of this block's K-walk. NS>1: split-K.
// Scheduling (m141 lesson): NO sched_barrier / NO per-phase lgkm drain — compiler
// tracks ds_read->MFMA deps. Only Ph1/Ph5 need an explicit lgkmcnt(0) BEFORE the
// closing barrier (bF[4..7] are consumed in later phases, so the compiler's own
// waits don't cover them before the region is re-staged in Ph2/Ph6).
#define TBM 256
#define TBN 256
#define TBK 64
template<int MODE, int OUTBF>
__global__ __launch_bounds__(512) void gemm256(
    const __bf16* __restrict__ A, const __bf16* __restrict__ Bt,
    void* __restrict__ Cv, const float* __restrict__ bias,
    const float* __restrict__ res, int M, int N, int K, int Kp,
    int NXT, int NYT, int NS)
{
    __shared__ __bf16 lds[2][2][TBM * TBK];   // [buf][A/B][256*64] = 128 KiB
    int nb = NXT * NYT;
    int sk = blockIdx.x / nb;
    int tx, ty;
    swz_tile(blockIdx.x % nb, NXT, NYT, tx, ty);
    if (NS > 1) {
        A  += (size_t)sk * K;
        Bt += (size_t)sk * K;
        Cv = (void*)((char*)Cv + (size_t)sk * M * N * (OUTBF ? 2 : 4));
    }
    const int bm = ty * TBM, bn = tx * TBN;
    const int t = threadIdx.x;
    const int l = t & 63, w = t >> 6;
    const int wm = w >> 2, wn = w & 3;        // 2 x 4 waves
    const int lm = l & 15, lk = l >> 4;

    f32x4 acc[8][4] = {};
    const int nt = K / TBK;                   // K-tiles (even, >=2)
    const int NIT = nt / 2;

    auto STAGEH = [&](int bf, int mat, int hf, int kt) {
        const __bf16* src = mat ? Bt : A;
        int base = mat ? bn : bm;
        int k0 = kt * TBK;
        #pragma unroll
        for (int i = 0; i < 2; i++) {
            int row = hf * 128 + i * 64 + (t >> 3);
            int sl = (t & 7) ^ (row & 7);     // inverse swizzle on source
            __builtin_amdgcn_global_load_lds(
                (const AS1 void*)(src + (size_t)(base + row) * Kp + k0 + sl * 8),
                (AS3 void*)(&lds[bf][mat][(hf * 2 + i) * 4096 + w * 512]), 16, 0, 0);
        }
    };
    auto LDA = [&](int bf, int g, bf16x8* af) {
        #pragma unroll
        for (int j = 0; j < 4; j++)
            #pragma unroll
            for (int kk = 0; kk < 2; kk++) {
                int row = wm * 128 + (g * 4 + j) * 16 + lm;
                int slot = kk * 4 + lk;
                af[j * 2 + kk] = *(const bf16x8*)&lds[bf][0][row * 64 + ((slot ^ (row & 7)) << 3)];
            }
    };
    auto LDB = [&](int bf, bf16x8* bfv) {
        #pragma unroll
        for (int n = 0; n < 4; n++)
            #pragma unroll
            for (int kk = 0; kk < 2; kk++) {
                int row = wn * 64 + n * 16 + lm;
                int slot = kk * 4 + lk;
                bfv[n * 2 + kk] = *(const bf16x8*)&lds[bf][1][row * 64 + ((slot ^ (row & 7)) << 3)];
            }
    };
    auto MM = [&](int g, int ng, bf16x8* af, bf16x8* bfv) {
        __builtin_amdgcn_s_setprio(1);
        #pragma unroll
        for (int j = 0; j < 4; j++)
            #pragma unroll
            for (int nn = 0; nn < 2; nn++)
                #pragma unroll
                for (int kk = 0; kk < 2; kk++)
                    acc[g * 4 + j][ng * 2 + nn] = __builtin_amdgcn_mfma_f32_16x16x32_bf16(
                        af[j * 2 + kk], bfv[(ng * 2 + nn) * 2 + kk], acc[g * 4 + j][ng * 2 + nn], 0, 0, 0);
        __builtin_amdgcn_s_setprio(0);
    };

    // ---- prologue: T0 fully, T1.{B0,B1,A0}; vmcnt(6) leaves T1's 3 halves in flight
    STAGEH(0, 0, 0, 0); STAGEH(0, 0, 1, 0); STAGEH(0, 1, 0, 0); STAGEH(0, 1, 1, 0);
    STAGEH(1, 1, 0, 1); STAGEH(1, 1, 1, 1); STAGEH(1, 0, 0, 1);
    asm volatile("s_waitcnt vmcnt(6)" ::: "memory");
    __builtin_amdgcn_s_barrier();

    bf16x8 aF[8], bF[8];
    for (int it = 0; it < NIT; it++) {
        int T2 = 2 * it + 2, U2 = 2 * it + 3;
        // Ph1: T:(A0 x B0); stage U.A1
        LDA(0, 0, aF); LDB(0, bF);
        STAGEH(1, 0, 1, 2 * it + 1);
        FENCE(); __builtin_amdgcn_s_barrier();
        MM(0, 0, aF, bF);
        WAIT_LGKM0_NOPIN();            // bF[4..7] consumed Ph2-4: drain before close
        FENCE(); __builtin_amdgcn_s_barrier();
        // Ph2: T:(A0 x B1); stage T'.B0
        if (T2 < nt) STAGEH(0, 1, 0, T2);
        FENCE(); __builtin_amdgcn_s_barrier();
        MM(0, 1, aF, bF);
        FENCE(); __builtin_amdgcn_s_barrier();
        // Ph3: T:(A1 x B1); stage T'.B1
        LDA(0, 1, aF);
        if (T2 < nt) STAGEH(0, 1, 1, T2);
        FENCE(); __builtin_amdgcn_s_barrier();
        MM(1, 1, aF, bF);
        FENCE(); __builtin_amdgcn_s_barrier();
        // Ph4: T:(A1 x B0); stage T'.A0; counted vmcnt
        if (T2 < nt) {
            STAGEH(0, 0, 0, T2);
            asm volatile("s_waitcnt vmcnt(6)" ::: "memory");
        } else {
            asm volatile("s_waitcnt vmcnt(0)" ::: "memory");
        }
        __builtin_amdgcn_s_barrier();
        MM(1, 0, aF, bF);
        FENCE(); __builtin_amdgcn_s_barrier();
        // Ph5: U:(A0 x B0); stage T'.A1
        LDA(1, 0, aF); LDB(1, bF);
        if (T2 < nt) STAGEH(0, 0, 1, T2);
        FENCE(); __builtin_amdgcn_s_barrier();
        MM(0, 0, aF, bF);
        WAIT_LGKM0_NOPIN();            // bF[4..7] consumed Ph6-8: drain before close
        FENCE(); __builtin_amdgcn_s_barrier();
        // Ph6: U:(A0 x B1); stage U'.B0
        if (U2 < nt) STAGEH(1, 1, 0, U2);
        FENCE(); __builtin_amdgcn_s_barrier();
        MM(0, 1, aF, bF);
        FENCE(); __builtin_amdgcn_s_barrier();
        // Ph7: U:(A1 x B1); stage U'.B1
        LDA(1, 1, aF);
        if (U2 < nt) STAGEH(1, 1, 1, U2);
        FENCE(); __builtin_amdgcn_s_barrier();
        MM(1, 1, aF, bF);
        FENCE(); __builtin_amdgcn_s_barrier();
        // Ph8: U:(A1 x B0); stage U'.A0; counted vmcnt
        if (U2 < nt) {
            STAGEH(1, 0, 0, U2);
            asm volatile("s_waitcnt vmcnt(6)" ::: "memory");
        } else {
            asm volatile("s_waitcnt vmcnt(0)" ::: "memory");
        }
        __builtin_amdgcn_s_barrier();
        MM(1, 0, aF, bF);
        FENCE(); __builtin_amdgcn_s_barrier();
    }

    // epilogue: C/D layout col=lane&15, row=(lane>>4)*4+r
    #pragma unroll
    for (int m = 0; m < 8; m++) {
        #pragma unroll
        for (int n = 0; n < 4; n++) {
            int col = bn + wn * 64 + n * 16 + lm;
            #pragma unroll
            for (int r = 0; r < 4; r++) {
                int row = bm + wm * 128 + m * 16 + lk * 4 + r;
                float v = acc[m][n][r];
                if (MODE == 1) v += res[(size_t)row * N + col] + bias[col];
                if (MODE == 2) v = gelu_fast(v + bias[col]);
                if (OUTBF) ((__bf16*)Cv)[(size_t)row * N + col] = (__bf16)v;
                else       ((float*)Cv)[(size_t)row * N + col] = v;
            }
        }
    }
}

// ---------------- reduce4: x += bias + sum of 4 bf16 split-K partials ------------
__global__ __launch_bounds__(256) void reduce4(
    const __bf16* __restrict__ parts, const float* __restrict__ bias,
    float* __restrict__ x)
{
    const size_t PS = (size_t)ROWS * DIM;     // elems per partial
    int idx = blockIdx.x * 256 + threadIdx.x; // float4 index, ROWS*DIM/4 total
    float4 xr = ((const float4*)x)[idx];
    float4 bv = ((const float4*)bias)[idx & (DIM / 4 - 1)];
    float o0 = xr.x + bv.x, o1 = xr.y + bv.y, o2 = xr.z + bv.z, o3 = xr.w + bv.w;
    #pragma unroll
    for (int s = 0; s < 4; s++) {
        bf16x4 p = *(const bf16x4*)(parts + s * PS + (size_t)idx * 4);
        o0 += (float)p[0]; o1 += (float)p[1]; o2 += (float)p[2]; o3 += (float)p[3];
    }
    float4 o = {o0, o1, o2, o3};
    ((float4*)x)[idx] = o;
}

// ---------------- attn kernel A: per-chunk KVT_c[e][d] = sum_m v[m][e]ek[m][d] --
__global__ __launch_bounds__(256) void attn_local_m(
    const __bf16* __restrict__ qkv, const __bf16* __restrict__ vTg,
    float* __restrict__ KVT, float* __restrict__ Ksum)
{
    int blk = blockIdx.x;
    int c = blk % NCHK, bh = blk / NCHK;
    int b = bh / NH, h = bh % NH;
    __shared__ __bf16 ek_s[64 * 64];
    __shared__ __bf16 ekT_s[64 * 68];
    __shared__ float ksum_p[4][64];
    int t = threadIdx.x, w = t >> 6, l = t & 63;
    size_t rowbase = (size_t)(b * SEQ + c * CHK);

    {
        int m = t >> 2, dq = t & 3;
        const __bf16* kr = qkv + (rowbase + m) * QKP + DIM + h * DH + dq * 16;
        bf16x8 k0 = *(const bf16x8*)kr;
        bf16x8 k1 = *(const bf16x8*)(kr + 8);
        bf16x8 e0, e1;
        #pragma unroll
        for (int j = 0; j < 8; j++) {
            e0[j] = (__bf16)__expf((float)k0[j]);
            e1[j] = (__bf16)__expf((float)k1[j]);
        }
        *(bf16x8*)&ek_s[swz128(m, dq * 16)] = e0;
        *(bf16x8*)&ek_s[swz128(m, dq * 16 + 8)] = e1;
    }
    __syncthreads();
    {
        float kacc = 0.f;
        #pragma unroll
        for (int g = 0; g < 4; g++) {
            bf16x4 pk;
            #pragma unroll
            for (int j = 0; j < 4; j++) {
                __bf16 e = ek_s[swz128(w * 16 + g * 4 + j, l)];
                pk[j] = e;
                kacc += (float)e;
            }
            *(bf16x4*)&ekT_s[l * 68 + w * 16 + g * 4] = pk;
        }
        ksum_p[w][l] = kacc;
    }
    __syncthreads();
    f32x4 acc[4] = {};
    const __bf16* vbase = vTg + (size_t)(h * DH + w * 16 + (l & 15)) * ROWS
                        + (size_t)b * SEQ + c * CHK + (l >> 4) * 8;
    bf16x8 a0 = *(const bf16x8*)vbase;
    bf16x8 a1 = *(const bf16x8*)(vbase + 32);
    #pragma unroll
    for (int fn = 0; fn < 4; fn++) {
        int rbase = (fn * 16 + (l & 15)) * 68 + (l >> 4) * 8;
        bf16x4 b0a = *(const bf16x4*)&ekT_s[rbase];
        bf16x4 b0b = *(const bf16x4*)&ekT_s[rbase + 4];
        bf16x4 b1a = *(const bf16x4*)&ekT_s[rbase + 32];
        bf16x4 b1b = *(const bf16x4*)&ekT_s[rbase + 36];
        bf16x8 b0, b1;
        #pragma unroll
        for (int j = 0; j < 4; j++) {
            b0[j] = b0a[j]; b0[j + 4] = b0b[j];
            b1[j] = b1a[j]; b1[j + 4] = b1b[j];
        }
        acc[fn] = __builtin_amdgcn_mfma_f32_16x16x32_bf16(a0, b0, acc[fn], 0, 0, 0);
        acc[fn] = __builtin_amdgcn_mfma_f32_16x16x32_bf16(a1, b1, acc[fn], 0, 0, 0);
    }
    float* kvout = KVT + (size_t)(bh * NCHK + c) * (DH * DH);
    #pragma unroll
    for (int fn = 0; fn < 4; fn++)
        #pragma unroll
        for (int r = 0; r < 4; r++)
            kvout[(w * 16 + (l >> 4) * 4 + r) * DH + fn * 16 + (l & 15)] = acc[fn][r];
    if (t < 64) {
        float s = ksum_p[0][t] + ksum_p[1][t] + ksum_p[2][t] + ksum_p[3][t];
        Ksum[(size_t)(bh * NCHK + c) * DH + t] = s;
    }
}

// ---------------- attn kernel B: parallel exclusive prefix over chunks ----------
__global__ __launch_bounds__(256) void attn_scan2(
    float* __restrict__ KV, float* __restrict__ Ksum)
{
    int bh = blockIdx.y;
    int bx = blockIdx.x;
    int t = threadIdx.x;
    if (bx < 16) {
        int elem = bx * 256 + t;
        float run = 0.f;
        for (int c = 0; c < NCHK; c++) {
            float* p = KV + ((size_t)(bh * NCHK + c)) * (DH * DH) + elem;
            float tmp = *p;
            *p = run;
            run += tmp;
        }
    } else if (t < DH) {
        float run = 0.f;
        for (int c = 0; c < NCHK; c++) {
            float* p = Ksum + ((size_t)(bh * NCHK + c)) * DH + t;
            float tmp = *p;
            *p = run;
            run += tmp;
        }
    }
}

// ---------------- attn kernel C: per-chunk output via MFMA ----------------------
__global__ __launch_bounds__(256) void attn_out_m(
    const __bf16* __restrict__ qkv, const __bf16* __restrict__ vTg,
    const float* __restrict__ KVT, const float* __restrict__ Ksum,
    __bf16* __restrict__ ag)
{
    int blk = blockIdx.x;
    int c = blk % NCHK, bh = blk / NCHK;
    int b = bh / NH, h = bh % NH;
    __shared__ __bf16 q_s[64 * 64];
    __shared__ __bf16 ek_s[64 * 64];
    __shared__ __bf16 s_s[64 * 64];
    __shared__ __bf16 kvT_s[64 * 64];
    __shared__ float denom_s[64];
    int t = threadIdx.x, w = t >> 6, l = t & 63;
    size_t rowbase = (size_t)(b * SEQ + c * CHK);

    {
        int i = t >> 2, dq = t & 3;
        const __bf16* qr = qkv + (rowbase + i) * QKP + h * DH + dq * 16;
        bf16x8 q0 = *(const bf16x8*)qr, q1 = *(const bf16x8*)(qr + 8);
        float qf[16];
        #pragma unroll
        for (int j = 0; j < 8; j++) { qf[j] = (float)q0[j]; qf[8 + j] = (float)q1[j]; }
        float mx = qf[0];
        #pragma unroll
        for (int j = 1; j < 16; j++) mx = fmaxf(mx, qf[j]);
        mx = fmaxf(mx, __shfl_xor(mx, 1));
        mx = fmaxf(mx, __shfl_xor(mx, 2));
        float ss = 0.f;
        #pragma unroll
        for (int j = 0; j < 16; j++) { qf[j] = __expf(qf[j] - mx); ss += qf[j]; }
        ss += __shfl_xor(ss, 1);
        ss += __shfl_xor(ss, 2);
        float sc = 0.125f / ss;
        bf16x8 o0, o1;
        #pragma unroll
        for (int j = 0; j < 8; j++) {
            o0[j] = (__bf16)(qf[j] * sc);
            o1[j] = (__bf16)(qf[8 + j] * sc);
        }
        *(bf16x8*)&q_s[swz128(i, dq * 16)] = o0;
        *(bf16x8*)&q_s[swz128(i, dq * 16 + 8)] = o1;
        const float* kp = Ksum + (size_t)(bh * NCHK + c) * DH + dq * 16;
        float dk = 0.f;
        #pragma unroll
        for (int j = 0; j < 16; j++) dk += (qf[j] * sc) * kp[j];
        dk += __shfl_xor(dk, 1);
        dk += __shfl_xor(dk, 2);
        if (dq == 0) denom_s[i] = dk;
    }
    {
        int m = t >> 2, dq = t & 3;
        const __bf16* kr = qkv + (rowbase + m) * QKP + DIM + h * DH + dq * 16;
        bf16x8 k0 = *(const bf16x8*)kr, k1 = *(const bf16x8*)(kr + 8);
        bf16x8 e0, e1;
        #pragma unroll
        for (int j = 0; j < 8; j++) {
            e0[j] = (__bf16)__expf((float)k0[j]);
            e1[j] = (__bf16)__expf((float)k1[j]);
        }
        *(bf16x8*)&ek_s[swz128(m, dq * 16)] = e0;
        *(bf16x8*)&ek_s[swz128(m, dq * 16 + 8)] = e1;
    }
    {
        int e = t >> 2, dq = t & 3;
        const float* kvr = KVT + (size_t)(bh * NCHK + c) * (DH * DH) + e * DH + dq * 16;
        bf16x8 o0, o1;
        #pragma unroll
        for (int j = 0; j < 8; j++) { o0[j] = (__bf16)kvr[j]; o1[j] = (__bf16)kvr[8 + j]; }
        *(bf16x8*)&kvT_s[swz128(e, dq * 16)] = o0;
        *(bf16x8*)&kvT_s[swz128(e, dq * 16 + 8)] = o1;
    }
    __syncthreads();

    bf16x8 bq0 = *(const bf16x8*)&q_s[swz128(w * 16 + (l & 15), (l >> 4) * 8)];
    bf16x8 bq1 = *(const bf16x8*)&q_s[swz128(w * 16 + (l & 15), 32 + (l >> 4) * 8)];
    int i_col = w * 16 + (l & 15);
    float dsum = 0.f;
    #pragma unroll
    for (int fm = 0; fm < 4; fm++) {
        bf16x8 ae0 = *(const bf16x8*)&ek_s[swz128(fm * 16 + (l & 15), (l >> 4) * 8)];
        bf16x8 ae1 = *(const bf16x8*)&ek_s[swz128(fm * 16 + (l & 15), 32 + (l >> 4) * 8)];
        f32x4 z = {};
        z = __builtin_amdgcn_mfma_f32_16x16x32_bf16(ae0, bq0, z, 0, 0, 0);
        z = __builtin_amdgcn_mfma_f32_16x16x32_bf16(ae1, bq1, z, 0, 0, 0);
        bf16x4 pk;
        #pragma unroll
        for (int r = 0; r < 4; r++) {
            int m = fm * 16 + (l >> 4) * 4 + r;
            float v = (m <= i_col) ? z[r] : 0.f;
            pk[r] = (__bf16)v;
            dsum += (float)pk[r];
        }
        *(bf16x4*)&s_s[swz128(i_col, fm * 16 + (l >> 4) * 4)] = pk;
    }
    dsum += __shfl_xor(dsum, 16);
    dsum += __shfl_xor(dsum, 32);
    if (l < 16) denom_s[w * 16 + l] += dsum;

    bf16x8 as0 = *(const bf16x8*)&s_s[swz128(w * 16 + (l & 15), (l >> 4) * 8)];
    bf16x8 as1 = *(const bf16x8*)&s_s[swz128(w * 16 + (l & 15), 32 + (l >> 4) * 8)];
    f32x4 oacc[4] = {};
    #pragma unroll
    for (int fn = 0; fn < 4; fn++) {
        const __bf16* vb = vTg + (size_t)(h * DH + fn * 16 + (l & 15)) * ROWS
                         + (size_t)b * SEQ + c * CHK + (l >> 4) * 8;
        bf16x8 bv0 = *(const bf16x8*)vb;
        bf16x8 bv1 = *(const bf16x8*)(vb + 32);
        bf16x8 bk0 = *(const bf16x8*)&kvT_s[swz128(fn * 16 + (l & 15), (l >> 4) * 8)];
        bf16x8 bk1 = *(const bf16x8*)&kvT_s[swz128(fn * 16 + (l & 15), 32 + (l >> 4) * 8)];
        f32x4 z = oacc[fn];
        z = __builtin_amdgcn_mfma_f32_16x16x32_bf16(as0, bv0, z, 0, 0, 0);
        z = __builtin_amdgcn_mfma_f32_16x16x32_bf16(as1, bv1, z, 0, 0, 0);
        z = __builtin_amdgcn_mfma_f32_16x16x32_bf16(bq0, bk0, z, 0, 0, 0);
        z = __builtin_amdgcn_mfma_f32_16x16x32_bf16(bq1, bk1, z, 0, 0, 0);
        oacc[fn] = z;
    }
    #pragma unroll
    for (int r = 0; r < 4; r++) {
        int i = w * 16 + (l >> 4) * 4 + r;
        float dinv = 1.0f / fmaxf(denom_s[i], 1e-3f);
        #pragma unroll
        for (int fn = 0; fn < 4; fn++)
            ag[(rowbase + i) * DIM + h * DH + fn * 16 + (l & 15)] = (__bf16)(oacc[fn][r] * dinv);
    }
}

// ---------------- launch --------------------------------------------------------
extern "C" void kernel_launch(void* const* d_in, const int* in_sizes, int n_in,
                              void* d_out, int out_size, void* d_ws, size_t ws_size,
                              hipStream_t stream) {
    (void)in_sizes; (void)n_in; (void)out_size; (void)ws_size;
    const float* x_in  = (const float*)d_in[0];
    const float* ln1_g = (const float*)d_in[1];
    const float* ln1_b = (const float*)d_in[2];
    const float* Wq    = (const float*)d_in[3];
    const float* Wk    = (const float*)d_in[4];
    const float* Wv    = (const float*)d_in[5];
    const float* Wo    = (const float*)d_in[6];
    const float* bo    = (const float*)d_in[7];
    const float* ln2_g = (const float*)d_in[8];
    const float* ln2_b = (const float*)d_in[9];
    const float* W1    = (const float*)d_in[10];
    const float* b1    = (const float*)d_in[11];
    const float* W2    = (const float*)d_in[12];
    const float* b2    = (const float*)d_in[13];

    float* x = (float*)d_out;
    const size_t MB = 1024 * 1024;
    char* base = (char*)d_ws;

    __bf16* qkv   = (__bf16*)base;
    __bf16* vTg   = (__bf16*)(base + 24 * MB);
    __bf16* h1    = (__bf16*)base;
    __bf16* xn    = (__bf16*)(base + 32 * MB);
    __bf16* parts = (__bf16*)(base + 32 * MB);
    __bf16* a     = (__bf16*)(base + 40 * MB);
    float*  KVT   = (float*)(base + 48 * MB);
    float*  Ks    = (float*)(base + 64 * MB);
    __bf16* wqkt  = (__bf16*)(base + 65 * MB);  // 6MB
    __bf16* wot   = (__bf16*)(base + 71 * MB);  // 2MB
    __bf16* w1t   = (__bf16*)(base + 73 * MB);  // 8MB
    __bf16* w2t   = (__bf16*)(base + 81 * MB);  // 8MB

    const size_t SZ = (size_t)ROWS * DIM;
    hipMemcpyAsync(x, x_in, SZ * sizeof(float), hipMemcpyDeviceToDevice, stream);

    dim3 gTd(DIM / 32, DIM / 32);
    dim3 gT1(FFD / 32, DIM / 32);
    dim3 gT2(DIM / 32, FFD / 32);
    dim3 gScan(17, BB * NH);
    dim3 gTv(ROWS / 64, DIM / 64);

    for (int l = 0; l < DEPTH; l++) {
        const float* wq = Wq + (size_t)l * DIM * DIM;
        const float* wk = Wk + (size_t)l * DIM * DIM;
        const float* wv = Wv + (size_t)l * DIM * DIM;
        const float* wo = Wo + (size_t)l * DIM * DIM;
        const float* w1 = W1 + (size_t)l * DIM * FFD;
        const float* w2 = W2 + (size_t)l * FFD * DIM;

        transpose_bf16<<<gTd, 256, 0, stream>>>(wq, wqkt, DIM, DIM);
        transpose_bf16<<<gTd, 256, 0, stream>>>(wk, wqkt + (size_t)DIM * DIM, DIM, DIM);
        transpose_bf16<<<gTd, 256, 0, stream>>>(wv, wqkt + 2 * (size_t)DIM * DIM, DIM, DIM);
        transpose_bf16<<<gTd, 256, 0, stream>>>(wo, wot, DIM, DIM);
        transpose_bf16<<<gT1, 256, 0, stream>>>(w1, w1t, DIM, FFD);
        transpose_bf16<<<gT2, 256, 0, stream>>>(w2, w2t, FFD, DIM);

        // pre-norm attention block
        ln_kernel<<<ROWS, 256, 0, stream>>>(x, ln1_g + l * DIM, ln1_b + l * DIM, xn);
        gemm256<0, 1><<<12 * 16, 512, 0, stream>>>(xn, wqkt, qkv, nullptr, nullptr,
                                                   ROWS, QKP, DIM, DIM, 12, 16, 1);
        transpose_v<<<gTv, 256, 0, stream>>>(qkv, vTg);
        attn_local_m<<<BB * NH * NCHK, 256, 0, stream>>>(qkv, vTg, KVT, Ks);
        attn_scan2<<<gScan, 256, 0, stream>>>(KVT, Ks);
        attn_out_m<<<BB * NH * NCHK, 256, 0, stream>>>(qkv, vTg, KVT, Ks, a);
        gemm_bf16<1, 0><<<8 * 32, 256, 0, stream>>>(a, wot, x, bo + l * DIM, x,
                                                    ROWS, DIM, DIM, 8, 32);

        // pre-norm FF block
        ln_kernel<<<ROWS, 256, 0, stream>>>(x, ln2_g + l * DIM, ln2_b + l * DIM, xn);
        gemm256<2, 1><<<16 * 16, 512, 0, stream>>>(xn, w1t, h1, b1 + l * FFD, nullptr,
                                                   ROWS, FFD, DIM, DIM, 16, 16, 1);
        // FF2: split-K 4 over K=4096 -> bf16 partials + fused reduce epilogue
        gemm256<0, 1><<<4 * 16 * 4, 512, 0, stream>>>(h1, w2t, parts, nullptr, nullptr,
                                                      ROWS, DIM, FFD / 4, FFD, 4, 16, 4);
        reduce4<<<ROWS * DIM / 4 / 256, 256, 0, stream>>>(parts, b2 + l * DIM, x);
    }
}

// Round 10
// 399.162 us; speedup vs baseline: 11.1894x; 1.0842x over previous
//
#include <hip/hip_runtime.h>
#include <cmath>

#define BB 2
#define SEQ 2048
#define DIM 1024
#define NH 16
#define DH 64
#define DEPTH 2
#define FFD 4096
#define CHK 64
#define NCHK (SEQ/CHK)      // 32
#define ROWS (BB*SEQ)       // 4096
#define QKP (3*DIM)         // fused qkv row pitch (3072)

typedef __bf16 bf16x8 __attribute__((ext_vector_type(8)));
typedef __bf16 bf16x4 __attribute__((ext_vector_type(4)));
typedef float  f32x4  __attribute__((ext_vector_type(4)));

#define AS1 __attribute__((address_space(1)))
#define AS3 __attribute__((address_space(3)))
#define FENCE() asm volatile("" ::: "memory")
#define WAIT_LGKM0_NOPIN() asm volatile("s_waitcnt lgkmcnt(0)" ::: "memory")

// tanh-form GELU: |err| < 1e-3 vs exact; invisible under bf16 rounding
__device__ __forceinline__ float gelu_fast(float x) {
    float x3 = x * x * x;
    float y = 1.5957691216057308f * (x + 0.044715f * x3);
    return x * __builtin_amdgcn_rcpf(1.0f + __expf(-y));
}

// swizzled halfword index into a row-pitch-64hw (128B) bf16 tile
__device__ __forceinline__ int swz128(int row, int col) {
    return row * 64 + (col ^ ((row & 7) << 3));
}

// T1: XCD-contiguous bijective block swizzle (m204) + width-4 column-group order
__device__ __forceinline__ void swz_tile(int bid, int NX, int NY, int& tx, int& ty) {
    int NB = NX * NY;
    int q = NB >> 3, r = NB & 7;
    int xcd = bid & 7, seq = bid >> 3;
    int start = (xcd < r) ? xcd * (q + 1) : r * (q + 1) + (xcd - r) * q;
    int wgid = start + seq;
    int g = 0, rem = wgid;
    int gw = (NX < 4) ? NX : 4;
    while (rem >= gw * NY) {
        rem -= gw * NY; g++;
        int left = NX - 4 * g;
        gw = left < 4 ? left : 4;
    }
    ty = rem / gw;
    tx = 4 * g + rem % gw;
}

// ---------------- LayerNorm (standalone; used only for layer-0 ln1) -------------
__global__ __launch_bounds__(256) void ln_kernel(
    const float* __restrict__ x, const float* __restrict__ g,
    const float* __restrict__ b, __bf16* __restrict__ out)
{
    int row = blockIdx.x;
    const float4* xr = (const float4*)(x + (size_t)row * DIM);
    int t = threadIdx.x;
    float4 v = xr[t];
    float s  = v.x + v.y + v.z + v.w;
    float ss = v.x*v.x + v.y*v.y + v.z*v.z + v.w*v.w;
    #pragma unroll
    for (int off = 32; off > 0; off >>= 1) {
        s  += __shfl_down(s, off);
        ss += __shfl_down(ss, off);
    }
    __shared__ float wsum[4], wsq[4], stats[2];
    int wid = t >> 6, lane = t & 63;
    if (lane == 0) { wsum[wid] = s; wsq[wid] = ss; }
    __syncthreads();
    if (t == 0) {
        float S  = wsum[0] + wsum[1] + wsum[2] + wsum[3];
        float SS = wsq[0] + wsq[1] + wsq[2] + wsq[3];
        float mean = S * (1.0f / DIM);
        float var  = SS * (1.0f / DIM) - mean * mean;
        stats[0] = mean;
        stats[1] = rsqrtf(var + 1e-5f);
    }
    __syncthreads();
    float mean = stats[0], rstd = stats[1];
    float4 gv = ((const float4*)g)[t];
    float4 bv = ((const float4*)b)[t];
    bf16x4 o;
    o[0] = (__bf16)((v.x - mean) * rstd * gv.x + bv.x);
    o[1] = (__bf16)((v.y - mean) * rstd * gv.y + bv.y);
    o[2] = (__bf16)((v.z - mean) * rstd * gv.z + bv.z);
    o[3] = (__bf16)((v.w - mean) * rstd * gv.w + bv.w);
    *(bf16x4*)(out + (size_t)row * DIM + t * 4) = o;
}

// ---------------- batched weight transpose: all 6 weights in one dispatch --------
__global__ __launch_bounds__(256) void transpose_all(
    const float* __restrict__ wq, const float* __restrict__ wk,
    const float* __restrict__ wv, const float* __restrict__ wo,
    const float* __restrict__ w1, const float* __restrict__ w2,
    __bf16* __restrict__ wqkt, __bf16* __restrict__ wot,
    __bf16* __restrict__ w1t, __bf16* __restrict__ w2t)
{
    int id = blockIdx.x;
    const float* W; __bf16* Wt; int K, N, txt, tyt;
    if (id < 4096) {                       // wq,wk,wv,wo: 1024x1024, 32x32 grid
        int seg = id >> 10, r = id & 1023;
        K = DIM; N = DIM;
        txt = r & 31; tyt = r >> 5;
        W  = seg == 0 ? wq : seg == 1 ? wk : seg == 2 ? wv : wo;
        Wt = seg < 3 ? wqkt + (size_t)seg * DIM * DIM : wot;
    } else if (id < 8192) {                // w1: 1024x4096, 128x32 grid
        int r = id - 4096;
        K = DIM; N = FFD;
        txt = r & 127; tyt = r >> 7;
        W = w1; Wt = w1t;
    } else {                               // w2: 4096x1024, 32x128 grid
        int r = id - 8192;
        K = FFD; N = DIM;
        txt = r & 31; tyt = r >> 5;
        W = w2; Wt = w2t;
    }
    __shared__ float tile[32][33];
    int bx = txt * 32, by = tyt * 32;
    int tx = threadIdx.x & 31, ty = threadIdx.x >> 5;
    #pragma unroll
    for (int i = 0; i < 32; i += 8)
        tile[ty + i][tx] = W[(size_t)(by + ty + i) * N + bx + tx];
    __syncthreads();
    #pragma unroll
    for (int i = 0; i < 32; i += 8)
        Wt[(size_t)(bx + ty + i) * K + by + tx] = (__bf16)tile[tx][ty + i];
}

// ---------------- v transpose: qkv[:,2048+d] -> vT[d][row] -----------------------
__global__ __launch_bounds__(256) void transpose_v(
    const __bf16* __restrict__ qkv, __bf16* __restrict__ vT)
{
    __shared__ __bf16 tile[64 * 64];
    int bx = blockIdx.x;  // row tile (ROWS/64)
    int by = blockIdx.y;  // d tile (DIM/64)
    int t = threadIdx.x;
    int r0 = t >> 3, sl = t & 7;
    #pragma unroll
    for (int i = 0; i < 2; i++) {
        int row = i * 32 + r0;
        bf16x8 d = *(const bf16x8*)(qkv + (size_t)(bx * 64 + row) * QKP + 2 * DIM + by * 64 + sl * 8);
        *(bf16x8*)&tile[row * 64 + ((sl ^ (row & 7)) << 3)] = d;
    }
    __syncthreads();
    #pragma unroll
    for (int i = 0; i < 2; i++) {
        int d = i * 32 + r0;
        int rbase = sl * 8;
        bf16x8 o;
        #pragma unroll
        for (int j = 0; j < 8; j++) {
            int rr = rbase + j;
            o[j] = tile[rr * 64 + (((((d >> 3)) ^ (rr & 7)) << 3) | (d & 7))];
        }
        *(bf16x8*)(vT + (size_t)(by * 64 + d) * ROWS + bx * 64 + rbase) = o;
    }
}

// ---------------- gemm256: 256x256, BK=64, 8-wave, 8-phase counted-vmcnt ---------
// Kp = row pitch of A/Bt; K = extent of this block's K-walk. NS>1: split-K.
// Round-10: all ds_read addresses hoisted to 8 loop-invariant per-lane base
// pointers + compile-time immediate offsets; staging swizzle hoisted (lane-const).
#define TBM 256
#define TBN 256
#define TBK 64
template<int MODE, int OUTBF>
__global__ __launch_bounds__(512) void gemm256(
    const __bf16* __restrict__ A, const __bf16* __restrict__ Bt,
    void* __restrict__ Cv, const float* __restrict__ bias,
    const float* __restrict__ res, int M, int N, int K, int Kp,
    int NXT, int NYT, int NS)
{
    __shared__ __bf16 lds[2][2][TBM * TBK];   // [buf][A/B][256*64] = 128 KiB
    int nb = NXT * NYT;
    int sk = blockIdx.x / nb;
    int tx, ty;
    swz_tile(blockIdx.x % nb, NXT, NYT, tx, ty);
    if (NS > 1) {
        A  += (size_t)sk * K;
        Bt += (size_t)sk * K;
        Cv = (void*)((char*)Cv + (size_t)sk * M * N * (OUTBF ? 2 : 4));
    }
    const int bm = ty * TBM, bn = tx * TBN;
    const int t = threadIdx.x;
    const int l = t & 63, w = t >> 6;
    const int wm = w >> 2, wn = w & 3;        // 2 x 4 waves
    const int lm = l & 15, lk = l >> 4;

    f32x4 acc[8][4] = {};
    const int nt = K / TBK;                   // K-tiles (even, >=2)
    const int NIT = nt / 2;

    // hoisted per-lane LDS fragment bases (kk slot: (kk*4+lk)^(lm&7), 4+lk==4^lk)
    const int s7 = lm & 7;
    const int c0 = (lk ^ s7) << 3;
    const int c1 = ((4 ^ lk) ^ s7) << 3;
    const __bf16* pA[2][2] = {
        { &lds[0][0][(wm * 128 + lm) * 64 + c0], &lds[0][0][(wm * 128 + lm) * 64 + c1] },
        { &lds[1][0][(wm * 128 + lm) * 64 + c0], &lds[1][0][(wm * 128 + lm) * 64 + c1] } };
    const __bf16* pB[2][2] = {
        { &lds[0][1][(wn * 64 + lm) * 64 + c0], &lds[0][1][(wn * 64 + lm) * 64 + c1] },
        { &lds[1][1][(wn * 64 + lm) * 64 + c0], &lds[1][1][(wn * 64 + lm) * 64 + c1] } };

    // hoisted staging bases: row = hf*128+i*64+(t>>3); swizzle col const per lane
    const int srow0 = t >> 3;
    const int scol0 = ((t & 7) ^ (srow0 & 7)) * 8;
    const __bf16* gAb = A + (size_t)(bm + srow0) * Kp + scol0;
    const __bf16* gBb = Bt + (size_t)(bn + srow0) * Kp + scol0;
    const int ldsw = w * 512;

    auto STAGEH = [&](int bf, int mat, int hf, int kt) {
        const __bf16* srcb = mat ? gBb : gAb;
        #pragma unroll
        for (int i = 0; i < 2; i++) {
            __builtin_amdgcn_global_load_lds(
                (const AS1 void*)(srcb + (size_t)(hf * 128 + i * 64) * Kp + kt * 64),
                (AS3 void*)(&lds[bf][mat][(hf * 2 + i) * 4096 + ldsw]), 16, 0, 0);
        }
    };
    auto LDA = [&](int bf, int g, bf16x8* af) {
        #pragma unroll
        for (int j = 0; j < 4; j++) {
            af[j * 2 + 0] = *(const bf16x8*)(pA[bf][0] + (g * 4 + j) * 1024);
            af[j * 2 + 1] = *(const bf16x8*)(pA[bf][1] + (g * 4 + j) * 1024);
        }
    };
    auto LDB = [&](int bf, bf16x8* bfv) {
        #pragma unroll
        for (int n = 0; n < 4; n++) {
            bfv[n * 2 + 0] = *(const bf16x8*)(pB[bf][0] + n * 1024);
            bfv[n * 2 + 1] = *(const bf16x8*)(pB[bf][1] + n * 1024);
        }
    };
    auto MM = [&](int g, int ng, bf16x8* af, bf16x8* bfv) {
        __builtin_amdgcn_s_setprio(1);
        #pragma unroll
        for (int j = 0; j < 4; j++)
            #pragma unroll
            for (int nn = 0; nn < 2; nn++)
                #pragma unroll
                for (int kk = 0; kk < 2; kk++)
                    acc[g * 4 + j][ng * 2 + nn] = __builtin_amdgcn_mfma_f32_16x16x32_bf16(
                        af[j * 2 + kk], bfv[(ng * 2 + nn) * 2 + kk], acc[g * 4 + j][ng * 2 + nn], 0, 0, 0);
        __builtin_amdgcn_s_setprio(0);
    };

    // ---- prologue: T0 fully, T1.{B0,B1,A0}; vmcnt(6) leaves T1's 3 halves in flight
    STAGEH(0, 0, 0, 0); STAGEH(0, 0, 1, 0); STAGEH(0, 1, 0, 0); STAGEH(0, 1, 1, 0);
    STAGEH(1, 1, 0, 1); STAGEH(1, 1, 1, 1); STAGEH(1, 0, 0, 1);
    asm volatile("s_waitcnt vmcnt(6)" ::: "memory");
    __builtin_amdgcn_s_barrier();

    bf16x8 aF[8], bF[8];
    for (int it = 0; it < NIT; it++) {
        int T2 = 2 * it + 2, U2 = 2 * it + 3;
        // Ph1: T:(A0 x B0); stage U.A1
        LDA(0, 0, aF); LDB(0, bF);
        STAGEH(1, 0, 1, 2 * it + 1);
        FENCE(); __builtin_amdgcn_s_barrier();
        MM(0, 0, aF, bF);
        WAIT_LGKM0_NOPIN();            // bF[4..7] consumed Ph2-4: drain before close
        FENCE(); __builtin_amdgcn_s_barrier();
        // Ph2: T:(A0 x B1); stage T'.B0
        if (T2 < nt) STAGEH(0, 1, 0, T2);
        FENCE(); __builtin_amdgcn_s_barrier();
        MM(0, 1, aF, bF);
        FENCE(); __builtin_amdgcn_s_barrier();
        // Ph3: T:(A1 x B1); stage T'.B1
        LDA(0, 1, aF);
        if (T2 < nt) STAGEH(0, 1, 1, T2);
        FENCE(); __builtin_amdgcn_s_barrier();
        MM(1, 1, aF, bF);
        FENCE(); __builtin_amdgcn_s_barrier();
        // Ph4: T:(A1 x B0); stage T'.A0; counted vmcnt
        if (T2 < nt) {
            STAGEH(0, 0, 0, T2);
            asm volatile("s_waitcnt vmcnt(6)" ::: "memory");
        } else {
            asm volatile("s_waitcnt vmcnt(0)" ::: "memory");
        }
        __builtin_amdgcn_s_barrier();
        MM(1, 0, aF, bF);
        FENCE(); __builtin_amdgcn_s_barrier();
        // Ph5: U:(A0 x B0); stage T'.A1
        LDA(1, 0, aF); LDB(1, bF);
        if (T2 < nt) STAGEH(0, 0, 1, T2);
        FENCE(); __builtin_amdgcn_s_barrier();
        MM(0, 0, aF, bF);
        WAIT_LGKM0_NOPIN();            // bF[4..7] consumed Ph6-8: drain before close
        FENCE(); __builtin_amdgcn_s_barrier();
        // Ph6: U:(A0 x B1); stage U'.B0
        if (U2 < nt) STAGEH(1, 1, 0, U2);
        FENCE(); __builtin_amdgcn_s_barrier();
        MM(0, 1, aF, bF);
        FENCE(); __builtin_amdgcn_s_barrier();
        // Ph7: U:(A1 x B1); stage U'.B1
        LDA(1, 1, aF);
        if (U2 < nt) STAGEH(1, 1, 1, U2);
        FENCE(); __builtin_amdgcn_s_barrier();
        MM(1, 1, aF, bF);
        FENCE(); __builtin_amdgcn_s_barrier();
        // Ph8: U:(A1 x B0); stage U'.A0; counted vmcnt
        if (U2 < nt) {
            STAGEH(1, 0, 0, U2);
            asm volatile("s_waitcnt vmcnt(6)" ::: "memory");
        } else {
            asm volatile("s_waitcnt vmcnt(0)" ::: "memory");
        }
        __builtin_amdgcn_s_barrier();
        MM(1, 0, aF, bF);
        FENCE(); __builtin_amdgcn_s_barrier();
    }

    // epilogue: C/D layout col=lane&15, row=(lane>>4)*4+r
    #pragma unroll
    for (int m = 0; m < 8; m++) {
        #pragma unroll
        for (int n = 0; n < 4; n++) {
            int col = bn + wn * 64 + n * 16 + lm;
            #pragma unroll
            for (int r = 0; r < 4; r++) {
                int row = bm + wm * 128 + m * 16 + lk * 4 + r;
                float v = acc[m][n][r];
                if (MODE == 1) v += res[(size_t)row * N + col] + bias[col];
                if (MODE == 2) v = gelu_fast(v + bias[col]);
                if (OUTBF) ((__bf16*)Cv)[(size_t)row * N + col] = (__bf16)v;
                else       ((float*)Cv)[(size_t)row * N + col] = v;
            }
        }
    }
}

// ---------------- reduce4ln: x += bias + sum of 4 bf16 partials; optional LN -----
// one block per row (256 thr x 4 elems). DOLN: also write xn = LN(x_new)*g + b.
template<int DOLN>
__global__ __launch_bounds__(256) void reduce4ln(
    const __bf16* __restrict__ parts, const float* __restrict__ bias,
    float* __restrict__ x, const float* __restrict__ g,
    const float* __restrict__ b, __bf16* __restrict__ xn)
{
    const size_t PS = (size_t)ROWS * DIM;
    int row = blockIdx.x, t = threadIdx.x;
    size_t base = (size_t)row * DIM + t * 4;
    float4 xr = *(const float4*)(x + base);
    float4 bv = ((const float4*)bias)[t];
    float o0 = xr.x + bv.x, o1 = xr.y + bv.y, o2 = xr.z + bv.z, o3 = xr.w + bv.w;
    #pragma unroll
    for (int s = 0; s < 4; s++) {
        bf16x4 p = *(const bf16x4*)(parts + s * PS + base);
        o0 += (float)p[0]; o1 += (float)p[1]; o2 += (float)p[2]; o3 += (float)p[3];
    }
    float4 o = {o0, o1, o2, o3};
    *(float4*)(x + base) = o;
    if constexpr (DOLN) {
        float s  = o0 + o1 + o2 + o3;
        float ss = o0*o0 + o1*o1 + o2*o2 + o3*o3;
        #pragma unroll
        for (int off = 32; off > 0; off >>= 1) {
            s  += __shfl_down(s, off);
            ss += __shfl_down(ss, off);
        }
        __shared__ float wsum[4], wsq[4], stats[2];
        int wid = t >> 6, lane = t & 63;
        if (lane == 0) { wsum[wid] = s; wsq[wid] = ss; }
        __syncthreads();
        if (t == 0) {
            float S  = wsum[0] + wsum[1] + wsum[2] + wsum[3];
            float SS = wsq[0] + wsq[1] + wsq[2] + wsq[3];
            float mean = S * (1.0f / DIM);
            float var  = SS * (1.0f / DIM) - mean * mean;
            stats[0] = mean;
            stats[1] = rsqrtf(var + 1e-5f);
        }
        __syncthreads();
        float mean = stats[0], rstd = stats[1];
        float4 gv = ((const float4*)g)[t];
        float4 bvv = ((const float4*)b)[t];
        bf16x4 on;
        on[0] = (__bf16)((o0 - mean) * rstd * gv.x + bvv.x);
        on[1] = (__bf16)((o1 - mean) * rstd * gv.y + bvv.y);
        on[2] = (__bf16)((o2 - mean) * rstd * gv.z + bvv.z);
        on[3] = (__bf16)((o3 - mean) * rstd * gv.w + bvv.w);
        *(bf16x4*)(xn + base) = on;
    }
}

// ---------------- attn kernel A: per-chunk KVT_c[e][d] = sum_m v[m][e]ek[m][d] --
__global__ __launch_bounds__(256) void attn_local_m(
    const __bf16* __restrict__ qkv, const __bf16* __restrict__ vTg,
    float* __restrict__ KVT, float* __restrict__ Ksum)
{
    int blk = blockIdx.x;
    int c = blk % NCHK, bh = blk / NCHK;
    int b = bh / NH, h = bh % NH;
    __shared__ __bf16 ek_s[64 * 64];
    __shared__ __bf16 ekT_s[64 * 68];
    __shared__ float ksum_p[4][64];
    int t = threadIdx.x, w = t >> 6, l = t & 63;
    size_t rowbase = (size_t)(b * SEQ + c * CHK);

    {
        int m = t >> 2, dq = t & 3;
        const __bf16* kr = qkv + (rowbase + m) * QKP + DIM + h * DH + dq * 16;
        bf16x8 k0 = *(const bf16x8*)kr;
        bf16x8 k1 = *(const bf16x8*)(kr + 8);
        bf16x8 e0, e1;
        #pragma unroll
        for (int j = 0; j < 8; j++) {
            e0[j] = (__bf16)__expf((float)k0[j]);
            e1[j] = (__bf16)__expf((float)k1[j]);
        }
        *(bf16x8*)&ek_s[swz128(m, dq * 16)] = e0;
        *(bf16x8*)&ek_s[swz128(m, dq * 16 + 8)] = e1;
    }
    __syncthreads();
    {
        float kacc = 0.f;
        #pragma unroll
        for (int g = 0; g < 4; g++) {
            bf16x4 pk;
            #pragma unroll
            for (int j = 0; j < 4; j++) {
                __bf16 e = ek_s[swz128(w * 16 + g * 4 + j, l)];
                pk[j] = e;
                kacc += (float)e;
            }
            *(bf16x4*)&ekT_s[l * 68 + w * 16 + g * 4] = pk;
        }
        ksum_p[w][l] = kacc;
    }
    __syncthreads();
    f32x4 acc[4] = {};
    const __bf16* vbase = vTg + (size_t)(h * DH + w * 16 + (l & 15)) * ROWS
                        + (size_t)b * SEQ + c * CHK + (l >> 4) * 8;
    bf16x8 a0 = *(const bf16x8*)vbase;
    bf16x8 a1 = *(const bf16x8*)(vbase + 32);
    #pragma unroll
    for (int fn = 0; fn < 4; fn++) {
        int rbase = (fn * 16 + (l & 15)) * 68 + (l >> 4) * 8;
        bf16x4 b0a = *(const bf16x4*)&ekT_s[rbase];
        bf16x4 b0b = *(const bf16x4*)&ekT_s[rbase + 4];
        bf16x4 b1a = *(const bf16x4*)&ekT_s[rbase + 32];
        bf16x4 b1b = *(const bf16x4*)&ekT_s[rbase + 36];
        bf16x8 b0, b1;
        #pragma unroll
        for (int j = 0; j < 4; j++) {
            b0[j] = b0a[j]; b0[j + 4] = b0b[j];
            b1[j] = b1a[j]; b1[j + 4] = b1b[j];
        }
        acc[fn] = __builtin_amdgcn_mfma_f32_16x16x32_bf16(a0, b0, acc[fn], 0, 0, 0);
        acc[fn] = __builtin_amdgcn_mfma_f32_16x16x32_bf16(a1, b1, acc[fn], 0, 0, 0);
    }
    float* kvout = KVT + (size_t)(bh * NCHK + c) * (DH * DH);
    #pragma unroll
    for (int fn = 0; fn < 4; fn++)
        #pragma unroll
        for (int r = 0; r < 4; r++)
            kvout[(w * 16 + (l >> 4) * 4 + r) * DH + fn * 16 + (l & 15)] = acc[fn][r];
    if (t < 64) {
        float s = ksum_p[0][t] + ksum_p[1][t] + ksum_p[2][t] + ksum_p[3][t];
        Ksum[(size_t)(bh * NCHK + c) * DH + t] = s;
    }
}

// ---------------- attn kernel B: parallel exclusive prefix over chunks ----------
__global__ __launch_bounds__(256) void attn_scan2(
    float* __restrict__ KV, float* __restrict__ Ksum)
{
    int bh = blockIdx.y;
    int bx = blockIdx.x;
    int t = threadIdx.x;
    if (bx < 16) {
        int elem = bx * 256 + t;
        float run = 0.f;
        for (int c = 0; c < NCHK; c++) {
            float* p = KV + ((size_t)(bh * NCHK + c)) * (DH * DH) + elem;
            float tmp = *p;
            *p = run;
            run += tmp;
        }
    } else if (t < DH) {
        float run = 0.f;
        for (int c = 0; c < NCHK; c++) {
            float* p = Ksum + ((size_t)(bh * NCHK + c)) * DH + t;
            float tmp = *p;
            *p = run;
            run += tmp;
        }
    }
}

// ---------------- attn kernel C: per-chunk output via MFMA ----------------------
__global__ __launch_bounds__(256) void attn_out_m(
    const __bf16* __restrict__ qkv, const __bf16* __restrict__ vTg,
    const float* __restrict__ KVT, const float* __restrict__ Ksum,
    __bf16* __restrict__ ag)
{
    int blk = blockIdx.x;
    int c = blk % NCHK, bh = blk / NCHK;
    int b = bh / NH, h = bh % NH;
    __shared__ __bf16 q_s[64 * 64];
    __shared__ __bf16 ek_s[64 * 64];
    __shared__ __bf16 s_s[64 * 64];
    __shared__ __bf16 kvT_s[64 * 64];
    __shared__ float denom_s[64];
    int t = threadIdx.x, w = t >> 6, l = t & 63;
    size_t rowbase = (size_t)(b * SEQ + c * CHK);

    {
        int i = t >> 2, dq = t & 3;
        const __bf16* qr = qkv + (rowbase + i) * QKP + h * DH + dq * 16;
        bf16x8 q0 = *(const bf16x8*)qr, q1 = *(const bf16x8*)(qr + 8);
        float qf[16];
        #pragma unroll
        for (int j = 0; j < 8; j++) { qf[j] = (float)q0[j]; qf[8 + j] = (float)q1[j]; }
        float mx = qf[0];
        #pragma unroll
        for (int j = 1; j < 16; j++) mx = fmaxf(mx, qf[j]);
        mx = fmaxf(mx, __shfl_xor(mx, 1));
        mx = fmaxf(mx, __shfl_xor(mx, 2));
        float ss = 0.f;
        #pragma unroll
        for (int j = 0; j < 16; j++) { qf[j] = __expf(qf[j] - mx); ss += qf[j]; }
        ss += __shfl_xor(ss, 1);
        ss += __shfl_xor(ss, 2);
        float sc = 0.125f / ss;
        bf16x8 o0, o1;
        #pragma unroll
        for (int j = 0; j < 8; j++) {
            o0[j] = (__bf16)(qf[j] * sc);
            o1[j] = (__bf16)(qf[8 + j] * sc);
        }
        *(bf16x8*)&q_s[swz128(i, dq * 16)] = o0;
        *(bf16x8*)&q_s[swz128(i, dq * 16 + 8)] = o1;
        const float* kp = Ksum + (size_t)(bh * NCHK + c) * DH + dq * 16;
        float dk = 0.f;
        #pragma unroll
        for (int j = 0; j < 16; j++) dk += (qf[j] * sc) * kp[j];
        dk += __shfl_xor(dk, 1);
        dk += __shfl_xor(dk, 2);
        if (dq == 0) denom_s[i] = dk;
    }
    {
        int m = t >> 2, dq = t & 3;
        const __bf16* kr = qkv + (rowbase + m) * QKP + DIM + h * DH + dq * 16;
        bf16x8 k0 = *(const bf16x8*)kr, k1 = *(const bf16x8*)(kr + 8);
        bf16x8 e0, e1;
        #pragma unroll
        for (int j = 0; j < 8; j++) {
            e0[j] = (__bf16)__expf((float)k0[j]);
            e1[j] = (__bf16)__expf((float)k1[j]);
        }
        *(bf16x8*)&ek_s[swz128(m, dq * 16)] = e0;
        *(bf16x8*)&ek_s[swz128(m, dq * 16 + 8)] = e1;
    }
    {
        int e = t >> 2, dq = t & 3;
        const float* kvr = KVT + (size_t)(bh * NCHK + c) * (DH * DH) + e * DH + dq * 16;
        bf16x8 o0, o1;
        #pragma unroll
        for (int j = 0; j < 8; j++) { o0[j] = (__bf16)kvr[j]; o1[j] = (__bf16)kvr[8 + j]; }
        *(bf16x8*)&kvT_s[swz128(e, dq * 16)] = o0;
        *(bf16x8*)&kvT_s[swz128(e, dq * 16 + 8)] = o1;
    }
    __syncthreads();

    bf16x8 bq0 = *(const bf16x8*)&q_s[swz128(w * 16 + (l & 15), (l >> 4) * 8)];
    bf16x8 bq1 = *(const bf16x8*)&q_s[swz128(w * 16 + (l & 15), 32 + (l >> 4) * 8)];
    int i_col = w * 16 + (l & 15);
    float dsum = 0.f;
    #pragma unroll
    for (int fm = 0; fm < 4; fm++) {
        bf16x8 ae0 = *(const bf16x8*)&ek_s[swz128(fm * 16 + (l & 15), (l >> 4) * 8)];
        bf16x8 ae1 = *(const bf16x8*)&ek_s[swz128(fm * 16 + (l & 15), 32 + (l >> 4) * 8)];
        f32x4 z = {};
        z = __builtin_amdgcn_mfma_f32_16x16x32_bf16(ae0, bq0, z, 0, 0, 0);
        z = __builtin_amdgcn_mfma_f32_16x16x32_bf16(ae1, bq1, z, 0, 0, 0);
        bf16x4 pk;
        #pragma unroll
        for (int r = 0; r < 4; r++) {
            int m = fm * 16 + (l >> 4) * 4 + r;
            float v = (m <= i_col) ? z[r] : 0.f;
            pk[r] = (__bf16)v;
            dsum += (float)pk[r];
        }
        *(bf16x4*)&s_s[swz128(i_col, fm * 16 + (l >> 4) * 4)] = pk;
    }
    dsum += __shfl_xor(dsum, 16);
    dsum += __shfl_xor(dsum, 32);
    if (l < 16) denom_s[w * 16 + l] += dsum;

    bf16x8 as0 = *(const bf16x8*)&s_s[swz128(w * 16 + (l & 15), (l >> 4) * 8)];
    bf16x8 as1 = *(const bf16x8*)&s_s[swz128(w * 16 + (l & 15), 32 + (l >> 4) * 8)];
    f32x4 oacc[4] = {};
    #pragma unroll
    for (int fn = 0; fn < 4; fn++) {
        const __bf16* vb = vTg + (size_t)(h * DH + fn * 16 + (l & 15)) * ROWS
                         + (size_t)b * SEQ + c * CHK + (l >> 4) * 8;
        bf16x8 bv0 = *(const bf16x8*)vb;
        bf16x8 bv1 = *(const bf16x8*)(vb + 32);
        bf16x8 bk0 = *(const bf16x8*)&kvT_s[swz128(fn * 16 + (l & 15), (l >> 4) * 8)];
        bf16x8 bk1 = *(const bf16x8*)&kvT_s[swz128(fn * 16 + (l & 15), 32 + (l >> 4) * 8)];
        f32x4 z = oacc[fn];
        z = __builtin_amdgcn_mfma_f32_16x16x32_bf16(as0, bv0, z, 0, 0, 0);
        z = __builtin_amdgcn_mfma_f32_16x16x32_bf16(as1, bv1, z, 0, 0, 0);
        z = __builtin_amdgcn_mfma_f32_16x16x32_bf16(bq0, bk0, z, 0, 0, 0);
        z = __builtin_amdgcn_mfma_f32_16x16x32_bf16(bq1, bk1, z, 0, 0, 0);
        oacc[fn] = z;
    }
    #pragma unroll
    for (int r = 0; r < 4; r++) {
        int i = w * 16 + (l >> 4) * 4 + r;
        float dinv = 1.0f / fmaxf(denom_s[i], 1e-3f);
        #pragma unroll
        for (int fn = 0; fn < 4; fn++)
            ag[(rowbase + i) * DIM + h * DH + fn * 16 + (l & 15)] = (__bf16)(oacc[fn][r] * dinv);
    }
}

// ---------------- launch --------------------------------------------------------
extern "C" void kernel_launch(void* const* d_in, const int* in_sizes, int n_in,
                              void* d_out, int out_size, void* d_ws, size_t ws_size,
                              hipStream_t stream) {
    (void)in_sizes; (void)n_in; (void)out_size; (void)ws_size;
    const float* x_in  = (const float*)d_in[0];
    const float* ln1_g = (const float*)d_in[1];
    const float* ln1_b = (const float*)d_in[2];
    const float* Wq    = (const float*)d_in[3];
    const float* Wk    = (const float*)d_in[4];
    const float* Wv    = (const float*)d_in[5];
    const float* Wo    = (const float*)d_in[6];
    const float* bo    = (const float*)d_in[7];
    const float* ln2_g = (const float*)d_in[8];
    const float* ln2_b = (const float*)d_in[9];
    const float* W1    = (const float*)d_in[10];
    const float* b1    = (const float*)d_in[11];
    const float* W2    = (const float*)d_in[12];
    const float* b2    = (const float*)d_in[13];

    float* x = (float*)d_out;
    const size_t MB = 1024 * 1024;
    char* base = (char*)d_ws;

    // layout (lifetimes):
    //  [0,24)  qkv (attn)   | [0,32) partsO (O-proj split-K) | [0,32) h1 (FF)
    //  [24,32) vTg (attn)   |
    //  [32,40) xn (GEMM A)  | [32,64) parts (FF2 split-K)
    //  [40,48) a (attn out) |
    //  [48,64) KVT (attn)   |
    //  [64,..) Ks; [65,89) transposed weights
    __bf16* qkv    = (__bf16*)base;
    __bf16* partsO = (__bf16*)base;
    __bf16* h1     = (__bf16*)base;
    __bf16* vTg    = (__bf16*)(base + 24 * MB);
    __bf16* xn     = (__bf16*)(base + 32 * MB);
    __bf16* parts  = (__bf16*)(base + 32 * MB);
    __bf16* a      = (__bf16*)(base + 40 * MB);
    float*  KVT    = (float*)(base + 48 * MB);
    float*  Ks     = (float*)(base + 64 * MB);
    __bf16* wqkt   = (__bf16*)(base + 65 * MB);  // 6MB
    __bf16* wot    = (__bf16*)(base + 71 * MB);  // 2MB
    __bf16* w1t    = (__bf16*)(base + 73 * MB);  // 8MB
    __bf16* w2t    = (__bf16*)(base + 81 * MB);  // 8MB

    const size_t SZ = (size_t)ROWS * DIM;
    hipMemcpyAsync(x, x_in, SZ * sizeof(float), hipMemcpyDeviceToDevice, stream);

    dim3 gScan(17, BB * NH);
    dim3 gTv(ROWS / 64, DIM / 64);

    for (int l = 0; l < DEPTH; l++) {
        const float* wq = Wq + (size_t)l * DIM * DIM;
        const float* wk = Wk + (size_t)l * DIM * DIM;
        const float* wv = Wv + (size_t)l * DIM * DIM;
        const float* wo = Wo + (size_t)l * DIM * DIM;
        const float* w1 = W1 + (size_t)l * DIM * FFD;
        const float* w2 = W2 + (size_t)l * FFD * DIM;

        transpose_all<<<12288, 256, 0, stream>>>(wq, wk, wv, wo, w1, w2,
                                                 wqkt, wot, w1t, w2t);

        // pre-norm attention block
        if (l == 0)
            ln_kernel<<<ROWS, 256, 0, stream>>>(x, ln1_g, ln1_b, xn);
        gemm256<0, 1><<<12 * 16, 512, 0, stream>>>(xn, wqkt, qkv, nullptr, nullptr,
                                                   ROWS, QKP, DIM, DIM, 12, 16, 1);
        transpose_v<<<gTv, 256, 0, stream>>>(qkv, vTg);
        attn_local_m<<<BB * NH * NCHK, 256, 0, stream>>>(qkv, vTg, KVT, Ks);
        attn_scan2<<<gScan, 256, 0, stream>>>(KVT, Ks);
        attn_out_m<<<BB * NH * NCHK, 256, 0, stream>>>(qkv, vTg, KVT, Ks, a);
        // O-proj: split-K 4 over K=1024 -> bf16 partials (qkv/vTg dead)
        gemm256<0, 1><<<4 * 16 * 4, 512, 0, stream>>>(a, wot, partsO, nullptr, nullptr,
                                                      ROWS, DIM, DIM / 4, DIM, 4, 16, 4);
        // x += bo + sum(partsO); xn = LN2(x)
        reduce4ln<1><<<ROWS, 256, 0, stream>>>(partsO, bo + l * DIM, x,
                                               ln2_g + l * DIM, ln2_b + l * DIM, xn);

        // pre-norm FF block (partsO dead -> h1 aliases)
        gemm256<2, 1><<<16 * 16, 512, 0, stream>>>(xn, w1t, h1, b1 + l * FFD, nullptr,
                                                   ROWS, FFD, DIM, DIM, 16, 16, 1);
        gemm256<0, 1><<<4 * 16 * 4, 512, 0, stream>>>(h1, w2t, parts, nullptr, nullptr,
                                                      ROWS, DIM, FFD / 4, FFD, 4, 16, 4);
        if (l + 1 < DEPTH)
            reduce4ln<1><<<ROWS, 256, 0, stream>>>(parts, b2 + l * DIM, x,
                                                   ln1_g + (l + 1) * DIM,
                                                   ln1_b + (l + 1) * DIM, xn);
        else
            reduce4ln<0><<<ROWS, 256, 0, stream>>>(parts, b2 + l * DIM, x,
                                                   nullptr, nullptr, nullptr);
    }
}

// Round 11
// 395.489 us; speedup vs baseline: 11.2933x; 1.0093x over previous
//
#include <hip/hip_runtime.h>
#include <cmath>

#define BB 2
#define SEQ 2048
#define DIM 1024
#define NH 16
#define DH 64
#define DEPTH 2
#define FFD 4096
#define CHK 64
#define NCHK (SEQ/CHK)      // 32
#define ROWS (BB*SEQ)       // 4096
#define QKP (3*DIM)         // fused qkv row pitch (3072)

typedef __bf16 bf16x8 __attribute__((ext_vector_type(8)));
typedef __bf16 bf16x4 __attribute__((ext_vector_type(4)));
typedef float  f32x4  __attribute__((ext_vector_type(4)));

#define AS1 __attribute__((address_space(1)))
#define AS3 __attribute__((address_space(3)))
#define FENCE() asm volatile("" ::: "memory")

// tanh-form GELU: |err| < 1e-3 vs exact; invisible under bf16 rounding
__device__ __forceinline__ float gelu_fast(float x) {
    float x3 = x * x * x;
    float y = 1.5957691216057308f * (x + 0.044715f * x3);
    return x * __builtin_amdgcn_rcpf(1.0f + __expf(-y));
}

// swizzled halfword index into a row-pitch-64hw (128B) bf16 tile
__device__ __forceinline__ int swz128(int row, int col) {
    return row * 64 + (col ^ ((row & 7) << 3));
}

// T1: XCD-contiguous bijective block swizzle (m204) + width-4 column-group order
__device__ __forceinline__ void swz_tile(int bid, int NX, int NY, int& tx, int& ty) {
    int NB = NX * NY;
    int q = NB >> 3, r = NB & 7;
    int xcd = bid & 7, seq = bid >> 3;
    int start = (xcd < r) ? xcd * (q + 1) : r * (q + 1) + (xcd - r) * q;
    int wgid = start + seq;
    int g = 0, rem = wgid;
    int gw = (NX < 4) ? NX : 4;
    while (rem >= gw * NY) {
        rem -= gw * NY; g++;
        int left = NX - 4 * g;
        gw = left < 4 ? left : 4;
    }
    ty = rem / gw;
    tx = 4 * g + rem % gw;
}

// ---------------- LayerNorm (standalone; used only for layer-0 ln1) -------------
__global__ __launch_bounds__(256) void ln_kernel(
    const float* __restrict__ x, const float* __restrict__ g,
    const float* __restrict__ b, __bf16* __restrict__ out)
{
    int row = blockIdx.x;
    const float4* xr = (const float4*)(x + (size_t)row * DIM);
    int t = threadIdx.x;
    float4 v = xr[t];
    float s  = v.x + v.y + v.z + v.w;
    float ss = v.x*v.x + v.y*v.y + v.z*v.z + v.w*v.w;
    #pragma unroll
    for (int off = 32; off > 0; off >>= 1) {
        s  += __shfl_down(s, off);
        ss += __shfl_down(ss, off);
    }
    __shared__ float wsum[4], wsq[4], stats[2];
    int wid = t >> 6, lane = t & 63;
    if (lane == 0) { wsum[wid] = s; wsq[wid] = ss; }
    __syncthreads();
    if (t == 0) {
        float S  = wsum[0] + wsum[1] + wsum[2] + wsum[3];
        float SS = wsq[0] + wsq[1] + wsq[2] + wsq[3];
        float mean = S * (1.0f / DIM);
        float var  = SS * (1.0f / DIM) - mean * mean;
        stats[0] = mean;
        stats[1] = rsqrtf(var + 1e-5f);
    }
    __syncthreads();
    float mean = stats[0], rstd = stats[1];
    float4 gv = ((const float4*)g)[t];
    float4 bv = ((const float4*)b)[t];
    bf16x4 o;
    o[0] = (__bf16)((v.x - mean) * rstd * gv.x + bv.x);
    o[1] = (__bf16)((v.y - mean) * rstd * gv.y + bv.y);
    o[2] = (__bf16)((v.z - mean) * rstd * gv.z + bv.z);
    o[3] = (__bf16)((v.w - mean) * rstd * gv.w + bv.w);
    *(bf16x4*)(out + (size_t)row * DIM + t * 4) = o;
}

// ---------------- batched weight transpose: all 6 weights in one dispatch --------
__global__ __launch_bounds__(256) void transpose_all(
    const float* __restrict__ wq, const float* __restrict__ wk,
    const float* __restrict__ wv, const float* __restrict__ wo,
    const float* __restrict__ w1, const float* __restrict__ w2,
    __bf16* __restrict__ wqkt, __bf16* __restrict__ wot,
    __bf16* __restrict__ w1t, __bf16* __restrict__ w2t)
{
    int id = blockIdx.x;
    const float* W; __bf16* Wt; int K, N, txt, tyt;
    if (id < 4096) {                       // wq,wk,wv,wo: 1024x1024, 32x32 grid
        int seg = id >> 10, r = id & 1023;
        K = DIM; N = DIM;
        txt = r & 31; tyt = r >> 5;
        W  = seg == 0 ? wq : seg == 1 ? wk : seg == 2 ? wv : wo;
        Wt = seg < 3 ? wqkt + (size_t)seg * DIM * DIM : wot;
    } else if (id < 8192) {                // w1: 1024x4096, 128x32 grid
        int r = id - 4096;
        K = DIM; N = FFD;
        txt = r & 127; tyt = r >> 7;
        W = w1; Wt = w1t;
    } else {                               // w2: 4096x1024, 32x128 grid
        int r = id - 8192;
        K = FFD; N = DIM;
        txt = r & 31; tyt = r >> 5;
        W = w2; Wt = w2t;
    }
    __shared__ float tile[32][33];
    int bx = txt * 32, by = tyt * 32;
    int tx = threadIdx.x & 31, ty = threadIdx.x >> 5;
    #pragma unroll
    for (int i = 0; i < 32; i += 8)
        tile[ty + i][tx] = W[(size_t)(by + ty + i) * N + bx + tx];
    __syncthreads();
    #pragma unroll
    for (int i = 0; i < 32; i += 8)
        Wt[(size_t)(bx + ty + i) * K + by + tx] = (__bf16)tile[tx][ty + i];
}

// ---------------- v transpose: qkv[:,2048+d] -> vT[d][row] -----------------------
__global__ __launch_bounds__(256) void transpose_v(
    const __bf16* __restrict__ qkv, __bf16* __restrict__ vT)
{
    __shared__ __bf16 tile[64 * 64];
    int bx = blockIdx.x;  // row tile (ROWS/64)
    int by = blockIdx.y;  // d tile (DIM/64)
    int t = threadIdx.x;
    int r0 = t >> 3, sl = t & 7;
    #pragma unroll
    for (int i = 0; i < 2; i++) {
        int row = i * 32 + r0;
        bf16x8 d = *(const bf16x8*)(qkv + (size_t)(bx * 64 + row) * QKP + 2 * DIM + by * 64 + sl * 8);
        *(bf16x8*)&tile[row * 64 + ((sl ^ (row & 7)) << 3)] = d;
    }
    __syncthreads();
    #pragma unroll
    for (int i = 0; i < 2; i++) {
        int d = i * 32 + r0;
        int rbase = sl * 8;
        bf16x8 o;
        #pragma unroll
        for (int j = 0; j < 8; j++) {
            int rr = rbase + j;
            o[j] = tile[rr * 64 + (((((d >> 3)) ^ (rr & 7)) << 3) | (d & 7))];
        }
        *(bf16x8*)(vT + (size_t)(by * 64 + d) * ROWS + bx * 64 + rbase) = o;
    }
}

// ---------------- gemm256: 256x256, BK=64, 8-wave, 4-phase counted-vmcnt ---------
// Kp = row pitch of A/Bt; K = extent of this block's K-walk. NS>1: split-K.
// Round-11 merged schedule (M1-M4, 32-MFMA clusters, 8 barriers/iter):
//   M1: read T.A-g0 + T.B(all); stage U.A0,A1   [buf1.A dead since prev M4]
//   M2: read T.A-g1;            stage T'.B0,B1  [buf0.B dead since M1] + vmcnt(4)
//   M3: read U.A-g0 + U.B(all); stage T'.A0,A1  [buf0.A dead since M2]
//   M4: read U.A-g1;            stage U'.B0,B1  [buf1.B dead since M3] + vmcnt(4)
// Every phase's ds_reads are consumed by its own MFMA cluster -> no lgkm drains.
// vmcnt(4)@M2 drains {prev M4: U.B, M1: U.A} -> buf1 ready for M3.
// vmcnt(4)@M4 drains {M2: T'.B, M3: T'.A}   -> buf0 ready for next M1.
#define TBM 256
#define TBN 256
#define TBK 64
template<int MODE, int OUTBF>
__global__ __launch_bounds__(512) void gemm256(
    const __bf16* __restrict__ A, const __bf16* __restrict__ Bt,
    void* __restrict__ Cv, const float* __restrict__ bias,
    const float* __restrict__ res, int M, int N, int K, int Kp,
    int NXT, int NYT, int NS)
{
    __shared__ __bf16 lds[2][2][TBM * TBK];   // [buf][A/B][256*64] = 128 KiB
    int nb = NXT * NYT;
    int sk = blockIdx.x / nb;
    int tx, ty;
    swz_tile(blockIdx.x % nb, NXT, NYT, tx, ty);
    if (NS > 1) {
        A  += (size_t)sk * K;
        Bt += (size_t)sk * K;
        Cv = (void*)((char*)Cv + (size_t)sk * M * N * (OUTBF ? 2 : 4));
    }
    const int bm = ty * TBM, bn = tx * TBN;
    const int t = threadIdx.x;
    const int l = t & 63, w = t >> 6;
    const int wm = w >> 2, wn = w & 3;        // 2 x 4 waves
    const int lm = l & 15, lk = l >> 4;

    f32x4 acc[8][4] = {};
    const int nt = K / TBK;                   // K-tiles (even, >=2)
    const int NIT = nt / 2;

    // hoisted per-lane LDS fragment bases
    const int s7 = lm & 7;
    const int c0 = (lk ^ s7) << 3;
    const int c1 = ((4 ^ lk) ^ s7) << 3;
    const __bf16* pA[2][2] = {
        { &lds[0][0][(wm * 128 + lm) * 64 + c0], &lds[0][0][(wm * 128 + lm) * 64 + c1] },
        { &lds[1][0][(wm * 128 + lm) * 64 + c0], &lds[1][0][(wm * 128 + lm) * 64 + c1] } };
    const __bf16* pB[2][2] = {
        { &lds[0][1][(wn * 64 + lm) * 64 + c0], &lds[0][1][(wn * 64 + lm) * 64 + c1] },
        { &lds[1][1][(wn * 64 + lm) * 64 + c0], &lds[1][1][(wn * 64 + lm) * 64 + c1] } };

    // hoisted staging bases: row = hf*128+i*64+(t>>3); swizzle col const per lane
    const int srow0 = t >> 3;
    const int scol0 = ((t & 7) ^ (srow0 & 7)) * 8;
    const __bf16* gAb = A + (size_t)(bm + srow0) * Kp + scol0;
    const __bf16* gBb = Bt + (size_t)(bn + srow0) * Kp + scol0;
    const int ldsw = w * 512;

    auto STAGEH = [&](int bf, int mat, int hf, int kt) {
        const __bf16* srcb = mat ? gBb : gAb;
        #pragma unroll
        for (int i = 0; i < 2; i++) {
            __builtin_amdgcn_global_load_lds(
                (const AS1 void*)(srcb + (size_t)(hf * 128 + i * 64) * Kp + kt * 64),
                (AS3 void*)(&lds[bf][mat][(hf * 2 + i) * 4096 + ldsw]), 16, 0, 0);
        }
    };
    auto LDA = [&](int bf, int g, bf16x8* af) {
        #pragma unroll
        for (int j = 0; j < 4; j++) {
            af[j * 2 + 0] = *(const bf16x8*)(pA[bf][0] + (g * 4 + j) * 1024);
            af[j * 2 + 1] = *(const bf16x8*)(pA[bf][1] + (g * 4 + j) * 1024);
        }
    };
    auto LDB = [&](int bf, bf16x8* bfv) {
        #pragma unroll
        for (int n = 0; n < 4; n++) {
            bfv[n * 2 + 0] = *(const bf16x8*)(pB[bf][0] + n * 1024);
            bfv[n * 2 + 1] = *(const bf16x8*)(pB[bf][1] + n * 1024);
        }
    };
    // 32 MFMA: A-group g x all B
    auto MM2 = [&](int g, bf16x8* af, bf16x8* bfv) {
        __builtin_amdgcn_s_setprio(1);
        #pragma unroll
        for (int j = 0; j < 4; j++)
            #pragma unroll
            for (int n = 0; n < 4; n++)
                #pragma unroll
                for (int kk = 0; kk < 2; kk++)
                    acc[g * 4 + j][n] = __builtin_amdgcn_mfma_f32_16x16x32_bf16(
                        af[j * 2 + kk], bfv[n * 2 + kk], acc[g * 4 + j][n], 0, 0, 0);
        __builtin_amdgcn_s_setprio(0);
    };

    // ---- prologue: T0 full + T1.B0,B1 (12 loads); vmcnt(4) drains T0 ----
    STAGEH(0, 0, 0, 0); STAGEH(0, 0, 1, 0); STAGEH(0, 1, 0, 0); STAGEH(0, 1, 1, 0);
    STAGEH(1, 1, 0, 1); STAGEH(1, 1, 1, 1);
    asm volatile("s_waitcnt vmcnt(4)" ::: "memory");
    __builtin_amdgcn_s_barrier();

    bf16x8 aF[8], bF[8];
    for (int it = 0; it < NIT; it++) {
        int u = 2 * it + 1, T2 = 2 * it + 2, U2 = 2 * it + 3;
        // M1: T:(A-g0 x Ball); stage U.A0,A1
        LDA(0, 0, aF); LDB(0, bF);
        STAGEH(1, 0, 0, u); STAGEH(1, 0, 1, u);
        FENCE(); __builtin_amdgcn_s_barrier();
        MM2(0, aF, bF);
        FENCE(); __builtin_amdgcn_s_barrier();
        // M2: T:(A-g1 x Ball); stage T'.B0,B1; vmcnt(4) -> buf1(U) ready for M3
        LDA(0, 1, aF);
        if (T2 < nt) {
            STAGEH(0, 1, 0, T2); STAGEH(0, 1, 1, T2);
            asm volatile("s_waitcnt vmcnt(4)" ::: "memory");
        } else {
            asm volatile("s_waitcnt vmcnt(0)" ::: "memory");
        }
        __builtin_amdgcn_s_barrier();
        MM2(1, aF, bF);
        FENCE(); __builtin_amdgcn_s_barrier();
        // M3: U:(A-g0 x Ball); stage T'.A0,A1
        LDA(1, 0, aF); LDB(1, bF);
        if (T2 < nt) { STAGEH(0, 0, 0, T2); STAGEH(0, 0, 1, T2); }
        FENCE(); __builtin_amdgcn_s_barrier();
        MM2(0, aF, bF);
        FENCE(); __builtin_amdgcn_s_barrier();
        // M4: U:(A-g1 x Ball); stage U'.B0,B1; vmcnt(4) -> buf0(T') ready for next M1
        LDA(1, 1, aF);
        if (U2 < nt) {
            STAGEH(1, 1, 0, U2); STAGEH(1, 1, 1, U2);
            asm volatile("s_waitcnt vmcnt(4)" ::: "memory");
        } else {
            asm volatile("s_waitcnt vmcnt(0)" ::: "memory");
        }
        __builtin_amdgcn_s_barrier();
        MM2(1, aF, bF);
        FENCE(); __builtin_amdgcn_s_barrier();
    }

    // epilogue: C/D layout col=lane&15, row=(lane>>4)*4+r
    #pragma unroll
    for (int m = 0; m < 8; m++) {
        #pragma unroll
        for (int n = 0; n < 4; n++) {
            int col = bn + wn * 64 + n * 16 + lm;
            #pragma unroll
            for (int r = 0; r < 4; r++) {
                int row = bm + wm * 128 + m * 16 + lk * 4 + r;
                float v = acc[m][n][r];
                if (MODE == 1) v += res[(size_t)row * N + col] + bias[col];
                if (MODE == 2) v = gelu_fast(v + bias[col]);
                if (OUTBF) ((__bf16*)Cv)[(size_t)row * N + col] = (__bf16)v;
                else       ((float*)Cv)[(size_t)row * N + col] = v;
            }
        }
    }
}

// ---------------- reduce4ln: x += bias + sum of 4 bf16 partials; optional LN -----
template<int DOLN>
__global__ __launch_bounds__(256) void reduce4ln(
    const __bf16* __restrict__ parts, const float* __restrict__ bias,
    float* __restrict__ x, const float* __restrict__ g,
    const float* __restrict__ b, __bf16* __restrict__ xn)
{
    const size_t PS = (size_t)ROWS * DIM;
    int row = blockIdx.x, t = threadIdx.x;
    size_t base = (size_t)row * DIM + t * 4;
    float4 xr = *(const float4*)(x + base);
    float4 bv = ((const float4*)bias)[t];
    float o0 = xr.x + bv.x, o1 = xr.y + bv.y, o2 = xr.z + bv.z, o3 = xr.w + bv.w;
    #pragma unroll
    for (int s = 0; s < 4; s++) {
        bf16x4 p = *(const bf16x4*)(parts + s * PS + base);
        o0 += (float)p[0]; o1 += (float)p[1]; o2 += (float)p[2]; o3 += (float)p[3];
    }
    float4 o = {o0, o1, o2, o3};
    *(float4*)(x + base) = o;
    if constexpr (DOLN) {
        float s  = o0 + o1 + o2 + o3;
        float ss = o0*o0 + o1*o1 + o2*o2 + o3*o3;
        #pragma unroll
        for (int off = 32; off > 0; off >>= 1) {
            s  += __shfl_down(s, off);
            ss += __shfl_down(ss, off);
        }
        __shared__ float wsum[4], wsq[4], stats[2];
        int wid = t >> 6, lane = t & 63;
        if (lane == 0) { wsum[wid] = s; wsq[wid] = ss; }
        __syncthreads();
        if (t == 0) {
            float S  = wsum[0] + wsum[1] + wsum[2] + wsum[3];
            float SS = wsq[0] + wsq[1] + wsq[2] + wsq[3];
            float mean = S * (1.0f / DIM);
            float var  = SS * (1.0f / DIM) - mean * mean;
            stats[0] = mean;
            stats[1] = rsqrtf(var + 1e-5f);
        }
        __syncthreads();
        float mean = stats[0], rstd = stats[1];
        float4 gv = ((const float4*)g)[t];
        float4 bvv = ((const float4*)b)[t];
        bf16x4 on;
        on[0] = (__bf16)((o0 - mean) * rstd * gv.x + bvv.x);
        on[1] = (__bf16)((o1 - mean) * rstd * gv.y + bvv.y);
        on[2] = (__bf16)((o2 - mean) * rstd * gv.z + bvv.z);
        on[3] = (__bf16)((o3 - mean) * rstd * gv.w + bvv.w);
        *(bf16x4*)(xn + base) = on;
    }
}

// ---------------- attn kernel A: per-chunk KVT_c[e][d] = sum_m v[m][e]ek[m][d] --
__global__ __launch_bounds__(256) void attn_local_m(
    const __bf16* __restrict__ qkv, const __bf16* __restrict__ vTg,
    float* __restrict__ KVT, float* __restrict__ Ksum)
{
    int blk = blockIdx.x;
    int c = blk % NCHK, bh = blk / NCHK;
    int b = bh / NH, h = bh % NH;
    __shared__ __bf16 ek_s[64 * 64];
    __shared__ __bf16 ekT_s[64 * 68];
    __shared__ float ksum_p[4][64];
    int t = threadIdx.x, w = t >> 6, l = t & 63;
    size_t rowbase = (size_t)(b * SEQ + c * CHK);

    {
        int m = t >> 2, dq = t & 3;
        const __bf16* kr = qkv + (rowbase + m) * QKP + DIM + h * DH + dq * 16;
        bf16x8 k0 = *(const bf16x8*)kr;
        bf16x8 k1 = *(const bf16x8*)(kr + 8);
        bf16x8 e0, e1;
        #pragma unroll
        for (int j = 0; j < 8; j++) {
            e0[j] = (__bf16)__expf((float)k0[j]);
            e1[j] = (__bf16)__expf((float)k1[j]);
        }
        *(bf16x8*)&ek_s[swz128(m, dq * 16)] = e0;
        *(bf16x8*)&ek_s[swz128(m, dq * 16 + 8)] = e1;
    }
    __syncthreads();
    {
        float kacc = 0.f;
        #pragma unroll
        for (int g = 0; g < 4; g++) {
            bf16x4 pk;
            #pragma unroll
            for (int j = 0; j < 4; j++) {
                __bf16 e = ek_s[swz128(w * 16 + g * 4 + j, l)];
                pk[j] = e;
                kacc += (float)e;
            }
            *(bf16x4*)&ekT_s[l * 68 + w * 16 + g * 4] = pk;
        }
        ksum_p[w][l] = kacc;
    }
    __syncthreads();
    f32x4 acc[4] = {};
    const __bf16* vbase = vTg + (size_t)(h * DH + w * 16 + (l & 15)) * ROWS
                        + (size_t)b * SEQ + c * CHK + (l >> 4) * 8;
    bf16x8 a0 = *(const bf16x8*)vbase;
    bf16x8 a1 = *(const bf16x8*)(vbase + 32);
    #pragma unroll
    for (int fn = 0; fn < 4; fn++) {
        int rbase = (fn * 16 + (l & 15)) * 68 + (l >> 4) * 8;
        bf16x4 b0a = *(const bf16x4*)&ekT_s[rbase];
        bf16x4 b0b = *(const bf16x4*)&ekT_s[rbase + 4];
        bf16x4 b1a = *(const bf16x4*)&ekT_s[rbase + 32];
        bf16x4 b1b = *(const bf16x4*)&ekT_s[rbase + 36];
        bf16x8 b0, b1;
        #pragma unroll
        for (int j = 0; j < 4; j++) {
            b0[j] = b0a[j]; b0[j + 4] = b0b[j];
            b1[j] = b1a[j]; b1[j + 4] = b1b[j];
        }
        acc[fn] = __builtin_amdgcn_mfma_f32_16x16x32_bf16(a0, b0, acc[fn], 0, 0, 0);
        acc[fn] = __builtin_amdgcn_mfma_f32_16x16x32_bf16(a1, b1, acc[fn], 0, 0, 0);
    }
    float* kvout = KVT + (size_t)(bh * NCHK + c) * (DH * DH);
    #pragma unroll
    for (int fn = 0; fn < 4; fn++)
        #pragma unroll
        for (int r = 0; r < 4; r++)
            kvout[(w * 16 + (l >> 4) * 4 + r) * DH + fn * 16 + (l & 15)] = acc[fn][r];
    if (t < 64) {
        float s = ksum_p[0][t] + ksum_p[1][t] + ksum_p[2][t] + ksum_p[3][t];
        Ksum[(size_t)(bh * NCHK + c) * DH + t] = s;
    }
}

// ---------------- attn kernel B: parallel exclusive prefix over chunks ----------
__global__ __launch_bounds__(256) void attn_scan2(
    float* __restrict__ KV, float* __restrict__ Ksum)
{
    int bh = blockIdx.y;
    int bx = blockIdx.x;
    int t = threadIdx.x;
    if (bx < 16) {
        int elem = bx * 256 + t;
        float run = 0.f;
        for (int c = 0; c < NCHK; c++) {
            float* p = KV + ((size_t)(bh * NCHK + c)) * (DH * DH) + elem;
            float tmp = *p;
            *p = run;
            run += tmp;
        }
    } else if (t < DH) {
        float run = 0.f;
        for (int c = 0; c < NCHK; c++) {
            float* p = Ksum + ((size_t)(bh * NCHK + c)) * DH + t;
            float tmp = *p;
            *p = run;
            run += tmp;
        }
    }
}

// ---------------- attn kernel C: per-chunk output via MFMA ----------------------
__global__ __launch_bounds__(256) void attn_out_m(
    const __bf16* __restrict__ qkv, const __bf16* __restrict__ vTg,
    const float* __restrict__ KVT, const float* __restrict__ Ksum,
    __bf16* __restrict__ ag)
{
    int blk = blockIdx.x;
    int c = blk % NCHK, bh = blk / NCHK;
    int b = bh / NH, h = bh % NH;
    __shared__ __bf16 q_s[64 * 64];
    __shared__ __bf16 ek_s[64 * 64];
    __shared__ __bf16 s_s[64 * 64];
    __shared__ __bf16 kvT_s[64 * 64];
    __shared__ float denom_s[64];
    int t = threadIdx.x, w = t >> 6, l = t & 63;
    size_t rowbase = (size_t)(b * SEQ + c * CHK);

    {
        int i = t >> 2, dq = t & 3;
        const __bf16* qr = qkv + (rowbase + i) * QKP + h * DH + dq * 16;
        bf16x8 q0 = *(const bf16x8*)qr, q1 = *(const bf16x8*)(qr + 8);
        float qf[16];
        #pragma unroll
        for (int j = 0; j < 8; j++) { qf[j] = (float)q0[j]; qf[8 + j] = (float)q1[j]; }
        float mx = qf[0];
        #pragma unroll
        for (int j = 1; j < 16; j++) mx = fmaxf(mx, qf[j]);
        mx = fmaxf(mx, __shfl_xor(mx, 1));
        mx = fmaxf(mx, __shfl_xor(mx, 2));
        float ss = 0.f;
        #pragma unroll
        for (int j = 0; j < 16; j++) { qf[j] = __expf(qf[j] - mx); ss += qf[j]; }
        ss += __shfl_xor(ss, 1);
        ss += __shfl_xor(ss, 2);
        float sc = 0.125f / ss;
        bf16x8 o0, o1;
        #pragma unroll
        for (int j = 0; j < 8; j++) {
            o0[j] = (__bf16)(qf[j] * sc);
            o1[j] = (__bf16)(qf[8 + j] * sc);
        }
        *(bf16x8*)&q_s[swz128(i, dq * 16)] = o0;
        *(bf16x8*)&q_s[swz128(i, dq * 16 + 8)] = o1;
        const float* kp = Ksum + (size_t)(bh * NCHK + c) * DH + dq * 16;
        float dk = 0.f;
        #pragma unroll
        for (int j = 0; j < 16; j++) dk += (qf[j] * sc) * kp[j];
        dk += __shfl_xor(dk, 1);
        dk += __shfl_xor(dk, 2);
        if (dq == 0) denom_s[i] = dk;
    }
    {
        int m = t >> 2, dq = t & 3;
        const __bf16* kr = qkv + (rowbase + m) * QKP + DIM + h * DH + dq * 16;
        bf16x8 k0 = *(const bf16x8*)kr, k1 = *(const bf16x8*)(kr + 8);
        bf16x8 e0, e1;
        #pragma unroll
        for (int j = 0; j < 8; j++) {
            e0[j] = (__bf16)__expf((float)k0[j]);
            e1[j] = (__bf16)__expf((float)k1[j]);
        }
        *(bf16x8*)&ek_s[swz128(m, dq * 16)] = e0;
        *(bf16x8*)&ek_s[swz128(m, dq * 16 + 8)] = e1;
    }
    {
        int e = t >> 2, dq = t & 3;
        const float* kvr = KVT + (size_t)(bh * NCHK + c) * (DH * DH) + e * DH + dq * 16;
        bf16x8 o0, o1;
        #pragma unroll
        for (int j = 0; j < 8; j++) { o0[j] = (__bf16)kvr[j]; o1[j] = (__bf16)kvr[8 + j]; }
        *(bf16x8*)&kvT_s[swz128(e, dq * 16)] = o0;
        *(bf16x8*)&kvT_s[swz128(e, dq * 16 + 8)] = o1;
    }
    __syncthreads();

    bf16x8 bq0 = *(const bf16x8*)&q_s[swz128(w * 16 + (l & 15), (l >> 4) * 8)];
    bf16x8 bq1 = *(const bf16x8*)&q_s[swz128(w * 16 + (l & 15), 32 + (l >> 4) * 8)];
    int i_col = w * 16 + (l & 15);
    float dsum = 0.f;
    #pragma unroll
    for (int fm = 0; fm < 4; fm++) {
        bf16x8 ae0 = *(const bf16x8*)&ek_s[swz128(fm * 16 + (l & 15), (l >> 4) * 8)];
        bf16x8 ae1 = *(const bf16x8*)&ek_s[swz128(fm * 16 + (l & 15), 32 + (l >> 4) * 8)];
        f32x4 z = {};
        z = __builtin_amdgcn_mfma_f32_16x16x32_bf16(ae0, bq0, z, 0, 0, 0);
        z = __builtin_amdgcn_mfma_f32_16x16x32_bf16(ae1, bq1, z, 0, 0, 0);
        bf16x4 pk;
        #pragma unroll
        for (int r = 0; r < 4; r++) {
            int m = fm * 16 + (l >> 4) * 4 + r;
            float v = (m <= i_col) ? z[r] : 0.f;
            pk[r] = (__bf16)v;
            dsum += (float)pk[r];
        }
        *(bf16x4*)&s_s[swz128(i_col, fm * 16 + (l >> 4) * 4)] = pk;
    }
    dsum += __shfl_xor(dsum, 16);
    dsum += __shfl_xor(dsum, 32);
    if (l < 16) denom_s[w * 16 + l] += dsum;

    bf16x8 as0 = *(const bf16x8*)&s_s[swz128(w * 16 + (l & 15), (l >> 4) * 8)];
    bf16x8 as1 = *(const bf16x8*)&s_s[swz128(w * 16 + (l & 15), 32 + (l >> 4) * 8)];
    f32x4 oacc[4] = {};
    #pragma unroll
    for (int fn = 0; fn < 4; fn++) {
        const __bf16* vb = vTg + (size_t)(h * DH + fn * 16 + (l & 15)) * ROWS
                         + (size_t)b * SEQ + c * CHK + (l >> 4) * 8;
        bf16x8 bv0 = *(const bf16x8*)vb;
        bf16x8 bv1 = *(const bf16x8*)(vb + 32);
        bf16x8 bk0 = *(const bf16x8*)&kvT_s[swz128(fn * 16 + (l & 15), (l >> 4) * 8)];
        bf16x8 bk1 = *(const bf16x8*)&kvT_s[swz128(fn * 16 + (l & 15), 32 + (l >> 4) * 8)];
        f32x4 z = oacc[fn];
        z = __builtin_amdgcn_mfma_f32_16x16x32_bf16(as0, bv0, z, 0, 0, 0);
        z = __builtin_amdgcn_mfma_f32_16x16x32_bf16(as1, bv1, z, 0, 0, 0);
        z = __builtin_amdgcn_mfma_f32_16x16x32_bf16(bq0, bk0, z, 0, 0, 0);
        z = __builtin_amdgcn_mfma_f32_16x16x32_bf16(bq1, bk1, z, 0, 0, 0);
        oacc[fn] = z;
    }
    #pragma unroll
    for (int r = 0; r < 4; r++) {
        int i = w * 16 + (l >> 4) * 4 + r;
        float dinv = 1.0f / fmaxf(denom_s[i], 1e-3f);
        #pragma unroll
        for (int fn = 0; fn < 4; fn++)
            ag[(rowbase + i) * DIM + h * DH + fn * 16 + (l & 15)] = (__bf16)(oacc[fn][r] * dinv);
    }
}

// ---------------- launch --------------------------------------------------------
extern "C" void kernel_launch(void* const* d_in, const int* in_sizes, int n_in,
                              void* d_out, int out_size, void* d_ws, size_t ws_size,
                              hipStream_t stream) {
    (void)in_sizes; (void)n_in; (void)out_size; (void)ws_size;
    const float* x_in  = (const float*)d_in[0];
    const float* ln1_g = (const float*)d_in[1];
    const float* ln1_b = (const float*)d_in[2];
    const float* Wq    = (const float*)d_in[3];
    const float* Wk    = (const float*)d_in[4];
    const float* Wv    = (const float*)d_in[5];
    const float* Wo    = (const float*)d_in[6];
    const float* bo    = (const float*)d_in[7];
    const float* ln2_g = (const float*)d_in[8];
    const float* ln2_b = (const float*)d_in[9];
    const float* W1    = (const float*)d_in[10];
    const float* b1    = (const float*)d_in[11];
    const float* W2    = (const float*)d_in[12];
    const float* b2    = (const float*)d_in[13];

    float* x = (float*)d_out;
    const size_t MB = 1024 * 1024;
    char* base = (char*)d_ws;

    __bf16* qkv    = (__bf16*)base;
    __bf16* partsO = (__bf16*)base;
    __bf16* h1     = (__bf16*)base;
    __bf16* vTg    = (__bf16*)(base + 24 * MB);
    __bf16* xn     = (__bf16*)(base + 32 * MB);
    __bf16* parts  = (__bf16*)(base + 32 * MB);
    __bf16* a      = (__bf16*)(base + 40 * MB);
    float*  KVT    = (float*)(base + 48 * MB);
    float*  Ks     = (float*)(base + 64 * MB);
    __bf16* wqkt   = (__bf16*)(base + 65 * MB);  // 6MB
    __bf16* wot    = (__bf16*)(base + 71 * MB);  // 2MB
    __bf16* w1t    = (__bf16*)(base + 73 * MB);  // 8MB
    __bf16* w2t    = (__bf16*)(base + 81 * MB);  // 8MB

    const size_t SZ = (size_t)ROWS * DIM;
    hipMemcpyAsync(x, x_in, SZ * sizeof(float), hipMemcpyDeviceToDevice, stream);

    dim3 gScan(17, BB * NH);
    dim3 gTv(ROWS / 64, DIM / 64);

    for (int l = 0; l < DEPTH; l++) {
        const float* wq = Wq + (size_t)l * DIM * DIM;
        const float* wk = Wk + (size_t)l * DIM * DIM;
        const float* wv = Wv + (size_t)l * DIM * DIM;
        const float* wo = Wo + (size_t)l * DIM * DIM;
        const float* w1 = W1 + (size_t)l * DIM * FFD;
        const float* w2 = W2 + (size_t)l * FFD * DIM;

        transpose_all<<<12288, 256, 0, stream>>>(wq, wk, wv, wo, w1, w2,
                                                 wqkt, wot, w1t, w2t);

        // pre-norm attention block
        if (l == 0)
            ln_kernel<<<ROWS, 256, 0, stream>>>(x, ln1_g, ln1_b, xn);
        gemm256<0, 1><<<12 * 16, 512, 0, stream>>>(xn, wqkt, qkv, nullptr, nullptr,
                                                   ROWS, QKP, DIM, DIM, 12, 16, 1);
        transpose_v<<<gTv, 256, 0, stream>>>(qkv, vTg);
        attn_local_m<<<BB * NH * NCHK, 256, 0, stream>>>(qkv, vTg, KVT, Ks);
        attn_scan2<<<gScan, 256, 0, stream>>>(KVT, Ks);
        attn_out_m<<<BB * NH * NCHK, 256, 0, stream>>>(qkv, vTg, KVT, Ks, a);
        // O-proj: split-K 4 over K=1024 -> bf16 partials (qkv/vTg dead)
        gemm256<0, 1><<<4 * 16 * 4, 512, 0, stream>>>(a, wot, partsO, nullptr, nullptr,
                                                      ROWS, DIM, DIM / 4, DIM, 4, 16, 4);
        // x += bo + sum(partsO); xn = LN2(x)
        reduce4ln<1><<<ROWS, 256, 0, stream>>>(partsO, bo + l * DIM, x,
                                               ln2_g + l * DIM, ln2_b + l * DIM, xn);

        // pre-norm FF block (partsO dead -> h1 aliases)
        gemm256<2, 1><<<16 * 16, 512, 0, stream>>>(xn, w1t, h1, b1 + l * FFD, nullptr,
                                                   ROWS, FFD, DIM, DIM, 16, 16, 1);
        gemm256<0, 1><<<4 * 16 * 4, 512, 0, stream>>>(h1, w2t, parts, nullptr, nullptr,
                                                      ROWS, DIM, FFD / 4, FFD, 4, 16, 4);
        if (l + 1 < DEPTH)
            reduce4ln<1><<<ROWS, 256, 0, stream>>>(parts, b2 + l * DIM, x,
                                                   ln1_g + (l + 1) * DIM,
                                                   ln1_b + (l + 1) * DIM, xn);
        else
            reduce4ln<0><<<ROWS, 256, 0, stream>>>(parts, b2 + l * DIM, x,
                                                   nullptr, nullptr, nullptr);
    }
}

// Round 12
// 390.768 us; speedup vs baseline: 11.4298x; 1.0121x over previous
//
#include <hip/hip_runtime.h>
#include <cmath>

#define BB 2
#define SEQ 2048
#define DIM 1024
#define NH 16
#define DH 64
#define DEPTH 2
#define FFD 4096
#define CHK 64
#define NCHK (SEQ/CHK)      // 32
#define ROWS (BB*SEQ)       // 4096
#define QKP (3*DIM)         // fused qkv row pitch (3072)

typedef __bf16 bf16x8 __attribute__((ext_vector_type(8)));
typedef __bf16 bf16x4 __attribute__((ext_vector_type(4)));
typedef float  f32x4  __attribute__((ext_vector_type(4)));

#define AS1 __attribute__((address_space(1)))
#define AS3 __attribute__((address_space(3)))
#define FENCE() asm volatile("" ::: "memory")

// tanh-form GELU: |err| < 1e-3 vs exact; invisible under bf16 rounding
__device__ __forceinline__ float gelu_fast(float x) {
    float x3 = x * x * x;
    float y = 1.5957691216057308f * (x + 0.044715f * x3);
    return x * __builtin_amdgcn_rcpf(1.0f + __expf(-y));
}

// swizzled halfword index into a row-pitch-64hw (128B) bf16 tile
__device__ __forceinline__ int swz128(int row, int col) {
    return row * 64 + (col ^ ((row & 7) << 3));
}

// T1: XCD-contiguous bijective block swizzle (m204) + width-4 column-group order
__device__ __forceinline__ void swz_tile(int bid, int NX, int NY, int& tx, int& ty) {
    int NB = NX * NY;
    int q = NB >> 3, r = NB & 7;
    int xcd = bid & 7, seq = bid >> 3;
    int start = (xcd < r) ? xcd * (q + 1) : r * (q + 1) + (xcd - r) * q;
    int wgid = start + seq;
    int g = 0, rem = wgid;
    int gw = (NX < 4) ? NX : 4;
    while (rem >= gw * NY) {
        rem -= gw * NY; g++;
        int left = NX - 4 * g;
        gw = left < 4 ? left : 4;
    }
    ty = rem / gw;
    tx = 4 * g + rem % gw;
}

// ---------------- LayerNorm (standalone; used only for layer-0 ln1) -------------
__global__ __launch_bounds__(256) void ln_kernel(
    const float* __restrict__ x, const float* __restrict__ g,
    const float* __restrict__ b, __bf16* __restrict__ out)
{
    int row = blockIdx.x;
    const float4* xr = (const float4*)(x + (size_t)row * DIM);
    int t = threadIdx.x;
    float4 v = xr[t];
    float s  = v.x + v.y + v.z + v.w;
    float ss = v.x*v.x + v.y*v.y + v.z*v.z + v.w*v.w;
    #pragma unroll
    for (int off = 32; off > 0; off >>= 1) {
        s  += __shfl_down(s, off);
        ss += __shfl_down(ss, off);
    }
    __shared__ float wsum[4], wsq[4], stats[2];
    int wid = t >> 6, lane = t & 63;
    if (lane == 0) { wsum[wid] = s; wsq[wid] = ss; }
    __syncthreads();
    if (t == 0) {
        float S  = wsum[0] + wsum[1] + wsum[2] + wsum[3];
        float SS = wsq[0] + wsq[1] + wsq[2] + wsq[3];
        float mean = S * (1.0f / DIM);
        float var  = SS * (1.0f / DIM) - mean * mean;
        stats[0] = mean;
        stats[1] = rsqrtf(var + 1e-5f);
    }
    __syncthreads();
    float mean = stats[0], rstd = stats[1];
    float4 gv = ((const float4*)g)[t];
    float4 bv = ((const float4*)b)[t];
    bf16x4 o;
    o[0] = (__bf16)((v.x - mean) * rstd * gv.x + bv.x);
    o[1] = (__bf16)((v.y - mean) * rstd * gv.y + bv.y);
    o[2] = (__bf16)((v.z - mean) * rstd * gv.z + bv.z);
    o[3] = (__bf16)((v.w - mean) * rstd * gv.w + bv.w);
    *(bf16x4*)(out + (size_t)row * DIM + t * 4) = o;
}

// ---------------- batched weight transpose: all 6 weights in one dispatch --------
__global__ __launch_bounds__(256) void transpose_all(
    const float* __restrict__ wq, const float* __restrict__ wk,
    const float* __restrict__ wv, const float* __restrict__ wo,
    const float* __restrict__ w1, const float* __restrict__ w2,
    __bf16* __restrict__ wqkt, __bf16* __restrict__ wot,
    __bf16* __restrict__ w1t, __bf16* __restrict__ w2t)
{
    int id = blockIdx.x;
    const float* W; __bf16* Wt; int K, N, txt, tyt;
    if (id < 4096) {
        int seg = id >> 10, r = id & 1023;
        K = DIM; N = DIM;
        txt = r & 31; tyt = r >> 5;
        W  = seg == 0 ? wq : seg == 1 ? wk : seg == 2 ? wv : wo;
        Wt = seg < 3 ? wqkt + (size_t)seg * DIM * DIM : wot;
    } else if (id < 8192) {
        int r = id - 4096;
        K = DIM; N = FFD;
        txt = r & 127; tyt = r >> 7;
        W = w1; Wt = w1t;
    } else {
        int r = id - 8192;
        K = FFD; N = DIM;
        txt = r & 31; tyt = r >> 5;
        W = w2; Wt = w2t;
    }
    __shared__ float tile[32][33];
    int bx = txt * 32, by = tyt * 32;
    int tx = threadIdx.x & 31, ty = threadIdx.x >> 5;
    #pragma unroll
    for (int i = 0; i < 32; i += 8)
        tile[ty + i][tx] = W[(size_t)(by + ty + i) * N + bx + tx];
    __syncthreads();
    #pragma unroll
    for (int i = 0; i < 32; i += 8)
        Wt[(size_t)(bx + ty + i) * K + by + tx] = (__bf16)tile[tx][ty + i];
}

// ---------------- v transpose: qkv[:,2048+d] -> vT[d][row] -----------------------
__global__ __launch_bounds__(256) void transpose_v(
    const __bf16* __restrict__ qkv, __bf16* __restrict__ vT)
{
    __shared__ __bf16 tile[64 * 64];
    int bx = blockIdx.x;  // row tile (ROWS/64)
    int by = blockIdx.y;  // d tile (DIM/64)
    int t = threadIdx.x;
    int r0 = t >> 3, sl = t & 7;
    #pragma unroll
    for (int i = 0; i < 2; i++) {
        int row = i * 32 + r0;
        bf16x8 d = *(const bf16x8*)(qkv + (size_t)(bx * 64 + row) * QKP + 2 * DIM + by * 64 + sl * 8);
        *(bf16x8*)&tile[row * 64 + ((sl ^ (row & 7)) << 3)] = d;
    }
    __syncthreads();
    #pragma unroll
    for (int i = 0; i < 2; i++) {
        int d = i * 32 + r0;
        int rbase = sl * 8;
        bf16x8 o;
        #pragma unroll
        for (int j = 0; j < 8; j++) {
            int rr = rbase + j;
            o[j] = tile[rr * 64 + (((((d >> 3)) ^ (rr & 7)) << 3) | (d & 7))];
        }
        *(bf16x8*)(vT + (size_t)(by * 64 + d) * ROWS + bx * 64 + rbase) = o;
    }
}

// ---------------- gemm256: 256xTBN (TBN=NBF*64), BK=64, 8-wave, 4-phase ----------
// Round-12: (a) NBF template (B-frag count per wave: 4->256-wide, 3->192, 2->128);
// (b) cross-phase A-g1 register pre-issue: M1/M3 pre-issue next phase's A-reads
// after their opening barrier (overlapping their own MFMA cluster); M2/M4 are
// pure-MFMA phases. Staging/vmcnt ledger identical to round-11 (race-verified):
//   M1 stages U.A(4); M2 stages T'.B(NBF)+vmcnt(NBF); M3 stages T'.A(4);
//   M4 stages U'.B(NBF)+vmcnt(NBF).
// Pre-issue safety: pre-issued reads of buf.A-g1 are consumed (lgkm) by the
// following phase's MFMA, which precedes the barrier that precedes that
// region's re-staging -> cross-wave overwrite ordering preserved.
#define TBM 256
#define TBK 64
template<int MODE, int OUTBF, int NBF>
__global__ __launch_bounds__(512) void gemm256(
    const __bf16* __restrict__ A, const __bf16* __restrict__ Bt,
    void* __restrict__ Cv, const float* __restrict__ bias,
    const float* __restrict__ res, int M, int N, int K, int Kp,
    int NXT, int NYT, int NS)
{
    constexpr int ASZ = TBM * TBK;            // 16384 elems
    constexpr int BSZ = NBF * 64 * TBK;       // NBF*4096 elems
    __shared__ __bf16 lds[2 * (ASZ + BSZ)];
    int nb = NXT * NYT;
    int sk = blockIdx.x / nb;
    int tx, ty;
    swz_tile(blockIdx.x % nb, NXT, NYT, tx, ty);
    if (NS > 1) {
        A  += (size_t)sk * K;
        Bt += (size_t)sk * K;
        Cv = (void*)((char*)Cv + (size_t)sk * M * N * (OUTBF ? 2 : 4));
    }
    const int bm = ty * TBM, bn = tx * (NBF * 64);
    const int t = threadIdx.x;
    const int l = t & 63, w = t >> 6;
    const int wm = w >> 2, wn = w & 3;        // 2 x 4 waves
    const int lm = l & 15, lk = l >> 4;

    f32x4 acc[8][NBF] = {};
    const int nt = K / TBK;                   // K-tiles (even, >=2)
    const int NIT = nt / 2;

    auto Aoff = [&](int bf) { return bf * (ASZ + BSZ); };
    auto Boff = [&](int bf) { return bf * (ASZ + BSZ) + ASZ; };

    // hoisted per-lane LDS fragment bases
    const int s7 = lm & 7;
    const int c0 = (lk ^ s7) << 3;
    const int c1 = ((4 ^ lk) ^ s7) << 3;
    const __bf16* pA[2][2] = {
        { &lds[Aoff(0) + (wm * 128 + lm) * 64 + c0], &lds[Aoff(0) + (wm * 128 + lm) * 64 + c1] },
        { &lds[Aoff(1) + (wm * 128 + lm) * 64 + c0], &lds[Aoff(1) + (wm * 128 + lm) * 64 + c1] } };
    const __bf16* pB[2][2] = {
        { &lds[Boff(0) + (wn * (NBF * 16) + lm) * 64 + c0], &lds[Boff(0) + (wn * (NBF * 16) + lm) * 64 + c1] },
        { &lds[Boff(1) + (wn * (NBF * 16) + lm) * 64 + c0], &lds[Boff(1) + (wn * (NBF * 16) + lm) * 64 + c1] } };

    // hoisted staging bases: row = u*64+(t>>3); swizzle col const per lane
    const int srow0 = t >> 3;
    const int scol0 = ((t & 7) ^ (srow0 & 7)) * 8;
    const __bf16* gAb = A + (size_t)(bm + srow0) * Kp + scol0;
    const __bf16* gBb = Bt + (size_t)(bn + srow0) * Kp + scol0;
    const int ldsw = w * 512;

    auto STAGEA = [&](int bf, int kt) {       // 4 loads
        #pragma unroll
        for (int u = 0; u < 4; u++)
            __builtin_amdgcn_global_load_lds(
                (const AS1 void*)(gAb + (size_t)(u * 64) * Kp + kt * 64),
                (AS3 void*)(&lds[Aoff(bf) + u * 4096 + ldsw]), 16, 0, 0);
    };
    auto STAGEB = [&](int bf, int kt) {       // NBF loads
        #pragma unroll
        for (int u = 0; u < NBF; u++)
            __builtin_amdgcn_global_load_lds(
                (const AS1 void*)(gBb + (size_t)(u * 64) * Kp + kt * 64),
                (AS3 void*)(&lds[Boff(bf) + u * 4096 + ldsw]), 16, 0, 0);
    };
    auto VMCNT_N = [&]() {
        if constexpr (NBF == 4) asm volatile("s_waitcnt vmcnt(4)" ::: "memory");
        else if constexpr (NBF == 3) asm volatile("s_waitcnt vmcnt(3)" ::: "memory");
        else asm volatile("s_waitcnt vmcnt(2)" ::: "memory");
    };
    auto LDA = [&](int bf, int g, bf16x8* af) {
        #pragma unroll
        for (int j = 0; j < 4; j++) {
            af[j * 2 + 0] = *(const bf16x8*)(pA[bf][0] + (g * 4 + j) * 1024);
            af[j * 2 + 1] = *(const bf16x8*)(pA[bf][1] + (g * 4 + j) * 1024);
        }
    };
    auto LDB = [&](int bf, bf16x8* bfv) {
        #pragma unroll
        for (int n = 0; n < NBF; n++) {
            bfv[n * 2 + 0] = *(const bf16x8*)(pB[bf][0] + n * 1024);
            bfv[n * 2 + 1] = *(const bf16x8*)(pB[bf][1] + n * 1024);
        }
    };
    auto MM2 = [&](int g, bf16x8* af, bf16x8* bfv) {
        __builtin_amdgcn_s_setprio(1);
        #pragma unroll
        for (int j = 0; j < 4; j++)
            #pragma unroll
            for (int n = 0; n < NBF; n++)
                #pragma unroll
                for (int kk = 0; kk < 2; kk++)
                    acc[g * 4 + j][n] = __builtin_amdgcn_mfma_f32_16x16x32_bf16(
                        af[j * 2 + kk], bfv[n * 2 + kk], acc[g * 4 + j][n], 0, 0, 0);
        __builtin_amdgcn_s_setprio(0);
    };

    // ---- prologue: T0.{A,B} + T1.B; vmcnt(NBF) leaves T1.B in flight ----
    STAGEA(0, 0); STAGEB(0, 0); STAGEB(1, 1);
    VMCNT_N();
    __builtin_amdgcn_s_barrier();

    bf16x8 aF[8], aFn[8], bF[2 * NBF];
    for (int it = 0; it < NIT; it++) {
        int u = 2 * it + 1, T2 = 2 * it + 2, U2 = 2 * it + 3;
        // M1: reads T.A-g0 + T.B; stage U.A; after BAR pre-issue T.A-g1
        LDA(0, 0, aF); LDB(0, bF);
        STAGEA(1, u);
        FENCE(); __builtin_amdgcn_s_barrier();
        LDA(0, 1, aFn);
        MM2(0, aF, bF);
        FENCE(); __builtin_amdgcn_s_barrier();
        // M2: pure MFMA on pre-issued aFn; stage T'.B; vmcnt(NBF) -> buf1 ready
        if (T2 < nt) {
            STAGEB(0, T2);
            VMCNT_N();
        } else {
            asm volatile("s_waitcnt vmcnt(0)" ::: "memory");
        }
        __builtin_amdgcn_s_barrier();
        MM2(1, aFn, bF);
        FENCE(); __builtin_amdgcn_s_barrier();
        // M3: reads U.A-g0 + U.B; stage T'.A; after BAR pre-issue U.A-g1
        LDA(1, 0, aF); LDB(1, bF);
        if (T2 < nt) STAGEA(0, T2);
        FENCE(); __builtin_amdgcn_s_barrier();
        LDA(1, 1, aFn);
        MM2(0, aF, bF);
        FENCE(); __builtin_amdgcn_s_barrier();
        // M4: pure MFMA on aFn; stage U'.B; vmcnt(NBF) -> buf0 ready for next M1
        if (U2 < nt) {
            STAGEB(1, U2);
            VMCNT_N();
        } else {
            asm volatile("s_waitcnt vmcnt(0)" ::: "memory");
        }
        __builtin_amdgcn_s_barrier();
        MM2(1, aFn, bF);
        FENCE(); __builtin_amdgcn_s_barrier();
    }

    // epilogue: C/D layout col=lane&15, row=(lane>>4)*4+r
    #pragma unroll
    for (int m = 0; m < 8; m++) {
        #pragma unroll
        for (int n = 0; n < NBF; n++) {
            int col = bn + wn * (NBF * 16) + n * 16 + lm;
            #pragma unroll
            for (int r = 0; r < 4; r++) {
                int row = bm + wm * 128 + m * 16 + lk * 4 + r;
                float v = acc[m][n][r];
                if (MODE == 1) v += res[(size_t)row * N + col] + bias[col];
                if (MODE == 2) v = gelu_fast(v + bias[col]);
                if (OUTBF) ((__bf16*)Cv)[(size_t)row * N + col] = (__bf16)v;
                else       ((float*)Cv)[(size_t)row * N + col] = v;
            }
        }
    }
}

// ---------------- reduce4ln: x += bias + sum of 4 bf16 partials; optional LN -----
template<int DOLN>
__global__ __launch_bounds__(256) void reduce4ln(
    const __bf16* __restrict__ parts, const float* __restrict__ bias,
    float* __restrict__ x, const float* __restrict__ g,
    const float* __restrict__ b, __bf16* __restrict__ xn)
{
    const size_t PS = (size_t)ROWS * DIM;
    int row = blockIdx.x, t = threadIdx.x;
    size_t base = (size_t)row * DIM + t * 4;
    float4 xr = *(const float4*)(x + base);
    float4 bv = ((const float4*)bias)[t];
    float o0 = xr.x + bv.x, o1 = xr.y + bv.y, o2 = xr.z + bv.z, o3 = xr.w + bv.w;
    #pragma unroll
    for (int s = 0; s < 4; s++) {
        bf16x4 p = *(const bf16x4*)(parts + s * PS + base);
        o0 += (float)p[0]; o1 += (float)p[1]; o2 += (float)p[2]; o3 += (float)p[3];
    }
    float4 o = {o0, o1, o2, o3};
    *(float4*)(x + base) = o;
    if constexpr (DOLN) {
        float s  = o0 + o1 + o2 + o3;
        float ss = o0*o0 + o1*o1 + o2*o2 + o3*o3;
        #pragma unroll
        for (int off = 32; off > 0; off >>= 1) {
            s  += __shfl_down(s, off);
            ss += __shfl_down(ss, off);
        }
        __shared__ float wsum[4], wsq[4], stats[2];
        int wid = t >> 6, lane = t & 63;
        if (lane == 0) { wsum[wid] = s; wsq[wid] = ss; }
        __syncthreads();
        if (t == 0) {
            float S  = wsum[0] + wsum[1] + wsum[2] + wsum[3];
            float SS = wsq[0] + wsq[1] + wsq[2] + wsq[3];
            float mean = S * (1.0f / DIM);
            float var  = SS * (1.0f / DIM) - mean * mean;
            stats[0] = mean;
            stats[1] = rsqrtf(var + 1e-5f);
        }
        __syncthreads();
        float mean = stats[0], rstd = stats[1];
        float4 gv = ((const float4*)g)[t];
        float4 bvv = ((const float4*)b)[t];
        bf16x4 on;
        on[0] = (__bf16)((o0 - mean) * rstd * gv.x + bvv.x);
        on[1] = (__bf16)((o1 - mean) * rstd * gv.y + bvv.y);
        on[2] = (__bf16)((o2 - mean) * rstd * gv.z + bvv.z);
        on[3] = (__bf16)((o3 - mean) * rstd * gv.w + bvv.w);
        *(bf16x4*)(xn + base) = on;
    }
}

// ---------------- attn kernel A: per-chunk KVT_c[e][d] = sum_m v[m][e]ek[m][d] --
__global__ __launch_bounds__(256) void attn_local_m(
    const __bf16* __restrict__ qkv, const __bf16* __restrict__ vTg,
    float* __restrict__ KVT, float* __restrict__ Ksum)
{
    int blk = blockIdx.x;
    int c = blk % NCHK, bh = blk / NCHK;
    int b = bh / NH, h = bh % NH;
    __shared__ __bf16 ek_s[64 * 64];
    __shared__ __bf16 ekT_s[64 * 68];
    __shared__ float ksum_p[4][64];
    int t = threadIdx.x, w = t >> 6, l = t & 63;
    size_t rowbase = (size_t)(b * SEQ + c * CHK);

    {
        int m = t >> 2, dq = t & 3;
        const __bf16* kr = qkv + (rowbase + m) * QKP + DIM + h * DH + dq * 16;
        bf16x8 k0 = *(const bf16x8*)kr;
        bf16x8 k1 = *(const bf16x8*)(kr + 8);
        bf16x8 e0, e1;
        #pragma unroll
        for (int j = 0; j < 8; j++) {
            e0[j] = (__bf16)__expf((float)k0[j]);
            e1[j] = (__bf16)__expf((float)k1[j]);
        }
        *(bf16x8*)&ek_s[swz128(m, dq * 16)] = e0;
        *(bf16x8*)&ek_s[swz128(m, dq * 16 + 8)] = e1;
    }
    __syncthreads();
    {
        float kacc = 0.f;
        #pragma unroll
        for (int g = 0; g < 4; g++) {
            bf16x4 pk;
            #pragma unroll
            for (int j = 0; j < 4; j++) {
                __bf16 e = ek_s[swz128(w * 16 + g * 4 + j, l)];
                pk[j] = e;
                kacc += (float)e;
            }
            *(bf16x4*)&ekT_s[l * 68 + w * 16 + g * 4] = pk;
        }
        ksum_p[w][l] = kacc;
    }
    __syncthreads();
    f32x4 acc[4] = {};
    const __bf16* vbase = vTg + (size_t)(h * DH + w * 16 + (l & 15)) * ROWS
                        + (size_t)b * SEQ + c * CHK + (l >> 4) * 8;
    bf16x8 a0 = *(const bf16x8*)vbase;
    bf16x8 a1 = *(const bf16x8*)(vbase + 32);
    #pragma unroll
    for (int fn = 0; fn < 4; fn++) {
        int rbase = (fn * 16 + (l & 15)) * 68 + (l >> 4) * 8;
        bf16x4 b0a = *(const bf16x4*)&ekT_s[rbase];
        bf16x4 b0b = *(const bf16x4*)&ekT_s[rbase + 4];
        bf16x4 b1a = *(const bf16x4*)&ekT_s[rbase + 32];
        bf16x4 b1b = *(const bf16x4*)&ekT_s[rbase + 36];
        bf16x8 b0, b1;
        #pragma unroll
        for (int j = 0; j < 4; j++) {
            b0[j] = b0a[j]; b0[j + 4] = b0b[j];
            b1[j] = b1a[j]; b1[j + 4] = b1b[j];
        }
        acc[fn] = __builtin_amdgcn_mfma_f32_16x16x32_bf16(a0, b0, acc[fn], 0, 0, 0);
        acc[fn] = __builtin_amdgcn_mfma_f32_16x16x32_bf16(a1, b1, acc[fn], 0, 0, 0);
    }
    float* kvout = KVT + (size_t)(bh * NCHK + c) * (DH * DH);
    #pragma unroll
    for (int fn = 0; fn < 4; fn++)
        #pragma unroll
        for (int r = 0; r < 4; r++)
            kvout[(w * 16 + (l >> 4) * 4 + r) * DH + fn * 16 + (l & 15)] = acc[fn][r];
    if (t < 64) {
        float s = ksum_p[0][t] + ksum_p[1][t] + ksum_p[2][t] + ksum_p[3][t];
        Ksum[(size_t)(bh * NCHK + c) * DH + t] = s;
    }
}

// ---------------- attn kernel B: parallel exclusive prefix over chunks ----------
__global__ __launch_bounds__(256) void attn_scan2(
    float* __restrict__ KV, float* __restrict__ Ksum)
{
    int bh = blockIdx.y;
    int bx = blockIdx.x;
    int t = threadIdx.x;
    if (bx < 16) {
        int elem = bx * 256 + t;
        float run = 0.f;
        for (int c = 0; c < NCHK; c++) {
            float* p = KV + ((size_t)(bh * NCHK + c)) * (DH * DH) + elem;
            float tmp = *p;
            *p = run;
            run += tmp;
        }
    } else if (t < DH) {
        float run = 0.f;
        for (int c = 0; c < NCHK; c++) {
            float* p = Ksum + ((size_t)(bh * NCHK + c)) * DH + t;
            float tmp = *p;
            *p = run;
            run += tmp;
        }
    }
}

// ---------------- attn kernel C: per-chunk output via MFMA ----------------------
__global__ __launch_bounds__(256) void attn_out_m(
    const __bf16* __restrict__ qkv, const __bf16* __restrict__ vTg,
    const float* __restrict__ KVT, const float* __restrict__ Ksum,
    __bf16* __restrict__ ag)
{
    int blk = blockIdx.x;
    int c = blk % NCHK, bh = blk / NCHK;
    int b = bh / NH, h = bh % NH;
    __shared__ __bf16 q_s[64 * 64];
    __shared__ __bf16 ek_s[64 * 64];
    __shared__ __bf16 s_s[64 * 64];
    __shared__ __bf16 kvT_s[64 * 64];
    __shared__ float denom_s[64];
    int t = threadIdx.x, w = t >> 6, l = t & 63;
    size_t rowbase = (size_t)(b * SEQ + c * CHK);

    {
        int i = t >> 2, dq = t & 3;
        const __bf16* qr = qkv + (rowbase + i) * QKP + h * DH + dq * 16;
        bf16x8 q0 = *(const bf16x8*)qr, q1 = *(const bf16x8*)(qr + 8);
        float qf[16];
        #pragma unroll
        for (int j = 0; j < 8; j++) { qf[j] = (float)q0[j]; qf[8 + j] = (float)q1[j]; }
        float mx = qf[0];
        #pragma unroll
        for (int j = 1; j < 16; j++) mx = fmaxf(mx, qf[j]);
        mx = fmaxf(mx, __shfl_xor(mx, 1));
        mx = fmaxf(mx, __shfl_xor(mx, 2));
        float ss = 0.f;
        #pragma unroll
        for (int j = 0; j < 16; j++) { qf[j] = __expf(qf[j] - mx); ss += qf[j]; }
        ss += __shfl_xor(ss, 1);
        ss += __shfl_xor(ss, 2);
        float sc = 0.125f / ss;
        bf16x8 o0, o1;
        #pragma unroll
        for (int j = 0; j < 8; j++) {
            o0[j] = (__bf16)(qf[j] * sc);
            o1[j] = (__bf16)(qf[8 + j] * sc);
        }
        *(bf16x8*)&q_s[swz128(i, dq * 16)] = o0;
        *(bf16x8*)&q_s[swz128(i, dq * 16 + 8)] = o1;
        const float* kp = Ksum + (size_t)(bh * NCHK + c) * DH + dq * 16;
        float dk = 0.f;
        #pragma unroll
        for (int j = 0; j < 16; j++) dk += (qf[j] * sc) * kp[j];
        dk += __shfl_xor(dk, 1);
        dk += __shfl_xor(dk, 2);
        if (dq == 0) denom_s[i] = dk;
    }
    {
        int m = t >> 2, dq = t & 3;
        const __bf16* kr = qkv + (rowbase + m) * QKP + DIM + h * DH + dq * 16;
        bf16x8 k0 = *(const bf16x8*)kr, k1 = *(const bf16x8*)(kr + 8);
        bf16x8 e0, e1;
        #pragma unroll
        for (int j = 0; j < 8; j++) {
            e0[j] = (__bf16)__expf((float)k0[j]);
            e1[j] = (__bf16)__expf((float)k1[j]);
        }
        *(bf16x8*)&ek_s[swz128(m, dq * 16)] = e0;
        *(bf16x8*)&ek_s[swz128(m, dq * 16 + 8)] = e1;
    }
    {
        int e = t >> 2, dq = t & 3;
        const float* kvr = KVT + (size_t)(bh * NCHK + c) * (DH * DH) + e * DH + dq * 16;
        bf16x8 o0, o1;
        #pragma unroll
        for (int j = 0; j < 8; j++) { o0[j] = (__bf16)kvr[j]; o1[j] = (__bf16)kvr[8 + j]; }
        *(bf16x8*)&kvT_s[swz128(e, dq * 16)] = o0;
        *(bf16x8*)&kvT_s[swz128(e, dq * 16 + 8)] = o1;
    }
    __syncthreads();

    bf16x8 bq0 = *(const bf16x8*)&q_s[swz128(w * 16 + (l & 15), (l >> 4) * 8)];
    bf16x8 bq1 = *(const bf16x8*)&q_s[swz128(w * 16 + (l & 15), 32 + (l >> 4) * 8)];
    int i_col = w * 16 + (l & 15);
    float dsum = 0.f;
    #pragma unroll
    for (int fm = 0; fm < 4; fm++) {
        bf16x8 ae0 = *(const bf16x8*)&ek_s[swz128(fm * 16 + (l & 15), (l >> 4) * 8)];
        bf16x8 ae1 = *(const bf16x8*)&ek_s[swz128(fm * 16 + (l & 15), 32 + (l >> 4) * 8)];
        f32x4 z = {};
        z = __builtin_amdgcn_mfma_f32_16x16x32_bf16(ae0, bq0, z, 0, 0, 0);
        z = __builtin_amdgcn_mfma_f32_16x16x32_bf16(ae1, bq1, z, 0, 0, 0);
        bf16x4 pk;
        #pragma unroll
        for (int r = 0; r < 4; r++) {
            int m = fm * 16 + (l >> 4) * 4 + r;
            float v = (m <= i_col) ? z[r] : 0.f;
            pk[r] = (__bf16)v;
            dsum += (float)pk[r];
        }
        *(bf16x4*)&s_s[swz128(i_col, fm * 16 + (l >> 4) * 4)] = pk;
    }
    dsum += __shfl_xor(dsum, 16);
    dsum += __shfl_xor(dsum, 32);
    if (l < 16) denom_s[w * 16 + l] += dsum;

    bf16x8 as0 = *(const bf16x8*)&s_s[swz128(w * 16 + (l & 15), (l >> 4) * 8)];
    bf16x8 as1 = *(const bf16x8*)&s_s[swz128(w * 16 + (l & 15), 32 + (l >> 4) * 8)];
    f32x4 oacc[4] = {};
    #pragma unroll
    for (int fn = 0; fn < 4; fn++) {
        const __bf16* vb = vTg + (size_t)(h * DH + fn * 16 + (l & 15)) * ROWS
                         + (size_t)b * SEQ + c * CHK + (l >> 4) * 8;
        bf16x8 bv0 = *(const bf16x8*)vb;
        bf16x8 bv1 = *(const bf16x8*)(vb + 32);
        bf16x8 bk0 = *(const bf16x8*)&kvT_s[swz128(fn * 16 + (l & 15), (l >> 4) * 8)];
        bf16x8 bk1 = *(const bf16x8*)&kvT_s[swz128(fn * 16 + (l & 15), 32 + (l >> 4) * 8)];
        f32x4 z = oacc[fn];
        z = __builtin_amdgcn_mfma_f32_16x16x32_bf16(as0, bv0, z, 0, 0, 0);
        z = __builtin_amdgcn_mfma_f32_16x16x32_bf16(as1, bv1, z, 0, 0, 0);
        z = __builtin_amdgcn_mfma_f32_16x16x32_bf16(bq0, bk0, z, 0, 0, 0);
        z = __builtin_amdgcn_mfma_f32_16x16x32_bf16(bq1, bk1, z, 0, 0, 0);
        oacc[fn] = z;
    }
    #pragma unroll
    for (int r = 0; r < 4; r++) {
        int i = w * 16 + (l >> 4) * 4 + r;
        float dinv = 1.0f / fmaxf(denom_s[i], 1e-3f);
        #pragma unroll
        for (int fn = 0; fn < 4; fn++)
            ag[(rowbase + i) * DIM + h * DH + fn * 16 + (l & 15)] = (__bf16)(oacc[fn][r] * dinv);
    }
}

// ---------------- launch --------------------------------------------------------
extern "C" void kernel_launch(void* const* d_in, const int* in_sizes, int n_in,
                              void* d_out, int out_size, void* d_ws, size_t ws_size,
                              hipStream_t stream) {
    (void)in_sizes; (void)n_in; (void)out_size; (void)ws_size;
    const float* x_in  = (const float*)d_in[0];
    const float* ln1_g = (const float*)d_in[1];
    const float* ln1_b = (const float*)d_in[2];
    const float* Wq    = (const float*)d_in[3];
    const float* Wk    = (const float*)d_in[4];
    const float* Wv    = (const float*)d_in[5];
    const float* Wo    = (const float*)d_in[6];
    const float* bo    = (const float*)d_in[7];
    const float* ln2_g = (const float*)d_in[8];
    const float* ln2_b = (const float*)d_in[9];
    const float* W1    = (const float*)d_in[10];
    const float* b1    = (const float*)d_in[11];
    const float* W2    = (const float*)d_in[12];
    const float* b2    = (const float*)d_in[13];

    float* x = (float*)d_out;
    const size_t MB = 1024 * 1024;
    char* base = (char*)d_ws;

    __bf16* qkv    = (__bf16*)base;
    __bf16* partsO = (__bf16*)base;
    __bf16* h1     = (__bf16*)base;
    __bf16* vTg    = (__bf16*)(base + 24 * MB);
    __bf16* xn     = (__bf16*)(base + 32 * MB);
    __bf16* parts  = (__bf16*)(base + 32 * MB);
    __bf16* a      = (__bf16*)(base + 40 * MB);
    float*  KVT    = (float*)(base + 48 * MB);
    float*  Ks     = (float*)(base + 64 * MB);
    __bf16* wqkt   = (__bf16*)(base + 65 * MB);  // 6MB
    __bf16* wot    = (__bf16*)(base + 71 * MB);  // 2MB
    __bf16* w1t    = (__bf16*)(base + 73 * MB);  // 8MB
    __bf16* w2t    = (__bf16*)(base + 81 * MB);  // 8MB

    const size_t SZ = (size_t)ROWS * DIM;
    hipMemcpyAsync(x, x_in, SZ * sizeof(float), hipMemcpyDeviceToDevice, stream);

    dim3 gScan(17, BB * NH);
    dim3 gTv(ROWS / 64, DIM / 64);

    for (int l = 0; l < DEPTH; l++) {
        const float* wq = Wq + (size_t)l * DIM * DIM;
        const float* wk = Wk + (size_t)l * DIM * DIM;
        const float* wv = Wv + (size_t)l * DIM * DIM;
        const float* wo = Wo + (size_t)l * DIM * DIM;
        const float* w1 = W1 + (size_t)l * DIM * FFD;
        const float* w2 = W2 + (size_t)l * FFD * DIM;

        transpose_all<<<12288, 256, 0, stream>>>(wq, wk, wv, wo, w1, w2,
                                                 wqkt, wot, w1t, w2t);

        // pre-norm attention block
        if (l == 0)
            ln_kernel<<<ROWS, 256, 0, stream>>>(x, ln1_g, ln1_b, xn);
        // fused QKV: N=3072 via TBN=192 (NBF=3) -> 16x16 = 256 blocks (full chip)
        gemm256<0, 1, 3><<<16 * 16, 512, 0, stream>>>(xn, wqkt, qkv, nullptr, nullptr,
                                                      ROWS, QKP, DIM, DIM, 16, 16, 1);
        transpose_v<<<gTv, 256, 0, stream>>>(qkv, vTg);
        attn_local_m<<<BB * NH * NCHK, 256, 0, stream>>>(qkv, vTg, KVT, Ks);
        attn_scan2<<<gScan, 256, 0, stream>>>(KVT, Ks);
        attn_out_m<<<BB * NH * NCHK, 256, 0, stream>>>(qkv, vTg, KVT, Ks, a);
        // O-proj: split-K 4 over K=1024 -> bf16 partials (qkv/vTg dead)
        gemm256<0, 1, 4><<<4 * 16 * 4, 512, 0, stream>>>(a, wot, partsO, nullptr, nullptr,
                                                         ROWS, DIM, DIM / 4, DIM, 4, 16, 4);
        reduce4ln<1><<<ROWS, 256, 0, stream>>>(partsO, bo + l * DIM, x,
                                               ln2_g + l * DIM, ln2_b + l * DIM, xn);

        // pre-norm FF block (partsO dead -> h1 aliases)
        gemm256<2, 1, 4><<<16 * 16, 512, 0, stream>>>(xn, w1t, h1, b1 + l * FFD, nullptr,
                                                      ROWS, FFD, DIM, DIM, 16, 16, 1);
        gemm256<0, 1, 4><<<4 * 16 * 4, 512, 0, stream>>>(h1, w2t, parts, nullptr, nullptr,
                                                         ROWS, DIM, FFD / 4, FFD, 4, 16, 4);
        if (l + 1 < DEPTH)
            reduce4ln<1><<<ROWS, 256, 0, stream>>>(parts, b2 + l * DIM, x,
                                                   ln1_g + (l + 1) * DIM,
                                                   ln1_b + (l + 1) * DIM, xn);
        else
            reduce4ln<0><<<ROWS, 256, 0, stream>>>(parts, b2 + l * DIM, x,
                                                   nullptr, nullptr, nullptr);
    }
}

// Round 13
// 390.509 us; speedup vs baseline: 11.4373x; 1.0007x over previous
//
#include <hip/hip_runtime.h>
#include <cmath>

#define BB 2
#define SEQ 2048
#define DIM 1024
#define NH 16
#define DH 64
#define DEPTH 2
#define FFD 4096
#define CHK 64
#define NCHK (SEQ/CHK)      // 32
#define ROWS (BB*SEQ)       // 4096
#define QKP (3*DIM)         // fused qkv row pitch (3072)

typedef __bf16 bf16x8 __attribute__((ext_vector_type(8)));
typedef __bf16 bf16x4 __attribute__((ext_vector_type(4)));
typedef float  f32x4  __attribute__((ext_vector_type(4)));

#define AS1 __attribute__((address_space(1)))
#define AS3 __attribute__((address_space(3)))
#define FENCE() asm volatile("" ::: "memory")
#define LGKM0() asm volatile("s_waitcnt lgkmcnt(0)" ::: "memory")

template<int N> __device__ __forceinline__ void vmcnt_wait() {
    if constexpr (N == 0) asm volatile("s_waitcnt vmcnt(0)" ::: "memory");
    else if constexpr (N == 3) asm volatile("s_waitcnt vmcnt(3)" ::: "memory");
    else if constexpr (N == 4) asm volatile("s_waitcnt vmcnt(4)" ::: "memory");
    else if constexpr (N == 5) asm volatile("s_waitcnt vmcnt(5)" ::: "memory");
    else asm volatile("s_waitcnt vmcnt(6)" ::: "memory");
}

// tanh-form GELU: |err| < 1e-3 vs exact; invisible under bf16 rounding
__device__ __forceinline__ float gelu_fast(float x) {
    float x3 = x * x * x;
    float y = 1.5957691216057308f * (x + 0.044715f * x3);
    return x * __builtin_amdgcn_rcpf(1.0f + __expf(-y));
}

// swizzled halfword index into a row-pitch-64hw (128B) bf16 tile
__device__ __forceinline__ int swz128(int row, int col) {
    return row * 64 + (col ^ ((row & 7) << 3));
}

// T1: XCD-contiguous bijective block swizzle (m204) + width-4 column-group order
__device__ __forceinline__ void swz_tile(int bid, int NX, int NY, int& tx, int& ty) {
    int NB = NX * NY;
    int q = NB >> 3, r = NB & 7;
    int xcd = bid & 7, seq = bid >> 3;
    int start = (xcd < r) ? xcd * (q + 1) : r * (q + 1) + (xcd - r) * q;
    int wgid = start + seq;
    int g = 0, rem = wgid;
    int gw = (NX < 4) ? NX : 4;
    while (rem >= gw * NY) {
        rem -= gw * NY; g++;
        int left = NX - 4 * g;
        gw = left < 4 ? left : 4;
    }
    ty = rem / gw;
    tx = 4 * g + rem % gw;
}

// ---------------- LayerNorm (standalone; used only for layer-0 ln1) -------------
__global__ __launch_bounds__(256) void ln_kernel(
    const float* __restrict__ x, const float* __restrict__ g,
    const float* __restrict__ b, __bf16* __restrict__ out)
{
    int row = blockIdx.x;
    const float4* xr = (const float4*)(x + (size_t)row * DIM);
    int t = threadIdx.x;
    float4 v = xr[t];
    float s  = v.x + v.y + v.z + v.w;
    float ss = v.x*v.x + v.y*v.y + v.z*v.z + v.w*v.w;
    #pragma unroll
    for (int off = 32; off > 0; off >>= 1) {
        s  += __shfl_down(s, off);
        ss += __shfl_down(ss, off);
    }
    __shared__ float wsum[4], wsq[4], stats[2];
    int wid = t >> 6, lane = t & 63;
    if (lane == 0) { wsum[wid] = s; wsq[wid] = ss; }
    __syncthreads();
    if (t == 0) {
        float S  = wsum[0] + wsum[1] + wsum[2] + wsum[3];
        float SS = wsq[0] + wsq[1] + wsq[2] + wsq[3];
        float mean = S * (1.0f / DIM);
        float var  = SS * (1.0f / DIM) - mean * mean;
        stats[0] = mean;
        stats[1] = rsqrtf(var + 1e-5f);
    }
    __syncthreads();
    float mean = stats[0], rstd = stats[1];
    float4 gv = ((const float4*)g)[t];
    float4 bv = ((const float4*)b)[t];
    bf16x4 o;
    o[0] = (__bf16)((v.x - mean) * rstd * gv.x + bv.x);
    o[1] = (__bf16)((v.y - mean) * rstd * gv.y + bv.y);
    o[2] = (__bf16)((v.z - mean) * rstd * gv.z + bv.z);
    o[3] = (__bf16)((v.w - mean) * rstd * gv.w + bv.w);
    *(bf16x4*)(out + (size_t)row * DIM + t * 4) = o;
}

// ---------------- batched weight transpose: all 6 weights in one dispatch --------
__global__ __launch_bounds__(256) void transpose_all(
    const float* __restrict__ wq, const float* __restrict__ wk,
    const float* __restrict__ wv, const float* __restrict__ wo,
    const float* __restrict__ w1, const float* __restrict__ w2,
    __bf16* __restrict__ wqkt, __bf16* __restrict__ wot,
    __bf16* __restrict__ w1t, __bf16* __restrict__ w2t)
{
    int id = blockIdx.x;
    const float* W; __bf16* Wt; int K, N, txt, tyt;
    if (id < 4096) {
        int seg = id >> 10, r = id & 1023;
        K = DIM; N = DIM;
        txt = r & 31; tyt = r >> 5;
        W  = seg == 0 ? wq : seg == 1 ? wk : seg == 2 ? wv : wo;
        Wt = seg < 3 ? wqkt + (size_t)seg * DIM * DIM : wot;
    } else if (id < 8192) {
        int r = id - 4096;
        K = DIM; N = FFD;
        txt = r & 127; tyt = r >> 7;
        W = w1; Wt = w1t;
    } else {
        int r = id - 8192;
        K = FFD; N = DIM;
        txt = r & 31; tyt = r >> 5;
        W = w2; Wt = w2t;
    }
    __shared__ float tile[32][33];
    int bx = txt * 32, by = tyt * 32;
    int tx = threadIdx.x & 31, ty = threadIdx.x >> 5;
    #pragma unroll
    for (int i = 0; i < 32; i += 8)
        tile[ty + i][tx] = W[(size_t)(by + ty + i) * N + bx + tx];
    __syncthreads();
    #pragma unroll
    for (int i = 0; i < 32; i += 8)
        Wt[(size_t)(bx + ty + i) * K + by + tx] = (__bf16)tile[tx][ty + i];
}

// ---------------- v transpose: qkv[:,2048+d] -> vT[d][row] -----------------------
__global__ __launch_bounds__(256) void transpose_v(
    const __bf16* __restrict__ qkv, __bf16* __restrict__ vT)
{
    __shared__ __bf16 tile[64 * 64];
    int bx = blockIdx.x;  // row tile (ROWS/64)
    int by = blockIdx.y;  // d tile (DIM/64)
    int t = threadIdx.x;
    int r0 = t >> 3, sl = t & 7;
    #pragma unroll
    for (int i = 0; i < 2; i++) {
        int row = i * 32 + r0;
        bf16x8 d = *(const bf16x8*)(qkv + (size_t)(bx * 64 + row) * QKP + 2 * DIM + by * 64 + sl * 8);
        *(bf16x8*)&tile[row * 64 + ((sl ^ (row & 7)) << 3)] = d;
    }
    __syncthreads();
    #pragma unroll
    for (int i = 0; i < 2; i++) {
        int d = i * 32 + r0;
        int rbase = sl * 8;
        bf16x8 o;
        #pragma unroll
        for (int j = 0; j < 8; j++) {
            int rr = rbase + j;
            o[j] = tile[rr * 64 + (((((d >> 3)) ^ (rr & 7)) << 3) | (d & 7))];
        }
        *(bf16x8*)(vT + (size_t)(by * 64 + d) * ROWS + bx * 64 + rbase) = o;
    }
}

// ---------------- gemm256: 256xTBN, BK=64, 8-wave, m201-style 8-phase ------------
// Round-13: faithful fine-interleave port. Per K-tile (4 phases, 16-MFMA each):
//   Ph.1: read aH<-A-m0(8) + bH0<-B-n0(4) -> MFMA m0 x n0
//   Ph.2: read bH1<-B-n1(4|2)             -> MFMA m0 x n1
//   Ph.3: read aH<-A-m1(8)                -> MFMA m1 x n1   (bH1 reg reuse)
//   Ph.4: no reads                        -> MFMA m1 x n0   (bH0,aH reg reuse)
// Stage units (2 loads; NBF=3 B-h1 is 1): Ph1:U.A1 Ph3:T'.B0 Ph4:T'.B1+vmcnt(VM4)
// Ph5:T'.A0 Ph6:T'.A1 Ph7:U'.B0+B1 Ph8:U'.A0+vmcnt(VM8). Ledger verified:
// VM4 leaves T'.B0+B1 (buf1=U complete); VM8 leaves U'.B+A0 (buf0=T' complete).
// Every phase's ds_reads drain at its own lgkmcnt(0) -> no cross-phase LDS hazard.
#define TBM 256
#define TBK 64
template<int MODE, int OUTBF, int NBF>
__global__ __launch_bounds__(512) void gemm256(
    const __bf16* __restrict__ A, const __bf16* __restrict__ Bt,
    void* __restrict__ Cv, const float* __restrict__ bias,
    const float* __restrict__ res, int M, int N, int K, int Kp,
    int NXT, int NYT, int NS)
{
    constexpr int ASZ = TBM * TBK;            // 16384 elems
    constexpr int BSZ = NBF * 64 * TBK;       // NBF*4096 elems
    constexpr int VM4 = (NBF == 4) ? 4 : 3;
    constexpr int VM8 = (NBF == 4) ? 6 : 5;
    __shared__ __bf16 lds[2 * (ASZ + BSZ)];
    int nb = NXT * NYT;
    int sk = blockIdx.x / nb;
    int tx, ty;
    swz_tile(blockIdx.x % nb, NXT, NYT, tx, ty);
    if (NS > 1) {
        A  += (size_t)sk * K;
        Bt += (size_t)sk * K;
        Cv = (void*)((char*)Cv + (size_t)sk * M * N * (OUTBF ? 2 : 4));
    }
    const int bm = ty * TBM, bn = tx * (NBF * 64);
    const int t = threadIdx.x;
    const int l = t & 63, w = t >> 6;
    const int wm = w >> 2, wn = w & 3;        // 2 x 4 waves
    const int lm = l & 15, lk = l >> 4;

    f32x4 acc[8][NBF] = {};
    const int nt = K / TBK;                   // K-tiles (even, >=4)
    const int NIT = nt / 2;

    auto Aoff = [&](int bf) { return bf * (ASZ + BSZ); };
    auto Boff = [&](int bf) { return bf * (ASZ + BSZ) + ASZ; };

    // hoisted per-lane LDS fragment bases
    const int s7 = lm & 7;
    const int c0 = (lk ^ s7) << 3;
    const int c1 = ((4 ^ lk) ^ s7) << 3;
    const __bf16* pA[2][2] = {
        { &lds[Aoff(0) + (wm * 128 + lm) * 64 + c0], &lds[Aoff(0) + (wm * 128 + lm) * 64 + c1] },
        { &lds[Aoff(1) + (wm * 128 + lm) * 64 + c0], &lds[Aoff(1) + (wm * 128 + lm) * 64 + c1] } };
    const __bf16* pB[2][2] = {
        { &lds[Boff(0) + (wn * (NBF * 16) + lm) * 64 + c0], &lds[Boff(0) + (wn * (NBF * 16) + lm) * 64 + c1] },
        { &lds[Boff(1) + (wn * (NBF * 16) + lm) * 64 + c0], &lds[Boff(1) + (wn * (NBF * 16) + lm) * 64 + c1] } };

    // hoisted staging bases
    const int srow0 = t >> 3;
    const int scol0 = ((t & 7) ^ (srow0 & 7)) * 8;
    const __bf16* gAb = A + (size_t)(bm + srow0) * Kp + scol0;
    const __bf16* gBb = Bt + (size_t)(bn + srow0) * Kp + scol0;
    const int ldsw = w * 512;

    auto STAGEA_H = [&](int bf, int hf, int kt) {    // 2 loads
        #pragma unroll
        for (int i = 0; i < 2; i++) {
            int u = hf * 2 + i;
            __builtin_amdgcn_global_load_lds(
                (const AS1 void*)(gAb + (size_t)(u * 64) * Kp + kt * 64),
                (AS3 void*)(&lds[Aoff(bf) + u * 4096 + ldsw]), 16, 0, 0);
        }
    };
    auto STAGEB_H = [&](int bf, int hf, int kt) {    // 2 loads (NBF3 hf1: 1)
        const int cnt = (NBF == 4) ? 2 : (hf == 0 ? 2 : 1);
        const int u0  = (NBF == 4) ? hf * 2 : (hf == 0 ? 0 : 2);
        #pragma unroll
        for (int i = 0; i < 2; i++) {
            if (i < cnt) {
                int u = u0 + i;
                __builtin_amdgcn_global_load_lds(
                    (const AS1 void*)(gBb + (size_t)(u * 64) * Kp + kt * 64),
                    (AS3 void*)(&lds[Boff(bf) + u * 4096 + ldsw]), 16, 0, 0);
            }
        }
    };
    auto LDA = [&](int bf, int g, bf16x8* aH) {      // 8 reads: m-half g
        #pragma unroll
        for (int j = 0; j < 4; j++) {
            aH[j * 2 + 0] = *(const bf16x8*)(pA[bf][0] + (g * 4 + j) * 1024);
            aH[j * 2 + 1] = *(const bf16x8*)(pA[bf][1] + (g * 4 + j) * 1024);
        }
    };
    auto LDB0 = [&](int bf, bf16x8* b0) {            // 4 reads: n frags 0,1
        #pragma unroll
        for (int n = 0; n < 2; n++) {
            b0[n * 2 + 0] = *(const bf16x8*)(pB[bf][0] + n * 1024);
            b0[n * 2 + 1] = *(const bf16x8*)(pB[bf][1] + n * 1024);
        }
    };
    auto LDB1 = [&](int bf, bf16x8* b1) {            // n frags 2..NBF-1
        #pragma unroll
        for (int n = 0; n < NBF - 2; n++) {
            b1[n * 2 + 0] = *(const bf16x8*)(pB[bf][0] + (2 + n) * 1024);
            b1[n * 2 + 1] = *(const bf16x8*)(pB[bf][1] + (2 + n) * 1024);
        }
    };
    auto MMQ0 = [&](int g, bf16x8* aH, bf16x8* b0) { // 16 MFMA: m-half g x n{0,1}
        __builtin_amdgcn_s_setprio(1);
        #pragma unroll
        for (int j = 0; j < 4; j++)
            #pragma unroll
            for (int nn = 0; nn < 2; nn++)
                #pragma unroll
                for (int kk = 0; kk < 2; kk++)
                    acc[g * 4 + j][nn] = __builtin_amdgcn_mfma_f32_16x16x32_bf16(
                        aH[j * 2 + kk], b0[nn * 2 + kk], acc[g * 4 + j][nn], 0, 0, 0);
        __builtin_amdgcn_s_setprio(0);
    };
    auto MMQ1 = [&](int g, bf16x8* aH, bf16x8* b1) { // m-half g x n{2..NBF-1}
        __builtin_amdgcn_s_setprio(1);
        #pragma unroll
        for (int j = 0; j < 4; j++)
            #pragma unroll
            for (int nn = 0; nn < NBF - 2; nn++)
                #pragma unroll
                for (int kk = 0; kk < 2; kk++)
                    acc[g * 4 + j][2 + nn] = __builtin_amdgcn_mfma_f32_16x16x32_bf16(
                        aH[j * 2 + kk], b1[nn * 2 + kk], acc[g * 4 + j][2 + nn], 0, 0, 0);
        __builtin_amdgcn_s_setprio(0);
    };

    // ---- prologue: T0 full + T1.{B0,B1,A0}; vmcnt leaves T1's units in flight ----
    STAGEA_H(0, 0, 0); STAGEA_H(0, 1, 0); STAGEB_H(0, 0, 0); STAGEB_H(0, 1, 0);
    STAGEB_H(1, 0, 1); STAGEB_H(1, 1, 1); STAGEA_H(1, 0, 1);
    vmcnt_wait<VM8>();
    __builtin_amdgcn_s_barrier();

    bf16x8 aH[8], bH0[4], bH1[2 * (NBF - 2)];
    for (int it = 0; it < NIT; it++) {
        int u = 2 * it + 1, T2 = 2 * it + 2, U2 = 2 * it + 3;
        // Ph1: T m0 x n0; stage U.A1
        LDA(0, 0, aH); LDB0(0, bH0);
        STAGEA_H(1, 1, u);
        FENCE(); __builtin_amdgcn_s_barrier();
        LGKM0();
        MMQ0(0, aH, bH0);
        FENCE(); __builtin_amdgcn_s_barrier();
        // Ph2: T m0 x n1
        LDB1(0, bH1);
        FENCE(); __builtin_amdgcn_s_barrier();
        LGKM0();
        MMQ1(0, aH, bH1);
        FENCE(); __builtin_amdgcn_s_barrier();
        // Ph3: T m1 x n1; stage T'.B0 (buf0.B last read Ph2)
        LDA(0, 1, aH);
        if (T2 < nt) STAGEB_H(0, 0, T2);
        FENCE(); __builtin_amdgcn_s_barrier();
        LGKM0();
        MMQ1(1, aH, bH1);
        FENCE(); __builtin_amdgcn_s_barrier();
        // Ph4: T m1 x n0 (reg reuse); stage T'.B1; vmcnt -> U complete
        if (T2 < nt) {
            STAGEB_H(0, 1, T2);
            vmcnt_wait<VM4>();
        } else {
            vmcnt_wait<0>();
        }
        __builtin_amdgcn_s_barrier();
        MMQ0(1, aH, bH0);
        FENCE(); __builtin_amdgcn_s_barrier();
        // Ph5: U m0 x n0; stage T'.A0 (buf0.A last read Ph3)
        LDA(1, 0, aH); LDB0(1, bH0);
        if (T2 < nt) STAGEA_H(0, 0, T2);
        FENCE(); __builtin_amdgcn_s_barrier();
        LGKM0();
        MMQ0(0, aH, bH0);
        FENCE(); __builtin_amdgcn_s_barrier();
        // Ph6: U m0 x n1; stage T'.A1
        LDB1(1, bH1);
        if (T2 < nt) STAGEA_H(0, 1, T2);
        FENCE(); __builtin_amdgcn_s_barrier();
        LGKM0();
        MMQ1(0, aH, bH1);
        FENCE(); __builtin_amdgcn_s_barrier();
        // Ph7: U m1 x n1; stage U'.B0+B1 (buf1.B last read Ph6)
        LDA(1, 1, aH);
        if (U2 < nt) { STAGEB_H(1, 0, U2); STAGEB_H(1, 1, U2); }
        FENCE(); __builtin_amdgcn_s_barrier();
        LGKM0();
        MMQ1(1, aH, bH1);
        FENCE(); __builtin_amdgcn_s_barrier();
        // Ph8: U m1 x n0; stage U'.A0; vmcnt -> T' complete for next Ph1
        if (U2 < nt) {
            STAGEA_H(1, 0, U2);
            vmcnt_wait<VM8>();
        } else {
            vmcnt_wait<0>();
        }
        __builtin_amdgcn_s_barrier();
        MMQ0(1, aH, bH0);
        FENCE(); __builtin_amdgcn_s_barrier();
    }

    // epilogue: C/D layout col=lane&15, row=(lane>>4)*4+r
    #pragma unroll
    for (int m = 0; m < 8; m++) {
        #pragma unroll
        for (int n = 0; n < NBF; n++) {
            int col = bn + wn * (NBF * 16) + n * 16 + lm;
            #pragma unroll
            for (int r = 0; r < 4; r++) {
                int row = bm + wm * 128 + m * 16 + lk * 4 + r;
                float v = acc[m][n][r];
                if (MODE == 1) v += res[(size_t)row * N + col] + bias[col];
                if (MODE == 2) v = gelu_fast(v + bias[col]);
                if (OUTBF) ((__bf16*)Cv)[(size_t)row * N + col] = (__bf16)v;
                else       ((float*)Cv)[(size_t)row * N + col] = v;
            }
        }
    }
}

// ---------------- reduce4ln: x += bias + sum of 4 bf16 partials; optional LN -----
template<int DOLN>
__global__ __launch_bounds__(256) void reduce4ln(
    const __bf16* __restrict__ parts, const float* __restrict__ bias,
    float* __restrict__ x, const float* __restrict__ g,
    const float* __restrict__ b, __bf16* __restrict__ xn)
{
    const size_t PS = (size_t)ROWS * DIM;
    int row = blockIdx.x, t = threadIdx.x;
    size_t base = (size_t)row * DIM + t * 4;
    float4 xr = *(const float4*)(x + base);
    float4 bv = ((const float4*)bias)[t];
    float o0 = xr.x + bv.x, o1 = xr.y + bv.y, o2 = xr.z + bv.z, o3 = xr.w + bv.w;
    #pragma unroll
    for (int s = 0; s < 4; s++) {
        bf16x4 p = *(const bf16x4*)(parts + s * PS + base);
        o0 += (float)p[0]; o1 += (float)p[1]; o2 += (float)p[2]; o3 += (float)p[3];
    }
    float4 o = {o0, o1, o2, o3};
    *(float4*)(x + base) = o;
    if constexpr (DOLN) {
        float s  = o0 + o1 + o2 + o3;
        float ss = o0*o0 + o1*o1 + o2*o2 + o3*o3;
        #pragma unroll
        for (int off = 32; off > 0; off >>= 1) {
            s  += __shfl_down(s, off);
            ss += __shfl_down(ss, off);
        }
        __shared__ float wsum[4], wsq[4], stats[2];
        int wid = t >> 6, lane = t & 63;
        if (lane == 0) { wsum[wid] = s; wsq[wid] = ss; }
        __syncthreads();
        if (t == 0) {
            float S  = wsum[0] + wsum[1] + wsum[2] + wsum[3];
            float SS = wsq[0] + wsq[1] + wsq[2] + wsq[3];
            float mean = S * (1.0f / DIM);
            float var  = SS * (1.0f / DIM) - mean * mean;
            stats[0] = mean;
            stats[1] = rsqrtf(var + 1e-5f);
        }
        __syncthreads();
        float mean = stats[0], rstd = stats[1];
        float4 gv = ((const float4*)g)[t];
        float4 bvv = ((const float4*)b)[t];
        bf16x4 on;
        on[0] = (__bf16)((o0 - mean) * rstd * gv.x + bvv.x);
        on[1] = (__bf16)((o1 - mean) * rstd * gv.y + bvv.y);
        on[2] = (__bf16)((o2 - mean) * rstd * gv.z + bvv.z);
        on[3] = (__bf16)((o3 - mean) * rstd * gv.w + bvv.w);
        *(bf16x4*)(xn + base) = on;
    }
}

// ---------------- attn kernel A: per-chunk KVT_c[e][d] = sum_m v[m][e]ek[m][d] --
__global__ __launch_bounds__(256) void attn_local_m(
    const __bf16* __restrict__ qkv, const __bf16* __restrict__ vTg,
    float* __restrict__ KVT, float* __restrict__ Ksum)
{
    int blk = blockIdx.x;
    int c = blk % NCHK, bh = blk / NCHK;
    int b = bh / NH, h = bh % NH;
    __shared__ __bf16 ek_s[64 * 64];
    __shared__ __bf16 ekT_s[64 * 68];
    __shared__ float ksum_p[4][64];
    int t = threadIdx.x, w = t >> 6, l = t & 63;
    size_t rowbase = (size_t)(b * SEQ + c * CHK);

    {
        int m = t >> 2, dq = t & 3;
        const __bf16* kr = qkv + (rowbase + m) * QKP + DIM + h * DH + dq * 16;
        bf16x8 k0 = *(const bf16x8*)kr;
        bf16x8 k1 = *(const bf16x8*)(kr + 8);
        bf16x8 e0, e1;
        #pragma unroll
        for (int j = 0; j < 8; j++) {
            e0[j] = (__bf16)__expf((float)k0[j]);
            e1[j] = (__bf16)__expf((float)k1[j]);
        }
        *(bf16x8*)&ek_s[swz128(m, dq * 16)] = e0;
        *(bf16x8*)&ek_s[swz128(m, dq * 16 + 8)] = e1;
    }
    __syncthreads();
    {
        float kacc = 0.f;
        #pragma unroll
        for (int g = 0; g < 4; g++) {
            bf16x4 pk;
            #pragma unroll
            for (int j = 0; j < 4; j++) {
                __bf16 e = ek_s[swz128(w * 16 + g * 4 + j, l)];
                pk[j] = e;
                kacc += (float)e;
            }
            *(bf16x4*)&ekT_s[l * 68 + w * 16 + g * 4] = pk;
        }
        ksum_p[w][l] = kacc;
    }
    __syncthreads();
    f32x4 acc[4] = {};
    const __bf16* vbase = vTg + (size_t)(h * DH + w * 16 + (l & 15)) * ROWS
                        + (size_t)b * SEQ + c * CHK + (l >> 4) * 8;
    bf16x8 a0 = *(const bf16x8*)vbase;
    bf16x8 a1 = *(const bf16x8*)(vbase + 32);
    #pragma unroll
    for (int fn = 0; fn < 4; fn++) {
        int rbase = (fn * 16 + (l & 15)) * 68 + (l >> 4) * 8;
        bf16x4 b0a = *(const bf16x4*)&ekT_s[rbase];
        bf16x4 b0b = *(const bf16x4*)&ekT_s[rbase + 4];
        bf16x4 b1a = *(const bf16x4*)&ekT_s[rbase + 32];
        bf16x4 b1b = *(const bf16x4*)&ekT_s[rbase + 36];
        bf16x8 b0, b1;
        #pragma unroll
        for (int j = 0; j < 4; j++) {
            b0[j] = b0a[j]; b0[j + 4] = b0b[j];
            b1[j] = b1a[j]; b1[j + 4] = b1b[j];
        }
        acc[fn] = __builtin_amdgcn_mfma_f32_16x16x32_bf16(a0, b0, acc[fn], 0, 0, 0);
        acc[fn] = __builtin_amdgcn_mfma_f32_16x16x32_bf16(a1, b1, acc[fn], 0, 0, 0);
    }
    float* kvout = KVT + (size_t)(bh * NCHK + c) * (DH * DH);
    #pragma unroll
    for (int fn = 0; fn < 4; fn++)
        #pragma unroll
        for (int r = 0; r < 4; r++)
            kvout[(w * 16 + (l >> 4) * 4 + r) * DH + fn * 16 + (l & 15)] = acc[fn][r];
    if (t < 64) {
        float s = ksum_p[0][t] + ksum_p[1][t] + ksum_p[2][t] + ksum_p[3][t];
        Ksum[(size_t)(bh * NCHK + c) * DH + t] = s;
    }
}

// ---------------- attn kernel B: parallel exclusive prefix over chunks ----------
__global__ __launch_bounds__(256) void attn_scan2(
    float* __restrict__ KV, float* __restrict__ Ksum)
{
    int bh = blockIdx.y;
    int bx = blockIdx.x;
    int t = threadIdx.x;
    if (bx < 16) {
        int elem = bx * 256 + t;
        float run = 0.f;
        for (int c = 0; c < NCHK; c++) {
            float* p = KV + ((size_t)(bh * NCHK + c)) * (DH * DH) + elem;
            float tmp = *p;
            *p = run;
            run += tmp;
        }
    } else if (t < DH) {
        float run = 0.f;
        for (int c = 0; c < NCHK; c++) {
            float* p = Ksum + ((size_t)(bh * NCHK + c)) * DH + t;
            float tmp = *p;
            *p = run;
            run += tmp;
        }
    }
}

// ---------------- attn kernel C: per-chunk output via MFMA ----------------------
__global__ __launch_bounds__(256) void attn_out_m(
    const __bf16* __restrict__ qkv, const __bf16* __restrict__ vTg,
    const float* __restrict__ KVT, const float* __restrict__ Ksum,
    __bf16* __restrict__ ag)
{
    int blk = blockIdx.x;
    int c = blk % NCHK, bh = blk / NCHK;
    int b = bh / NH, h = bh % NH;
    __shared__ __bf16 q_s[64 * 64];
    __shared__ __bf16 ek_s[64 * 64];
    __shared__ __bf16 s_s[64 * 64];
    __shared__ __bf16 kvT_s[64 * 64];
    __shared__ float denom_s[64];
    int t = threadIdx.x, w = t >> 6, l = t & 63;
    size_t rowbase = (size_t)(b * SEQ + c * CHK);

    {
        int i = t >> 2, dq = t & 3;
        const __bf16* qr = qkv + (rowbase + i) * QKP + h * DH + dq * 16;
        bf16x8 q0 = *(const bf16x8*)qr, q1 = *(const bf16x8*)(qr + 8);
        float qf[16];
        #pragma unroll
        for (int j = 0; j < 8; j++) { qf[j] = (float)q0[j]; qf[8 + j] = (float)q1[j]; }
        float mx = qf[0];
        #pragma unroll
        for (int j = 1; j < 16; j++) mx = fmaxf(mx, qf[j]);
        mx = fmaxf(mx, __shfl_xor(mx, 1));
        mx = fmaxf(mx, __shfl_xor(mx, 2));
        float ss = 0.f;
        #pragma unroll
        for (int j = 0; j < 16; j++) { qf[j] = __expf(qf[j] - mx); ss += qf[j]; }
        ss += __shfl_xor(ss, 1);
        ss += __shfl_xor(ss, 2);
        float sc = 0.125f / ss;
        bf16x8 o0, o1;
        #pragma unroll
        for (int j = 0; j < 8; j++) {
            o0[j] = (__bf16)(qf[j] * sc);
            o1[j] = (__bf16)(qf[8 + j] * sc);
        }
        *(bf16x8*)&q_s[swz128(i, dq * 16)] = o0;
        *(bf16x8*)&q_s[swz128(i, dq * 16 + 8)] = o1;
        const float* kp = Ksum + (size_t)(bh * NCHK + c) * DH + dq * 16;
        float dk = 0.f;
        #pragma unroll
        for (int j = 0; j < 16; j++) dk += (qf[j] * sc) * kp[j];
        dk += __shfl_xor(dk, 1);
        dk += __shfl_xor(dk, 2);
        if (dq == 0) denom_s[i] = dk;
    }
    {
        int m = t >> 2, dq = t & 3;
        const __bf16* kr = qkv + (rowbase + m) * QKP + DIM + h * DH + dq * 16;
        bf16x8 k0 = *(const bf16x8*)kr, k1 = *(const bf16x8*)(kr + 8);
        bf16x8 e0, e1;
        #pragma unroll
        for (int j = 0; j < 8; j++) {
            e0[j] = (__bf16)__expf((float)k0[j]);
            e1[j] = (__bf16)__expf((float)k1[j]);
        }
        *(bf16x8*)&ek_s[swz128(m, dq * 16)] = e0;
        *(bf16x8*)&ek_s[swz128(m, dq * 16 + 8)] = e1;
    }
    {
        int e = t >> 2, dq = t & 3;
        const float* kvr = KVT + (size_t)(bh * NCHK + c) * (DH * DH) + e * DH + dq * 16;
        bf16x8 o0, o1;
        #pragma unroll
        for (int j = 0; j < 8; j++) { o0[j] = (__bf16)kvr[j]; o1[j] = (__bf16)kvr[8 + j]; }
        *(bf16x8*)&kvT_s[swz128(e, dq * 16)] = o0;
        *(bf16x8*)&kvT_s[swz128(e, dq * 16 + 8)] = o1;
    }
    __syncthreads();

    bf16x8 bq0 = *(const bf16x8*)&q_s[swz128(w * 16 + (l & 15), (l >> 4) * 8)];
    bf16x8 bq1 = *(const bf16x8*)&q_s[swz128(w * 16 + (l & 15), 32 + (l >> 4) * 8)];
    int i_col = w * 16 + (l & 15);
    float dsum = 0.f;
    #pragma unroll
    for (int fm = 0; fm < 4; fm++) {
        bf16x8 ae0 = *(const bf16x8*)&ek_s[swz128(fm * 16 + (l & 15), (l >> 4) * 8)];
        bf16x8 ae1 = *(const bf16x8*)&ek_s[swz128(fm * 16 + (l & 15), 32 + (l >> 4) * 8)];
        f32x4 z = {};
        z = __builtin_amdgcn_mfma_f32_16x16x32_bf16(ae0, bq0, z, 0, 0, 0);
        z = __builtin_amdgcn_mfma_f32_16x16x32_bf16(ae1, bq1, z, 0, 0, 0);
        bf16x4 pk;
        #pragma unroll
        for (int r = 0; r < 4; r++) {
            int m = fm * 16 + (l >> 4) * 4 + r;
            float v = (m <= i_col) ? z[r] : 0.f;
            pk[r] = (__bf16)v;
            dsum += (float)pk[r];
        }
        *(bf16x4*)&s_s[swz128(i_col, fm * 16 + (l >> 4) * 4)] = pk;
    }
    dsum += __shfl_xor(dsum, 16);
    dsum += __shfl_xor(dsum, 32);
    if (l < 16) denom_s[w * 16 + l] += dsum;

    bf16x8 as0 = *(const bf16x8*)&s_s[swz128(w * 16 + (l & 15), (l >> 4) * 8)];
    bf16x8 as1 = *(const bf16x8*)&s_s[swz128(w * 16 + (l & 15), 32 + (l >> 4) * 8)];
    f32x4 oacc[4] = {};
    #pragma unroll
    for (int fn = 0; fn < 4; fn++) {
        const __bf16* vb = vTg + (size_t)(h * DH + fn * 16 + (l & 15)) * ROWS
                         + (size_t)b * SEQ + c * CHK + (l >> 4) * 8;
        bf16x8 bv0 = *(const bf16x8*)vb;
        bf16x8 bv1 = *(const bf16x8*)(vb + 32);
        bf16x8 bk0 = *(const bf16x8*)&kvT_s[swz128(fn * 16 + (l & 15), (l >> 4) * 8)];
        bf16x8 bk1 = *(const bf16x8*)&kvT_s[swz128(fn * 16 + (l & 15), 32 + (l >> 4) * 8)];
        f32x4 z = oacc[fn];
        z = __builtin_amdgcn_mfma_f32_16x16x32_bf16(as0, bv0, z, 0, 0, 0);
        z = __builtin_amdgcn_mfma_f32_16x16x32_bf16(as1, bv1, z, 0, 0, 0);
        z = __builtin_amdgcn_mfma_f32_16x16x32_bf16(bq0, bk0, z, 0, 0, 0);
        z = __builtin_amdgcn_mfma_f32_16x16x32_bf16(bq1, bk1, z, 0, 0, 0);
        oacc[fn] = z;
    }
    #pragma unroll
    for (int r = 0; r < 4; r++) {
        int i = w * 16 + (l >> 4) * 4 + r;
        float dinv = 1.0f / fmaxf(denom_s[i], 1e-3f);
        #pragma unroll
        for (int fn = 0; fn < 4; fn++)
            ag[(rowbase + i) * DIM + h * DH + fn * 16 + (l & 15)] = (__bf16)(oacc[fn][r] * dinv);
    }
}

// ---------------- launch --------------------------------------------------------
extern "C" void kernel_launch(void* const* d_in, const int* in_sizes, int n_in,
                              void* d_out, int out_size, void* d_ws, size_t ws_size,
                              hipStream_t stream) {
    (void)in_sizes; (void)n_in; (void)out_size; (void)ws_size;
    const float* x_in  = (const float*)d_in[0];
    const float* ln1_g = (const float*)d_in[1];
    const float* ln1_b = (const float*)d_in[2];
    const float* Wq    = (const float*)d_in[3];
    const float* Wk    = (const float*)d_in[4];
    const float* Wv    = (const float*)d_in[5];
    const float* Wo    = (const float*)d_in[6];
    const float* bo    = (const float*)d_in[7];
    const float* ln2_g = (const float*)d_in[8];
    const float* ln2_b = (const float*)d_in[9];
    const float* W1    = (const float*)d_in[10];
    const float* b1    = (const float*)d_in[11];
    const float* W2    = (const float*)d_in[12];
    const float* b2    = (const float*)d_in[13];

    float* x = (float*)d_out;
    const size_t MB = 1024 * 1024;
    char* base = (char*)d_ws;

    __bf16* qkv    = (__bf16*)base;
    __bf16* partsO = (__bf16*)base;
    __bf16* h1     = (__bf16*)base;
    __bf16* vTg    = (__bf16*)(base + 24 * MB);
    __bf16* xn     = (__bf16*)(base + 32 * MB);
    __bf16* parts  = (__bf16*)(base + 32 * MB);
    __bf16* a      = (__bf16*)(base + 40 * MB);
    float*  KVT    = (float*)(base + 48 * MB);
    float*  Ks     = (float*)(base + 64 * MB);
    __bf16* wqkt   = (__bf16*)(base + 65 * MB);  // 6MB
    __bf16* wot    = (__bf16*)(base + 71 * MB);  // 2MB
    __bf16* w1t    = (__bf16*)(base + 73 * MB);  // 8MB
    __bf16* w2t    = (__bf16*)(base + 81 * MB);  // 8MB

    const size_t SZ = (size_t)ROWS * DIM;
    hipMemcpyAsync(x, x_in, SZ * sizeof(float), hipMemcpyDeviceToDevice, stream);

    dim3 gScan(17, BB * NH);
    dim3 gTv(ROWS / 64, DIM / 64);

    for (int l = 0; l < DEPTH; l++) {
        const float* wq = Wq + (size_t)l * DIM * DIM;
        const float* wk = Wk + (size_t)l * DIM * DIM;
        const float* wv = Wv + (size_t)l * DIM * DIM;
        const float* wo = Wo + (size_t)l * DIM * DIM;
        const float* w1 = W1 + (size_t)l * DIM * FFD;
        const float* w2 = W2 + (size_t)l * FFD * DIM;

        transpose_all<<<12288, 256, 0, stream>>>(wq, wk, wv, wo, w1, w2,
                                                 wqkt, wot, w1t, w2t);

        // pre-norm attention block
        if (l == 0)
            ln_kernel<<<ROWS, 256, 0, stream>>>(x, ln1_g, ln1_b, xn);
        // fused QKV: N=3072 via TBN=192 (NBF=3) -> 16x16 = 256 blocks
        gemm256<0, 1, 3><<<16 * 16, 512, 0, stream>>>(xn, wqkt, qkv, nullptr, nullptr,
                                                      ROWS, QKP, DIM, DIM, 16, 16, 1);
        transpose_v<<<gTv, 256, 0, stream>>>(qkv, vTg);
        attn_local_m<<<BB * NH * NCHK, 256, 0, stream>>>(qkv, vTg, KVT, Ks);
        attn_scan2<<<gScan, 256, 0, stream>>>(KVT, Ks);
        attn_out_m<<<BB * NH * NCHK, 256, 0, stream>>>(qkv, vTg, KVT, Ks, a);
        // O-proj: split-K 4 over K=1024 -> bf16 partials (qkv/vTg dead)
        gemm256<0, 1, 4><<<4 * 16 * 4, 512, 0, stream>>>(a, wot, partsO, nullptr, nullptr,
                                                         ROWS, DIM, DIM / 4, DIM, 4, 16, 4);
        reduce4ln<1><<<ROWS, 256, 0, stream>>>(partsO, bo + l * DIM, x,
                                               ln2_g + l * DIM, ln2_b + l * DIM, xn);

        // pre-norm FF block (partsO dead -> h1 aliases)
        gemm256<2, 1, 4><<<16 * 16, 512, 0, stream>>>(xn, w1t, h1, b1 + l * FFD, nullptr,
                                                      ROWS, FFD, DIM, DIM, 16, 16, 1);
        gemm256<0, 1, 4><<<4 * 16 * 4, 512, 0, stream>>>(h1, w2t, parts, nullptr, nullptr,
                                                         ROWS, DIM, FFD / 4, FFD, 4, 16, 4);
        if (l + 1 < DEPTH)
            reduce4ln<1><<<ROWS, 256, 0, stream>>>(parts, b2 + l * DIM, x,
                                                   ln1_g + (l + 1) * DIM,
                                                   ln1_b + (l + 1) * DIM, xn);
        else
            reduce4ln<0><<<ROWS, 256, 0, stream>>>(parts, b2 + l * DIM, x,
                                                   nullptr, nullptr, nullptr);
    }
}